// Round 1
// baseline (7217.113 us; speedup 1.0000x reference)
//
#include <hip/hip_runtime.h>
#include <math.h>

#define HP     270
#define PLANE  72900      // 270*270
#define PW     272
#define PPLANE 73984      // 272*272

// ---------------- reduction helper ----------------
__device__ __forceinline__ float blockReduceSum(float val) {
  __shared__ float sh[16];
  int lane = threadIdx.x & 63, wid = threadIdx.x >> 6;
#pragma unroll
  for (int o = 32; o > 0; o >>= 1) val += __shfl_down(val, o, 64);
  __syncthreads();
  if (lane == 0) sh[wid] = val;
  __syncthreads();
  float tot = 0.f;
  int nw = (blockDim.x + 63) >> 6;
  for (int i = 0; i < nw; ++i) tot += sh[i];
  return tot;
}

// ---------------- twiddle matrix: tw[j*270+k] = (cos, sin)(2*pi*j*k/270) ----------------
__global__ __launch_bounds__(256) void k_twiddle(float2* __restrict__ tw) {
  int idx = blockIdx.x * 256 + threadIdx.x;
  if (idx >= PLANE) return;
  int j = idx / HP, k = idx % HP;
  int m = (j * k) % HP;
  double ang = (2.0 * M_PI * (double)m) / 270.0;
  tw[idx] = make_float2((float)cos(ang), (float)sin(ang));
}

// ---------------- symmetric pad x (2,256,256) -> xp (2,270,270), pad 7 ----------------
__global__ __launch_bounds__(256) void k_sympad(const float* __restrict__ x, float* __restrict__ xp) {
  int idx = blockIdx.x * 256 + threadIdx.x;
  if (idx >= 2 * PLANE) return;
  int b = idx / PLANE, p = idx % PLANE;
  int i = p / HP, j = p % HP;
  int si = i - 7; si = si < 0 ? -1 - si : (si > 255 ? 511 - si : si);
  int sj = j - 7; sj = sj < 0 ? -1 - sj : (sj > 255 ? 511 - sj : sj);
  xp[idx] = x[(b * 256 + si) * 256 + sj];
}

// ---------------- edgetaper 1D weights ah (270), aw (270) ----------------
__global__ __launch_bounds__(512) void k_edget(const float* __restrict__ bk, float* __restrict__ ahw) {
  __shared__ float pr[15], pc[15], acr[15], accl[15];
  int t = threadIdx.x;
  if (t < 15) {
    float sr = 0.f, scv = 0.f;
    for (int k = 0; k < 15; ++k) { sr += bk[t * 15 + k]; scv += bk[k * 15 + t]; }
    pr[t] = sr; pc[t] = scv;
  }
  __syncthreads();
  if (t < 30) {
    int l = t % 15; bool isr = (t < 15);
    const float* p = isr ? pr : pc;
    float s = 0.f;
    for (int j = 0; j + l < 15; ++j) s += p[j] * p[j + l];
    if (isr) acr[l] = s; else accl[l] = s;
  }
  __syncthreads();
  for (int i = t; i < 540; i += blockDim.x) {
    bool isr = (i < 270);
    int ii = isr ? i : i - 270;
    const float* ac = isr ? acr : accl;
    int m = (ii == 269) ? 0 : ii;      // z270[269] = z269[0]
    float zv;
    if (m < 15) zv = ac[m];
    else if (m >= 255) zv = ac[269 - m];
    else zv = 0.f;
    ahw[i] = 1.f - zv / ac[0];
  }
}

// ---------------- Hf = psf2otf(blur 15x15, roll -7) ----------------
__global__ __launch_bounds__(256) void k_Hf(const float* __restrict__ bk, float2* __restrict__ Hf) {
  int p = blockIdx.x * 256 + threadIdx.x;
  if (p >= PLANE) return;
  int u = p / HP, v = p % HP;
  float2 er[15], es[15];
#pragma unroll
  for (int r = 0; r < 15; ++r) {
    int m = ((u * (r - 7)) % HP + HP) % HP;
    float sn, cs;
    sincosf(2.f * (float)M_PI * (float)m / 270.f, &sn, &cs);
    er[r] = make_float2(cs, -sn);
    int m2 = ((v * (r - 7)) % HP + HP) % HP;
    sincosf(2.f * (float)M_PI * (float)m2 / 270.f, &sn, &cs);
    es[r] = make_float2(cs, -sn);
  }
  float ar = 0.f, ai = 0.f;
#pragma unroll 1
  for (int r = 0; r < 15; ++r) {
    float rr = 0.f, ri = 0.f;
#pragma unroll
    for (int s = 0; s < 15; ++s) {
      float wv = bk[r * 15 + s];
      rr += wv * es[s].x; ri += wv * es[s].y;
    }
    ar += er[r].x * rr - er[r].y * ri;
    ai += er[r].x * ri + er[r].y * rr;
  }
  Hf[p] = make_float2(ar, ai);
}

// ---------------- weight normalization (wnorm) ----------------
// trans==0: out[f*fsize+i].  trans==1: grouped-transposed conv layout:
// g=f/fmod, fi=f%fmod; out[g*fmod*fsize + ((fi/8)*CIN + ci)*72 + (fi%8)*9 + rs]
__global__ __launch_bounds__(256) void k_wnorm(const float* __restrict__ w, const float* __restrict__ scale,
                                               float* __restrict__ out, int fsize, int fmod, int trans, int CIN) {
  int f = blockIdx.x;
  const float* wf = w + (size_t)f * fsize;
  float s = 0.f;
  for (int i = threadIdx.x; i < fsize; i += 256) s += wf[i];
  float mean = blockReduceSum(s) / (float)fsize;
  float s2 = 0.f;
  for (int i = threadIdx.x; i < fsize; i += 256) { float d = wf[i] - mean; s2 += d * d; }
  float nrm = sqrtf(blockReduceSum(s2));
  float sc = scale[f] / nrm;
  for (int i = threadIdx.x; i < fsize; i += 256) {
    float val = (wf[i] - mean) * sc;
    if (!trans) out[(size_t)f * fsize + i] = val;
    else {
      int g = f / fmod, fi = f % fmod;
      int ci = i / 9, rs = i % 9;
      out[(size_t)g * fmod * fsize + ((fi / 8) * CIN + ci) * 72 + (fi % 8) * 9 + rs] = val;
    }
  }
}

// ---------------- S = sum_f |FT(ww_f 5x5)|^2 ----------------
__global__ __launch_bounds__(256) void k_S(const float* __restrict__ wwn, float* __restrict__ S) {
  int p = blockIdx.x * 256 + threadIdx.x;
  if (p >= PLANE) return;
  int u = p / HP, v = p % HP;
  float2 er[5], es[5];
#pragma unroll
  for (int r = 0; r < 5; ++r) {
    float sn, cs;
    int m = (u * r) % HP;
    sincosf(2.f * (float)M_PI * (float)m / 270.f, &sn, &cs);
    er[r] = make_float2(cs, -sn);
    int m2 = (v * r) % HP;
    sincosf(2.f * (float)M_PI * (float)m2 / 270.f, &sn, &cs);
    es[r] = make_float2(cs, -sn);
  }
  float prr[25], pii[25];
#pragma unroll
  for (int r = 0; r < 5; ++r)
#pragma unroll
    for (int s = 0; s < 5; ++s) {
      prr[r * 5 + s] = er[r].x * es[s].x - er[r].y * es[s].y;
      pii[r * 5 + s] = er[r].x * es[s].y + er[r].y * es[s].x;
    }
  float acc = 0.f;
#pragma unroll 1
  for (int f = 0; f < 24; ++f) {
    float xr = 0.f, xi = 0.f;
#pragma unroll
    for (int t = 0; t < 25; ++t) {
      float wv = wwn[f * 25 + t];
      xr += wv * prr[t]; xi += wv * pii[t];
    }
    acc += xr * xr + xi * xi;
  }
  S[p] = acc;
}

// ---------------- T = conj(Hf)/(|Hf|^2 + a_d S) ----------------
__global__ __launch_bounds__(256) void k_T(const float2* __restrict__ Hf, const float* __restrict__ S,
                                           const float* __restrict__ alpha, float2* __restrict__ T) {
  int idx = blockIdx.x * 256 + threadIdx.x;
  if (idx >= 4 * PLANE) return;
  int d = idx / PLANE, p = idx % PLANE;
  float a = expf(alpha[d]);
  float2 h = Hf[p];
  float den = h.x * h.x + h.y * h.y + a * S[p];
  T[idx] = make_float2(h.x / den, -h.y / den);
}

__global__ __launch_bounds__(256) void k_amp(const float2* __restrict__ T, float* __restrict__ red) {
  int d = blockIdx.x;
  const float2* Td = T + (size_t)d * PLANE;
  float acc = 0.f;
  for (int i = threadIdx.x; i < PLANE; i += 256) { float2 t = Td[i]; acc += t.x * t.x + t.y * t.y; }
  float tot = blockReduceSum(acc);
  if (threadIdx.x == 0) red[d] = tot / (float)PLANE;
}

__global__ void k_eps(const float* __restrict__ apj, const float* __restrict__ stdn, float* __restrict__ red) {
  int s = threadIdx.x;
  if (s < 8) {
    int b = s >> 2, d = s & 3;
    red[8 + s] = expf(apj[0]) * stdn[b] * sqrtf(red[d]) * sqrtf(72899.f);
  }
}

// ---------------- DFT passes (270-pt dense) ----------------
// row, real input:  out[m][r][v] = sum_w in[m][r][w] * (c, sgn*s)[w*270+v]
__global__ __launch_bounds__(256) void k_row_r(const float* __restrict__ in, float2* __restrict__ out,
                                               const float2* __restrict__ tw, float sgn) {
  int v = blockIdx.x * 64 + threadIdx.x;
  int r = blockIdx.y * 4 + threadIdx.y;
  int m = blockIdx.z;
  if (v >= HP || r >= HP) return;
  const float* row = in + ((size_t)m * HP + r) * HP;
  float ar = 0.f, ai = 0.f;
#pragma unroll 2
  for (int w = 0; w < HP; ++w) {
    float a = row[w];
    float2 t = tw[w * HP + v];
    ar += a * t.x;
    ai += (a * sgn) * t.y;
  }
  out[((size_t)m * HP + r) * HP + v] = make_float2(ar, ai);
}

// row, complex input
__global__ __launch_bounds__(256) void k_row_c(const float2* __restrict__ in, float2* __restrict__ out,
                                               const float2* __restrict__ tw, float sgn) {
  int v = blockIdx.x * 64 + threadIdx.x;
  int r = blockIdx.y * 4 + threadIdx.y;
  int m = blockIdx.z;
  if (v >= HP || r >= HP) return;
  const float2* row = in + ((size_t)m * HP + r) * HP;
  float ar = 0.f, ai = 0.f;
#pragma unroll 2
  for (int w = 0; w < HP; ++w) {
    float2 g = row[w];
    float2 t = tw[w * HP + v];
    float ty = sgn * t.y;
    ar += g.x * t.x - g.y * ty;
    ai += g.x * ty + g.y * t.x;
  }
  out[((size_t)m * HP + r) * HP + v] = make_float2(ar, ai);
}

// col, complex output
__global__ __launch_bounds__(256) void k_col_c(const float2* __restrict__ in, float2* __restrict__ out,
                                               const float2* __restrict__ tw, float sgn, float scale) {
  int v = blockIdx.x * 64 + threadIdx.x;
  int u = blockIdx.y * 4 + threadIdx.y;
  int m = blockIdx.z;
  if (v >= HP || u >= HP) return;
  const float2* cp = in + (size_t)m * PLANE;
  float ar = 0.f, ai = 0.f;
#pragma unroll 2
  for (int h = 0; h < HP; ++h) {
    float2 g = cp[h * HP + v];
    float2 t = tw[h * HP + u];
    float ty = sgn * t.y;
    ar += g.x * t.x - g.y * ty;
    ai += g.x * ty + g.y * t.x;
  }
  out[((size_t)m * HP + u) * HP + v] = make_float2(ar * scale, ai * scale);
}

// col, real output
__global__ __launch_bounds__(256) void k_col_r(const float2* __restrict__ in, float* __restrict__ out,
                                               const float2* __restrict__ tw, float sgn, float scale) {
  int v = blockIdx.x * 64 + threadIdx.x;
  int u = blockIdx.y * 4 + threadIdx.y;
  int m = blockIdx.z;
  if (v >= HP || u >= HP) return;
  const float2* cp = in + (size_t)m * PLANE;
  float ar = 0.f;
#pragma unroll 2
  for (int h = 0; h < HP; ++h) {
    float2 g = cp[h * HP + v];
    float2 t = tw[h * HP + u];
    float ty = sgn * t.y;
    ar += g.x * t.x - g.y * ty;
  }
  out[((size_t)m * HP + u) * HP + v] = ar * scale;
}

// ---------------- pointwise ----------------
__global__ __launch_bounds__(256) void k_mulHf(const float2* __restrict__ in, const float2* __restrict__ Hf,
                                               float2* __restrict__ out) {
  int idx = blockIdx.x * 256 + threadIdx.x;
  if (idx >= 2 * PLANE) return;
  int p = idx % PLANE;
  float2 a = in[idx], b = Hf[p];
  out[idx] = make_float2(a.x * b.x - a.y * b.y, a.x * b.y + a.y * b.x);
}

__global__ __launch_bounds__(256) void k_taper(float* __restrict__ xp, const float* __restrict__ blr,
                                               const float* __restrict__ ahw) {
  int idx = blockIdx.x * 256 + threadIdx.x;
  if (idx >= 2 * PLANE) return;
  int p = idx % PLANE;
  int i = p / HP, j = p % HP;
  float al = ahw[i] * ahw[270 + j];
  xp[idx] = al * xp[idx] + (1.f - al) * blr[idx];
}

__global__ __launch_bounds__(256) void k_mulTY(const float2* __restrict__ T, const float2* __restrict__ Y,
                                               float2* __restrict__ out) {
  int idx = blockIdx.x * 256 + threadIdx.x;
  if (idx >= 8 * PLANE) return;
  int s = idx / PLANE, p = idx % PLANE;
  int b = s >> 2, d = s & 3;
  float2 a = T[(size_t)d * PLANE + p], y = Y[(size_t)b * PLANE + p];
  out[idx] = make_float2(a.x * y.x - a.y * y.y, a.x * y.y + a.y * y.x);
}

// ---------------- first conv 5x5 1->32 (symmetric pad 2), writes padded layout ----------------
__global__ __launch_bounds__(256) void k_conv5(const float* __restrict__ z, const float* __restrict__ cw,
                                               const float* __restrict__ bias, float* __restrict__ out) {
  int p = blockIdx.x * 256 + threadIdx.x;
  if (p >= PLANE) return;
  int sc = blockIdx.y;
  int i = p / HP, j = p % HP;
  const float* zs = z + (size_t)sc * PLANE;
  float v[25];
#pragma unroll
  for (int r = 0; r < 5; ++r) {
    int ii = i + r - 2; ii = ii < 0 ? -1 - ii : (ii > 269 ? 539 - ii : ii);
#pragma unroll
    for (int s = 0; s < 5; ++s) {
      int jj = j + s - 2; jj = jj < 0 ? -1 - jj : (jj > 269 ? 539 - jj : jj);
      v[r * 5 + s] = zs[ii * HP + jj];
    }
  }
  int o = (i + 1) * PW + (j + 1);
#pragma unroll 1
  for (int co = 0; co < 32; ++co) {
    float acc = bias[co];
#pragma unroll
    for (int k = 0; k < 25; ++k) acc += cw[co * 25 + k] * v[k];
    out[(size_t)(sc * 32 + co) * PPLANE + o] = acc;
  }
}

// ---------------- halo fill (symmetric pad 1 on 272x272 planes) ----------------
__global__ __launch_bounds__(256) void k_halo(float* __restrict__ buf, int nplanes) {
  int idx = blockIdx.x * 256 + threadIdx.x;
  const int per = 272 * 2 + 270 * 2;  // 1084
  int plane = idx / per;
  if (plane >= nplanes) return;
  int c = idx % per;
  float* b = buf + (size_t)plane * PPLANE;
  int r, cl;
  if (c < 272) { r = 0; cl = c; }
  else if (c < 544) { r = 271; cl = c - 272; }
  else if (c < 814) { r = c - 544 + 1; cl = 0; }
  else { r = c - 814 + 1; cl = 271; }
  int si = r - 1;  si = si < 0 ? 0 : (si > 269 ? 269 : si);
  int sj = cl - 1; sj = sj < 0 ? 0 : (sj > 269 ? 269 : sj);
  b[r * PW + cl] = b[(si + 1) * PW + (sj + 1)];
}

// ---------------- 3x3 conv, prelu on input, padded in/out layouts ----------------
template <int CIN, int COUT, bool SC>
__global__ __launch_bounds__(256) void k_conv3(const float* __restrict__ in, const float* __restrict__ wt,
                                               const float* __restrict__ bias, const float* __restrict__ pre,
                                               float* __restrict__ out, const float* __restrict__ oldo) {
  int sc = blockIdx.y;
  int tile = blockIdx.x;
  int tx0 = (tile % 9) * 32, ty0 = (tile / 9) * 32;
  int ix = threadIdx.x & 15, iy = threadIdx.x >> 4;
  int x = tx0 + 2 * ix, y = ty0 + 2 * iy;
  int lx = x > 268 ? 268 : x, ly = y > 268 ? 268 : y;
  const float* inp = in + (size_t)sc * CIN * PPLANE;
  int pbase = ly * PW + lx;  // padded addr of (ly-1, lx-1)

#pragma unroll 1
  for (int cb = 0; cb < COUT / 8; ++cb) {
    float acc[8][4];
#pragma unroll
    for (int co = 0; co < 8; ++co)
#pragma unroll
      for (int q = 0; q < 4; ++q) acc[co][q] = 0.f;
    const float* wcb = wt + (size_t)cb * CIN * 72;
#pragma unroll 1
    for (int ci = 0; ci < CIN; ++ci) {
      const float* ip = inp + (size_t)ci * PPLANE + pbase;
      float a = pre[ci];
      float v[16];
#pragma unroll
      for (int r = 0; r < 4; ++r)
#pragma unroll
        for (int cc = 0; cc < 4; ++cc) {
          float t = ip[r * PW + cc];
          v[r * 4 + cc] = fmaxf(t, 0.f) + a * fminf(t, 0.f);
        }
      const float* w = wcb + ci * 72;
#pragma unroll
      for (int co = 0; co < 8; ++co)
#pragma unroll
        for (int r = 0; r < 3; ++r)
#pragma unroll
          for (int s = 0; s < 3; ++s) {
            float wv = w[co * 9 + r * 3 + s];
            acc[co][0] += v[r * 4 + s] * wv;
            acc[co][1] += v[r * 4 + s + 1] * wv;
            acc[co][2] += v[(r + 1) * 4 + s] * wv;
            acc[co][3] += v[(r + 1) * 4 + s + 1] * wv;
          }
    }
#pragma unroll
    for (int co = 0; co < 8; ++co) {
      int oc = cb * 8 + co;
      float b = bias[oc];
      float* op = out + (size_t)(sc * COUT + oc) * PPLANE;
#pragma unroll
      for (int q = 0; q < 4; ++q) {
        int xx = x + (q & 1), yy = y + (q >> 1);
        if (xx < 270 && yy < 270) {
          int o = (yy + 1) * PW + (xx + 1);
          float val = acc[co][q] + b;
          if (SC) val += oldo[(size_t)(sc * COUT + oc) * PPLANE + o];
          op[o] = val;
        }
      }
    }
  }
}

// ---------------- transposed conv 5x5 32->1, zero boundary, crop built in ----------------
__global__ __launch_bounds__(256) void k_convT(const float* __restrict__ O, const float* __restrict__ cw,
                                               const float* __restrict__ bt, float* __restrict__ yo) {
  int p = blockIdx.x * 256 + threadIdx.x;
  if (p >= PLANE) return;
  int sc = blockIdx.y;
  int h = p / HP, w = p % HP;
  float acc = bt[0];
#pragma unroll 1
  for (int f = 0; f < 32; ++f) {
    const float* Of = O + (size_t)(sc * 32 + f) * PPLANE;
    const float* wf = cw + f * 25;
#pragma unroll
    for (int r = 0; r < 5; ++r) {
      int ih = h + 2 - r;
      if ((unsigned)ih >= (unsigned)HP) continue;
      const float* orow = Of + (ih + 1) * PW + 1;
#pragma unroll
      for (int s = 0; s < 5; ++s) {
        int iw = w + 2 - s;
        if ((unsigned)iw < (unsigned)HP) acc += orow[iw] * wf[r * 5 + s];
      }
    }
  }
  yo[(size_t)sc * PLANE + p] = acc;
}

// ---------------- norm projection scale ----------------
__global__ __launch_bounds__(256) void k_nrm(const float* __restrict__ yb, float* __restrict__ red) {
  int s = blockIdx.x;
  const float* ys = yb + (size_t)s * PLANE;
  float acc = 0.f;
  for (int i = threadIdx.x; i < PLANE; i += 256) { float v = ys[i]; acc += v * v; }
  float tot = blockReduceSum(acc);
  if (threadIdx.x == 0) {
    float nrm = sqrtf(tot);
    float eps = red[8 + s];
    red[16 + s] = (nrm > eps) ? eps / fmaxf(nrm, 1e-12f) : 1.0f;
  }
}

// ---------------- final: clip(z - scl*y), crop, mix ----------------
__global__ __launch_bounds__(256) void k_final(const float* __restrict__ z, const float* __restrict__ yb,
                                               const float* __restrict__ red, const float* __restrict__ mw,
                                               float* __restrict__ out) {
  int idx = blockIdx.x * 256 + threadIdx.x;
  if (idx >= 131072) return;
  int b = idx >> 16;
  int rem = idx & 65535;
  int h = rem >> 8, w = rem & 255;
  int p = (h + 7) * HP + (w + 7);
  float acc = 0.f;
#pragma unroll
  for (int d = 0; d < 4; ++d) {
    int s = b * 4 + d;
    float v = z[(size_t)s * PLANE + p] - red[16 + s] * yb[(size_t)s * PLANE + p];
    v = fminf(fmaxf(v, 0.f), 255.f);
    acc += mw[d] * v;
  }
  out[idx] = acc;
}

// =====================================================================
extern "C" void kernel_launch(void* const* d_in, const int* in_sizes, int n_in,
                              void* d_out, int out_size, void* d_ws, size_t ws_size,
                              hipStream_t stream) {
  (void)in_sizes; (void)n_in; (void)out_size; (void)ws_size;
  const float* x    = (const float*)d_in[0];
  const float* bk   = (const float*)d_in[1];
  const float* stdn = (const float*)d_in[2];
  const float* ww   = (const float*)d_in[3];
  const float* wwsc = (const float*)d_in[4];
  const float* alph = (const float*)d_in[5];
  const float* cw   = (const float*)d_in[6];
  const float* sf   = (const float*)d_in[7];
  const float* bf   = (const float*)d_in[8];
  const float* bt   = (const float*)d_in[9];
  const float* p1   = (const float*)d_in[10];
  const float* w1   = (const float*)d_in[11];
  const float* s1   = (const float*)d_in[12];
  const float* b1   = (const float*)d_in[13];
  const float* p2   = (const float*)d_in[14];
  const float* w2   = (const float*)d_in[15];
  const float* s2   = (const float*)d_in[16];
  const float* b2   = (const float*)d_in[17];
  const float* apj  = (const float*)d_in[18];
  const float* mwp  = (const float*)d_in[19];
  float* out = (float*)d_out;

  size_t off = 0;
  char* wsbase = (char*)d_ws;
  auto alloc = [&](size_t nfloats) -> float* {
    float* p = (float*)(wsbase + off);
    off += ((nfloats * sizeof(float) + 255) / 256) * 256;
    return p;
  };
  float2* tw  = (float2*)alloc(2 * (size_t)PLANE);
  float*  xp  = alloc(2 * (size_t)PLANE);
  float*  rtm = alloc(2 * (size_t)PLANE);
  float2* cb0 = (float2*)alloc(2 * 8 * (size_t)PLANE);
  float2* cb1 = (float2*)alloc(2 * 8 * (size_t)PLANE);
  float2* Yb  = (float2*)alloc(2 * 2 * (size_t)PLANE);
  float2* Hf  = (float2*)alloc(2 * (size_t)PLANE);
  float*  Sb  = alloc(PLANE);
  float2* Tb  = (float2*)alloc(2 * 4 * (size_t)PLANE);
  float*  zb  = alloc(8 * (size_t)PLANE);
  float*  yb  = alloc(8 * (size_t)PLANE);
  float*  ahw = alloc(540);
  float*  wwn = alloc(600);
  float*  cwn = alloc(800);
  float*  w1n = alloc(92160);
  float*  w2n = alloc(92160);
  float*  red = alloc(64);
  float*  Ob  = alloc(4 * 32 * (size_t)PPLANE);
  float*  T1b = alloc(4 * 64 * (size_t)PPLANE);

  dim3 dft_g(5, 68, 2), dft_b(64, 4);

  // setup
  k_twiddle<<<285, 256, 0, stream>>>(tw);
  k_sympad<<<(2 * PLANE + 255) / 256, 256, 0, stream>>>(x, xp);
  k_edget<<<1, 512, 0, stream>>>(bk, ahw);
  k_Hf<<<285, 256, 0, stream>>>(bk, Hf);
  k_wnorm<<<24, 256, 0, stream>>>(ww, wwsc, wwn, 25, 9999, 0, 0);
  k_wnorm<<<32, 256, 0, stream>>>(cw, sf, cwn, 25, 9999, 0, 0);
  k_wnorm<<<320, 256, 0, stream>>>(w1, s1, w1n, 288, 64, 1, 32);
  k_wnorm<<<160, 256, 0, stream>>>(w2, s2, w2n, 576, 32, 1, 64);
  k_S<<<285, 256, 0, stream>>>(wwn, Sb);
  k_T<<<(4 * PLANE + 255) / 256, 256, 0, stream>>>(Hf, Sb, alph, Tb);
  k_amp<<<4, 256, 0, stream>>>(Tb, red);
  k_eps<<<1, 64, 0, stream>>>(apj, stdn, red);

  // edgetaper: blurred = ifft2(fft2(xp)*Hf); xp = a*xp + (1-a)*blurred
  k_row_r<<<dft_g, dft_b, 0, stream>>>(xp, cb1, tw, -1.f);
  k_col_c<<<dft_g, dft_b, 0, stream>>>(cb1, cb0, tw, -1.f, 1.f);
  k_mulHf<<<(2 * PLANE + 255) / 256, 256, 0, stream>>>(cb0, Hf, cb1);
  k_row_c<<<dft_g, dft_b, 0, stream>>>(cb1, cb0, tw, 1.f);
  k_col_r<<<dft_g, dft_b, 0, stream>>>(cb0, rtm, tw, 1.f, 1.f / (float)PLANE);
  k_taper<<<(2 * PLANE + 255) / 256, 256, 0, stream>>>(xp, rtm, ahw);

  // Y = fft2(xp)
  k_row_r<<<dft_g, dft_b, 0, stream>>>(xp, cb1, tw, -1.f);
  k_col_c<<<dft_g, dft_b, 0, stream>>>(cb1, Yb, tw, -1.f, 1.f);

  // z = ifft2(T*Y).real for all 8 (b,d)
  dim3 dft_g8(5, 68, 8);
  k_mulTY<<<(8 * PLANE + 255) / 256, 256, 0, stream>>>(Tb, Yb, cb0);
  k_row_c<<<dft_g8, dft_b, 0, stream>>>(cb0, cb1, tw, 1.f);
  k_col_r<<<dft_g8, dft_b, 0, stream>>>(cb1, zb, tw, 1.f, 1.f / (float)PLANE);

  // conv net, 2 chunks of 4 samples
  for (int c = 0; c < 2; ++c) {
    const float* zc = zb + (size_t)c * 4 * PLANE;
    float* ybc = yb + (size_t)c * 4 * PLANE;
    k_conv5<<<dim3(285, 4), 256, 0, stream>>>(zc, cwn, bf, Ob);
    k_halo<<<(128 * 1084 + 255) / 256, 256, 0, stream>>>(Ob, 128);
    for (int i = 0; i < 5; ++i) {
      k_conv3<32, 64, false><<<dim3(81, 4), 256, 0, stream>>>(Ob, w1n + i * 18432, b1 + i * 64, p1 + i * 32, T1b, Ob);
      k_halo<<<(256 * 1084 + 255) / 256, 256, 0, stream>>>(T1b, 256);
      if (i == 0)
        k_conv3<64, 32, true><<<dim3(81, 4), 256, 0, stream>>>(T1b, w2n + i * 18432, b2 + i * 32, p2 + i * 64, Ob, Ob);
      else
        k_conv3<64, 32, false><<<dim3(81, 4), 256, 0, stream>>>(T1b, w2n + i * 18432, b2 + i * 32, p2 + i * 64, Ob, Ob);
      k_halo<<<(128 * 1084 + 255) / 256, 256, 0, stream>>>(Ob, 128);
    }
    k_convT<<<dim3(285, 4), 256, 0, stream>>>(Ob, cwn, bt, ybc);
  }

  // projection + final mix
  k_nrm<<<8, 256, 0, stream>>>(yb, red);
  k_final<<<(131072 + 255) / 256, 256, 0, stream>>>(zb, yb, red, mwp, out);
}

// Round 2
// 4759.498 us; speedup vs baseline: 1.5164x; 1.5164x over previous
//
#include <hip/hip_runtime.h>
#include <math.h>

#define HP     270
#define PLANE  72900      // 270*270
#define PW     272
#define PPLANE 73984      // 272*272

// ---------------- reduction helper ----------------
__device__ __forceinline__ float blockReduceSum(float val) {
  __shared__ float sh[16];
  int lane = threadIdx.x & 63, wid = threadIdx.x >> 6;
#pragma unroll
  for (int o = 32; o > 0; o >>= 1) val += __shfl_down(val, o, 64);
  __syncthreads();
  if (lane == 0) sh[wid] = val;
  __syncthreads();
  float tot = 0.f;
  int nw = (blockDim.x + 63) >> 6;
  for (int i = 0; i < nw; ++i) tot += sh[i];
  return tot;
}

// ---------------- twiddle matrix: tw[j*270+k] = (cos, sin)(2*pi*j*k/270) ----------------
__global__ __launch_bounds__(256) void k_twiddle(float2* __restrict__ tw) {
  int idx = blockIdx.x * 256 + threadIdx.x;
  if (idx >= PLANE) return;
  int j = idx / HP, k = idx % HP;
  int m = (j * k) % HP;
  double ang = (2.0 * M_PI * (double)m) / 270.0;
  tw[idx] = make_float2((float)cos(ang), (float)sin(ang));
}

// ---------------- symmetric pad x (2,256,256) -> xp (2,270,270), pad 7 ----------------
__global__ __launch_bounds__(256) void k_sympad(const float* __restrict__ x, float* __restrict__ xp) {
  int idx = blockIdx.x * 256 + threadIdx.x;
  if (idx >= 2 * PLANE) return;
  int b = idx / PLANE, p = idx % PLANE;
  int i = p / HP, j = p % HP;
  int si = i - 7; si = si < 0 ? -1 - si : (si > 255 ? 511 - si : si);
  int sj = j - 7; sj = sj < 0 ? -1 - sj : (sj > 255 ? 511 - sj : sj);
  xp[idx] = x[(b * 256 + si) * 256 + sj];
}

// ---------------- edgetaper 1D weights ah (270), aw (270) ----------------
__global__ __launch_bounds__(512) void k_edget(const float* __restrict__ bk, float* __restrict__ ahw) {
  __shared__ float pr[15], pc[15], acr[15], accl[15];
  int t = threadIdx.x;
  if (t < 15) {
    float sr = 0.f, scv = 0.f;
    for (int k = 0; k < 15; ++k) { sr += bk[t * 15 + k]; scv += bk[k * 15 + t]; }
    pr[t] = sr; pc[t] = scv;
  }
  __syncthreads();
  if (t < 30) {
    int l = t % 15; bool isr = (t < 15);
    const float* p = isr ? pr : pc;
    float s = 0.f;
    for (int j = 0; j + l < 15; ++j) s += p[j] * p[j + l];
    if (isr) acr[l] = s; else accl[l] = s;
  }
  __syncthreads();
  for (int i = t; i < 540; i += blockDim.x) {
    bool isr = (i < 270);
    int ii = isr ? i : i - 270;
    const float* ac = isr ? acr : accl;
    int m = (ii == 269) ? 0 : ii;      // z270[269] = z269[0]
    float zv;
    if (m < 15) zv = ac[m];
    else if (m >= 255) zv = ac[269 - m];
    else zv = 0.f;
    ahw[i] = 1.f - zv / ac[0];
  }
}

// ---------------- Hf = psf2otf(blur 15x15, roll -7) ----------------
__global__ __launch_bounds__(256) void k_Hf(const float* __restrict__ bk, float2* __restrict__ Hf) {
  int p = blockIdx.x * 256 + threadIdx.x;
  if (p >= PLANE) return;
  int u = p / HP, v = p % HP;
  float2 er[15], es[15];
#pragma unroll
  for (int r = 0; r < 15; ++r) {
    int m = ((u * (r - 7)) % HP + HP) % HP;
    float sn, cs;
    sincosf(2.f * (float)M_PI * (float)m / 270.f, &sn, &cs);
    er[r] = make_float2(cs, -sn);
    int m2 = ((v * (r - 7)) % HP + HP) % HP;
    sincosf(2.f * (float)M_PI * (float)m2 / 270.f, &sn, &cs);
    es[r] = make_float2(cs, -sn);
  }
  float ar = 0.f, ai = 0.f;
#pragma unroll 1
  for (int r = 0; r < 15; ++r) {
    float rr = 0.f, ri = 0.f;
#pragma unroll
    for (int s = 0; s < 15; ++s) {
      float wv = bk[r * 15 + s];
      rr += wv * es[s].x; ri += wv * es[s].y;
    }
    ar += er[r].x * rr - er[r].y * ri;
    ai += er[r].x * ri + er[r].y * rr;
  }
  Hf[p] = make_float2(ar, ai);
}

// ---------------- weight normalization (wnorm) ----------------
// trans==0: out[f*fsize+i].  trans==1: grouped-transposed conv layout:
// g=f/fmod, fi=f%fmod; out[g*fmod*fsize + ((fi/8)*CIN + ci)*72 + (fi%8)*9 + rs]
__global__ __launch_bounds__(256) void k_wnorm(const float* __restrict__ w, const float* __restrict__ scale,
                                               float* __restrict__ out, int fsize, int fmod, int trans, int CIN) {
  int f = blockIdx.x;
  const float* wf = w + (size_t)f * fsize;
  float s = 0.f;
  for (int i = threadIdx.x; i < fsize; i += 256) s += wf[i];
  float mean = blockReduceSum(s) / (float)fsize;
  float s2 = 0.f;
  for (int i = threadIdx.x; i < fsize; i += 256) { float d = wf[i] - mean; s2 += d * d; }
  float nrm = sqrtf(blockReduceSum(s2));
  float sc = scale[f] / nrm;
  for (int i = threadIdx.x; i < fsize; i += 256) {
    float val = (wf[i] - mean) * sc;
    if (!trans) out[(size_t)f * fsize + i] = val;
    else {
      int g = f / fmod, fi = f % fmod;
      int ci = i / 9, rs = i % 9;
      out[(size_t)g * fmod * fsize + ((fi / 8) * CIN + ci) * 72 + (fi % 8) * 9 + rs] = val;
    }
  }
}

// ---------------- S = sum_f |FT(ww_f 5x5)|^2 ----------------
__global__ __launch_bounds__(256) void k_S(const float* __restrict__ wwn, float* __restrict__ S) {
  int p = blockIdx.x * 256 + threadIdx.x;
  if (p >= PLANE) return;
  int u = p / HP, v = p % HP;
  float2 er[5], es[5];
#pragma unroll
  for (int r = 0; r < 5; ++r) {
    float sn, cs;
    int m = (u * r) % HP;
    sincosf(2.f * (float)M_PI * (float)m / 270.f, &sn, &cs);
    er[r] = make_float2(cs, -sn);
    int m2 = (v * r) % HP;
    sincosf(2.f * (float)M_PI * (float)m2 / 270.f, &sn, &cs);
    es[r] = make_float2(cs, -sn);
  }
  float prr[25], pii[25];
#pragma unroll
  for (int r = 0; r < 5; ++r)
#pragma unroll
    for (int s = 0; s < 5; ++s) {
      prr[r * 5 + s] = er[r].x * es[s].x - er[r].y * es[s].y;
      pii[r * 5 + s] = er[r].x * es[s].y + er[r].y * es[s].x;
    }
  float acc = 0.f;
#pragma unroll 1
  for (int f = 0; f < 24; ++f) {
    float xr = 0.f, xi = 0.f;
#pragma unroll
    for (int t = 0; t < 25; ++t) {
      float wv = wwn[f * 25 + t];
      xr += wv * prr[t]; xi += wv * pii[t];
    }
    acc += xr * xr + xi * xi;
  }
  S[p] = acc;
}

// ---------------- T = conj(Hf)/(|Hf|^2 + a_d S) ----------------
__global__ __launch_bounds__(256) void k_T(const float2* __restrict__ Hf, const float* __restrict__ S,
                                           const float* __restrict__ alpha, float2* __restrict__ T) {
  int idx = blockIdx.x * 256 + threadIdx.x;
  if (idx >= 4 * PLANE) return;
  int d = idx / PLANE, p = idx % PLANE;
  float a = expf(alpha[d]);
  float2 h = Hf[p];
  float den = h.x * h.x + h.y * h.y + a * S[p];
  T[idx] = make_float2(h.x / den, -h.y / den);
}

__global__ __launch_bounds__(256) void k_amp(const float2* __restrict__ T, float* __restrict__ red) {
  int d = blockIdx.x;
  const float2* Td = T + (size_t)d * PLANE;
  float acc = 0.f;
  for (int i = threadIdx.x; i < PLANE; i += 256) { float2 t = Td[i]; acc += t.x * t.x + t.y * t.y; }
  float tot = blockReduceSum(acc);
  if (threadIdx.x == 0) red[d] = tot / (float)PLANE;
}

__global__ void k_eps(const float* __restrict__ apj, const float* __restrict__ stdn, float* __restrict__ red) {
  int s = threadIdx.x;
  if (s < 8) {
    int b = s >> 2, d = s & 3;
    red[8 + s] = expf(apj[0]) * stdn[b] * sqrtf(red[d]) * sqrtf(72899.f);
  }
}

// ---------------- DFT passes (270-pt dense) ----------------
__global__ __launch_bounds__(256) void k_row_r(const float* __restrict__ in, float2* __restrict__ out,
                                               const float2* __restrict__ tw, float sgn) {
  int v = blockIdx.x * 64 + threadIdx.x;
  int r = blockIdx.y * 4 + threadIdx.y;
  int m = blockIdx.z;
  if (v >= HP || r >= HP) return;
  const float* row = in + ((size_t)m * HP + r) * HP;
  float ar = 0.f, ai = 0.f;
#pragma unroll 2
  for (int w = 0; w < HP; ++w) {
    float a = row[w];
    float2 t = tw[w * HP + v];
    ar += a * t.x;
    ai += (a * sgn) * t.y;
  }
  out[((size_t)m * HP + r) * HP + v] = make_float2(ar, ai);
}

__global__ __launch_bounds__(256) void k_row_c(const float2* __restrict__ in, float2* __restrict__ out,
                                               const float2* __restrict__ tw, float sgn) {
  int v = blockIdx.x * 64 + threadIdx.x;
  int r = blockIdx.y * 4 + threadIdx.y;
  int m = blockIdx.z;
  if (v >= HP || r >= HP) return;
  const float2* row = in + ((size_t)m * HP + r) * HP;
  float ar = 0.f, ai = 0.f;
#pragma unroll 2
  for (int w = 0; w < HP; ++w) {
    float2 g = row[w];
    float2 t = tw[w * HP + v];
    float ty = sgn * t.y;
    ar += g.x * t.x - g.y * ty;
    ai += g.x * ty + g.y * t.x;
  }
  out[((size_t)m * HP + r) * HP + v] = make_float2(ar, ai);
}

__global__ __launch_bounds__(256) void k_col_c(const float2* __restrict__ in, float2* __restrict__ out,
                                               const float2* __restrict__ tw, float sgn, float scale) {
  int v = blockIdx.x * 64 + threadIdx.x;
  int u = blockIdx.y * 4 + threadIdx.y;
  int m = blockIdx.z;
  if (v >= HP || u >= HP) return;
  const float2* cp = in + (size_t)m * PLANE;
  float ar = 0.f, ai = 0.f;
#pragma unroll 2
  for (int h = 0; h < HP; ++h) {
    float2 g = cp[h * HP + v];
    float2 t = tw[h * HP + u];
    float ty = sgn * t.y;
    ar += g.x * t.x - g.y * ty;
    ai += g.x * ty + g.y * t.x;
  }
  out[((size_t)m * HP + u) * HP + v] = make_float2(ar * scale, ai * scale);
}

__global__ __launch_bounds__(256) void k_col_r(const float2* __restrict__ in, float* __restrict__ out,
                                               const float2* __restrict__ tw, float sgn, float scale) {
  int v = blockIdx.x * 64 + threadIdx.x;
  int u = blockIdx.y * 4 + threadIdx.y;
  int m = blockIdx.z;
  if (v >= HP || u >= HP) return;
  const float2* cp = in + (size_t)m * PLANE;
  float ar = 0.f;
#pragma unroll 2
  for (int h = 0; h < HP; ++h) {
    float2 g = cp[h * HP + v];
    float2 t = tw[h * HP + u];
    float ty = sgn * t.y;
    ar += g.x * t.x - g.y * ty;
  }
  out[((size_t)m * HP + u) * HP + v] = ar * scale;
}

// ---------------- pointwise ----------------
__global__ __launch_bounds__(256) void k_mulHf(const float2* __restrict__ in, const float2* __restrict__ Hf,
                                               float2* __restrict__ out) {
  int idx = blockIdx.x * 256 + threadIdx.x;
  if (idx >= 2 * PLANE) return;
  int p = idx % PLANE;
  float2 a = in[idx], b = Hf[p];
  out[idx] = make_float2(a.x * b.x - a.y * b.y, a.x * b.y + a.y * b.x);
}

__global__ __launch_bounds__(256) void k_taper(float* __restrict__ xp, const float* __restrict__ blr,
                                               const float* __restrict__ ahw) {
  int idx = blockIdx.x * 256 + threadIdx.x;
  if (idx >= 2 * PLANE) return;
  int p = idx % PLANE;
  int i = p / HP, j = p % HP;
  float al = ahw[i] * ahw[270 + j];
  xp[idx] = al * xp[idx] + (1.f - al) * blr[idx];
}

__global__ __launch_bounds__(256) void k_mulTY(const float2* __restrict__ T, const float2* __restrict__ Y,
                                               float2* __restrict__ out) {
  int idx = blockIdx.x * 256 + threadIdx.x;
  if (idx >= 8 * PLANE) return;
  int s = idx / PLANE, p = idx % PLANE;
  int b = s >> 2, d = s & 3;
  float2 a = T[(size_t)d * PLANE + p], y = Y[(size_t)b * PLANE + p];
  out[idx] = make_float2(a.x * y.x - a.y * y.y, a.x * y.y + a.y * y.x);
}

// ---------------- fused edge-replication halo store (symmetric pad 1) ----------------
__device__ __forceinline__ void store_halo(float* __restrict__ op, int xx, int yy, int o, float val) {
  op[o] = val;
  bool xl = (xx == 0), xr = (xx == 269), yt = (yy == 0), yb = (yy == 269);
  if (xl) op[o - 1] = val;
  if (xr) op[o + 1] = val;
  if (yt) { op[o - PW] = val; if (xl) op[o - PW - 1] = val; if (xr) op[o - PW + 1] = val; }
  if (yb) { op[o + PW] = val; if (xl) op[o + PW - 1] = val; if (xr) op[o + PW + 1] = val; }
}

// ---------------- first conv 5x5 1->32 (symmetric pad 2), writes padded layout + halo ----------------
__global__ __launch_bounds__(256) void k_conv5(const float* __restrict__ z, const float* __restrict__ cw,
                                               const float* __restrict__ bias, float* __restrict__ out) {
  int p = blockIdx.x * 256 + threadIdx.x;
  if (p >= PLANE) return;
  int sc = blockIdx.y;
  int i = p / HP, j = p % HP;
  const float* zs = z + (size_t)sc * PLANE;
  float v[25];
#pragma unroll
  for (int r = 0; r < 5; ++r) {
    int ii = i + r - 2; ii = ii < 0 ? -1 - ii : (ii > 269 ? 539 - ii : ii);
#pragma unroll
    for (int s = 0; s < 5; ++s) {
      int jj = j + s - 2; jj = jj < 0 ? -1 - jj : (jj > 269 ? 539 - jj : jj);
      v[r * 5 + s] = zs[ii * HP + jj];
    }
  }
  int o = (i + 1) * PW + (j + 1);
#pragma unroll 1
  for (int co = 0; co < 32; ++co) {
    float acc = bias[co];
#pragma unroll
    for (int k = 0; k < 25; ++k) acc += cw[co * 25 + k] * v[k];
    store_halo(out + (size_t)(sc * 32 + co) * PPLANE, j, i, o, acc);
  }
}

// ---------------- 3x3 conv, prelu on input, padded in/out layouts, halo fused ----------------
// COB output channels per block; group fastest in blockIdx.x for L2/L3 temporal locality.
template <int CIN, int COUT, int COB, bool SC>
__global__ __launch_bounds__(256) void k_conv3(const float* __restrict__ in, const float* __restrict__ wt,
                                               const float* __restrict__ bias, const float* __restrict__ pre,
                                               float* __restrict__ out, const float* __restrict__ oldo) {
  constexpr int GROUPS = COUT / COB;
  constexpr int NB = COB / 8;
  int g = blockIdx.x % GROUPS;
  int tile = blockIdx.x / GROUPS;
  int sc = blockIdx.y;
  int tx0 = (tile % 9) * 32, ty0 = (tile / 9) * 32;
  int ix = threadIdx.x & 15, iy = threadIdx.x >> 4;
  int x = tx0 + 2 * ix, y = ty0 + 2 * iy;
  int lx = x > 268 ? 268 : x, ly = y > 268 ? 268 : y;
  const float* inp = in + (size_t)sc * CIN * PPLANE;
  int pbase = ly * PW + lx;  // padded addr of (ly-1, lx-1)

  float acc[COB][4];
#pragma unroll
  for (int co = 0; co < COB; ++co)
#pragma unroll
    for (int q = 0; q < 4; ++q) acc[co][q] = 0.f;

  const float* wbase = wt + (size_t)(g * NB) * CIN * 72;
#pragma unroll 1
  for (int ci = 0; ci < CIN; ++ci) {
    const float* ip = inp + (size_t)ci * PPLANE + pbase;
    float a = pre[ci];
    float v[16];
#pragma unroll
    for (int r = 0; r < 4; ++r)
#pragma unroll
      for (int cc = 0; cc < 4; ++cc) {
        float t = ip[r * PW + cc];
        v[r * 4 + cc] = fmaxf(t, 0.f) + a * fminf(t, 0.f);
      }
#pragma unroll
    for (int nb = 0; nb < NB; ++nb) {
      const float* w = wbase + (size_t)nb * CIN * 72 + ci * 72;
#pragma unroll
      for (int co = 0; co < 8; ++co)
#pragma unroll
        for (int r = 0; r < 3; ++r)
#pragma unroll
          for (int s = 0; s < 3; ++s) {
            float wv = w[co * 9 + r * 3 + s];
            acc[nb * 8 + co][0] += v[r * 4 + s] * wv;
            acc[nb * 8 + co][1] += v[r * 4 + s + 1] * wv;
            acc[nb * 8 + co][2] += v[(r + 1) * 4 + s] * wv;
            acc[nb * 8 + co][3] += v[(r + 1) * 4 + s + 1] * wv;
          }
    }
  }
#pragma unroll
  for (int co = 0; co < COB; ++co) {
    int oc = g * COB + co;
    float b = bias[oc];
    float* op = out + (size_t)(sc * COUT + oc) * PPLANE;
#pragma unroll
    for (int q = 0; q < 4; ++q) {
      int xx = x + (q & 1), yy = y + (q >> 1);
      if (xx < 270 && yy < 270) {
        int o = (yy + 1) * PW + (xx + 1);
        float val = acc[co][q] + b;
        if (SC) val += oldo[(size_t)(sc * COUT + oc) * PPLANE + o];
        store_halo(op, xx, yy, o, val);
      }
    }
  }
}

// ---------------- transposed conv 5x5 32->1, zero boundary, crop built in ----------------
__global__ __launch_bounds__(256) void k_convT(const float* __restrict__ O, const float* __restrict__ cw,
                                               const float* __restrict__ bt, float* __restrict__ yo) {
  int p = blockIdx.x * 256 + threadIdx.x;
  if (p >= PLANE) return;
  int sc = blockIdx.y;
  int h = p / HP, w = p % HP;
  float acc = bt[0];
#pragma unroll 1
  for (int f = 0; f < 32; ++f) {
    const float* Of = O + (size_t)(sc * 32 + f) * PPLANE;
    const float* wf = cw + f * 25;
#pragma unroll
    for (int r = 0; r < 5; ++r) {
      int ih = h + 2 - r;
      if ((unsigned)ih >= (unsigned)HP) continue;
      const float* orow = Of + (ih + 1) * PW + 1;
#pragma unroll
      for (int s = 0; s < 5; ++s) {
        int iw = w + 2 - s;
        if ((unsigned)iw < (unsigned)HP) acc += orow[iw] * wf[r * 5 + s];
      }
    }
  }
  yo[(size_t)sc * PLANE + p] = acc;
}

// ---------------- norm projection scale ----------------
__global__ __launch_bounds__(256) void k_nrm(const float* __restrict__ yb, float* __restrict__ red) {
  int s = blockIdx.x;
  const float* ys = yb + (size_t)s * PLANE;
  float acc = 0.f;
  for (int i = threadIdx.x; i < PLANE; i += 256) { float v = ys[i]; acc += v * v; }
  float tot = blockReduceSum(acc);
  if (threadIdx.x == 0) {
    float nrm = sqrtf(tot);
    float eps = red[8 + s];
    red[16 + s] = (nrm > eps) ? eps / fmaxf(nrm, 1e-12f) : 1.0f;
  }
}

// ---------------- final: clip(z - scl*y), crop, mix ----------------
__global__ __launch_bounds__(256) void k_final(const float* __restrict__ z, const float* __restrict__ yb,
                                               const float* __restrict__ red, const float* __restrict__ mw,
                                               float* __restrict__ out) {
  int idx = blockIdx.x * 256 + threadIdx.x;
  if (idx >= 131072) return;
  int b = idx >> 16;
  int rem = idx & 65535;
  int h = rem >> 8, w = rem & 255;
  int p = (h + 7) * HP + (w + 7);
  float acc = 0.f;
#pragma unroll
  for (int d = 0; d < 4; ++d) {
    int s = b * 4 + d;
    float v = z[(size_t)s * PLANE + p] - red[16 + s] * yb[(size_t)s * PLANE + p];
    v = fminf(fmaxf(v, 0.f), 255.f);
    acc += mw[d] * v;
  }
  out[idx] = acc;
}

// =====================================================================
extern "C" void kernel_launch(void* const* d_in, const int* in_sizes, int n_in,
                              void* d_out, int out_size, void* d_ws, size_t ws_size,
                              hipStream_t stream) {
  (void)in_sizes; (void)n_in; (void)out_size; (void)ws_size;
  const float* x    = (const float*)d_in[0];
  const float* bk   = (const float*)d_in[1];
  const float* stdn = (const float*)d_in[2];
  const float* ww   = (const float*)d_in[3];
  const float* wwsc = (const float*)d_in[4];
  const float* alph = (const float*)d_in[5];
  const float* cw   = (const float*)d_in[6];
  const float* sf   = (const float*)d_in[7];
  const float* bf   = (const float*)d_in[8];
  const float* bt   = (const float*)d_in[9];
  const float* p1   = (const float*)d_in[10];
  const float* w1   = (const float*)d_in[11];
  const float* s1   = (const float*)d_in[12];
  const float* b1   = (const float*)d_in[13];
  const float* p2   = (const float*)d_in[14];
  const float* w2   = (const float*)d_in[15];
  const float* s2   = (const float*)d_in[16];
  const float* b2   = (const float*)d_in[17];
  const float* apj  = (const float*)d_in[18];
  const float* mwp  = (const float*)d_in[19];
  float* out = (float*)d_out;

  size_t off = 0;
  char* wsbase = (char*)d_ws;
  auto alloc = [&](size_t nfloats) -> float* {
    float* p = (float*)(wsbase + off);
    off += ((nfloats * sizeof(float) + 255) / 256) * 256;
    return p;
  };
  float2* tw  = (float2*)alloc(2 * (size_t)PLANE);
  float*  xp  = alloc(2 * (size_t)PLANE);
  float*  rtm = alloc(2 * (size_t)PLANE);
  float2* cb0 = (float2*)alloc(2 * 8 * (size_t)PLANE);
  float2* cb1 = (float2*)alloc(2 * 8 * (size_t)PLANE);
  float2* Yb  = (float2*)alloc(2 * 2 * (size_t)PLANE);
  float2* Hf  = (float2*)alloc(2 * (size_t)PLANE);
  float*  Sb  = alloc(PLANE);
  float2* Tb  = (float2*)alloc(2 * 4 * (size_t)PLANE);
  float*  zb  = alloc(8 * (size_t)PLANE);
  float*  yb  = alloc(8 * (size_t)PLANE);
  float*  ahw = alloc(540);
  float*  wwn = alloc(600);
  float*  cwn = alloc(800);
  float*  w1n = alloc(92160);
  float*  w2n = alloc(92160);
  float*  red = alloc(64);
  float*  Ob  = alloc(4 * 32 * (size_t)PPLANE);
  float*  T1b = alloc(4 * 64 * (size_t)PPLANE);

  dim3 dft_g(5, 68, 2), dft_b(64, 4);

  // setup
  k_twiddle<<<285, 256, 0, stream>>>(tw);
  k_sympad<<<(2 * PLANE + 255) / 256, 256, 0, stream>>>(x, xp);
  k_edget<<<1, 512, 0, stream>>>(bk, ahw);
  k_Hf<<<285, 256, 0, stream>>>(bk, Hf);
  k_wnorm<<<24, 256, 0, stream>>>(ww, wwsc, wwn, 25, 9999, 0, 0);
  k_wnorm<<<32, 256, 0, stream>>>(cw, sf, cwn, 25, 9999, 0, 0);
  k_wnorm<<<320, 256, 0, stream>>>(w1, s1, w1n, 288, 64, 1, 32);
  k_wnorm<<<160, 256, 0, stream>>>(w2, s2, w2n, 576, 32, 1, 64);
  k_S<<<285, 256, 0, stream>>>(wwn, Sb);
  k_T<<<(4 * PLANE + 255) / 256, 256, 0, stream>>>(Hf, Sb, alph, Tb);
  k_amp<<<4, 256, 0, stream>>>(Tb, red);
  k_eps<<<1, 64, 0, stream>>>(apj, stdn, red);

  // edgetaper: blurred = ifft2(fft2(xp)*Hf); xp = a*xp + (1-a)*blurred
  k_row_r<<<dft_g, dft_b, 0, stream>>>(xp, cb1, tw, -1.f);
  k_col_c<<<dft_g, dft_b, 0, stream>>>(cb1, cb0, tw, -1.f, 1.f);
  k_mulHf<<<(2 * PLANE + 255) / 256, 256, 0, stream>>>(cb0, Hf, cb1);
  k_row_c<<<dft_g, dft_b, 0, stream>>>(cb1, cb0, tw, 1.f);
  k_col_r<<<dft_g, dft_b, 0, stream>>>(cb0, rtm, tw, 1.f, 1.f / (float)PLANE);
  k_taper<<<(2 * PLANE + 255) / 256, 256, 0, stream>>>(xp, rtm, ahw);

  // Y = fft2(xp)
  k_row_r<<<dft_g, dft_b, 0, stream>>>(xp, cb1, tw, -1.f);
  k_col_c<<<dft_g, dft_b, 0, stream>>>(cb1, Yb, tw, -1.f, 1.f);

  // z = ifft2(T*Y).real for all 8 (b,d)
  dim3 dft_g8(5, 68, 8);
  k_mulTY<<<(8 * PLANE + 255) / 256, 256, 0, stream>>>(Tb, Yb, cb0);
  k_row_c<<<dft_g8, dft_b, 0, stream>>>(cb0, cb1, tw, 1.f);
  k_col_r<<<dft_g8, dft_b, 0, stream>>>(cb1, zb, tw, 1.f, 1.f / (float)PLANE);

  // conv net, 2 chunks of 4 samples
  for (int c = 0; c < 2; ++c) {
    const float* zc = zb + (size_t)c * 4 * PLANE;
    float* ybc = yb + (size_t)c * 4 * PLANE;
    k_conv5<<<dim3(285, 4), 256, 0, stream>>>(zc, cwn, bf, Ob);
    for (int i = 0; i < 5; ++i) {
      // 32->64: 16 out-channels per block, 4 groups -> 81*4 x-blocks
      k_conv3<32, 64, 16, false><<<dim3(81 * 4, 4), 256, 0, stream>>>(Ob, w1n + i * 18432, b1 + i * 64, p1 + i * 32, T1b, Ob);
      // 64->32: 8 out-channels per block, 4 groups
      if (i == 0)
        k_conv3<64, 32, 8, true><<<dim3(81 * 4, 4), 256, 0, stream>>>(T1b, w2n + i * 18432, b2 + i * 32, p2 + i * 64, Ob, Ob);
      else
        k_conv3<64, 32, 8, false><<<dim3(81 * 4, 4), 256, 0, stream>>>(T1b, w2n + i * 18432, b2 + i * 32, p2 + i * 64, Ob, Ob);
    }
    k_convT<<<dim3(285, 4), 256, 0, stream>>>(Ob, cwn, bt, ybc);
  }

  // projection + final mix
  k_nrm<<<8, 256, 0, stream>>>(yb, red);
  k_final<<<(131072 + 255) / 256, 256, 0, stream>>>(zb, yb, red, mwp, out);
}

// Round 3
// 3399.591 us; speedup vs baseline: 2.1229x; 1.4000x over previous
//
#include <hip/hip_runtime.h>
#include <math.h>

#define HP     270
#define PLANE  72900      // 270*270
#define PW     272
#define PPLANE 73984      // 272*272

typedef unsigned int  uint32;
typedef unsigned short ushort16;
typedef __attribute__((ext_vector_type(8))) short bf16x8;
typedef __attribute__((ext_vector_type(4))) float f32x4;

// ---------------- reduction helper ----------------
__device__ __forceinline__ float blockReduceSum(float val) {
  __shared__ float sh[16];
  int lane = threadIdx.x & 63, wid = threadIdx.x >> 6;
#pragma unroll
  for (int o = 32; o > 0; o >>= 1) val += __shfl_down(val, o, 64);
  __syncthreads();
  if (lane == 0) sh[wid] = val;
  __syncthreads();
  float tot = 0.f;
  int nw = (blockDim.x + 63) >> 6;
  for (int i = 0; i < nw; ++i) tot += sh[i];
  return tot;
}

// ---------------- twiddle matrix ----------------
__global__ __launch_bounds__(256) void k_twiddle(float2* __restrict__ tw) {
  int idx = blockIdx.x * 256 + threadIdx.x;
  if (idx >= PLANE) return;
  int j = idx / HP, k = idx % HP;
  int m = (j * k) % HP;
  double ang = (2.0 * M_PI * (double)m) / 270.0;
  tw[idx] = make_float2((float)cos(ang), (float)sin(ang));
}

// ---------------- symmetric pad x (2,256,256) -> xp (2,270,270), pad 7 ----------------
__global__ __launch_bounds__(256) void k_sympad(const float* __restrict__ x, float* __restrict__ xp) {
  int idx = blockIdx.x * 256 + threadIdx.x;
  if (idx >= 2 * PLANE) return;
  int b = idx / PLANE, p = idx % PLANE;
  int i = p / HP, j = p % HP;
  int si = i - 7; si = si < 0 ? -1 - si : (si > 255 ? 511 - si : si);
  int sj = j - 7; sj = sj < 0 ? -1 - sj : (sj > 255 ? 511 - sj : sj);
  xp[idx] = x[(b * 256 + si) * 256 + sj];
}

// ---------------- edgetaper 1D weights ----------------
__global__ __launch_bounds__(512) void k_edget(const float* __restrict__ bk, float* __restrict__ ahw) {
  __shared__ float pr[15], pc[15], acr[15], accl[15];
  int t = threadIdx.x;
  if (t < 15) {
    float sr = 0.f, scv = 0.f;
    for (int k = 0; k < 15; ++k) { sr += bk[t * 15 + k]; scv += bk[k * 15 + t]; }
    pr[t] = sr; pc[t] = scv;
  }
  __syncthreads();
  if (t < 30) {
    int l = t % 15; bool isr = (t < 15);
    const float* p = isr ? pr : pc;
    float s = 0.f;
    for (int j = 0; j + l < 15; ++j) s += p[j] * p[j + l];
    if (isr) acr[l] = s; else accl[l] = s;
  }
  __syncthreads();
  for (int i = t; i < 540; i += blockDim.x) {
    bool isr = (i < 270);
    int ii = isr ? i : i - 270;
    const float* ac = isr ? acr : accl;
    int m = (ii == 269) ? 0 : ii;
    float zv;
    if (m < 15) zv = ac[m];
    else if (m >= 255) zv = ac[269 - m];
    else zv = 0.f;
    ahw[i] = 1.f - zv / ac[0];
  }
}

// ---------------- Hf = psf2otf(blur 15x15) ----------------
__global__ __launch_bounds__(256) void k_Hf(const float* __restrict__ bk, float2* __restrict__ Hf) {
  int p = blockIdx.x * 256 + threadIdx.x;
  if (p >= PLANE) return;
  int u = p / HP, v = p % HP;
  float2 er[15], es[15];
#pragma unroll
  for (int r = 0; r < 15; ++r) {
    int m = ((u * (r - 7)) % HP + HP) % HP;
    float sn, cs;
    sincosf(2.f * (float)M_PI * (float)m / 270.f, &sn, &cs);
    er[r] = make_float2(cs, -sn);
    int m2 = ((v * (r - 7)) % HP + HP) % HP;
    sincosf(2.f * (float)M_PI * (float)m2 / 270.f, &sn, &cs);
    es[r] = make_float2(cs, -sn);
  }
  float ar = 0.f, ai = 0.f;
#pragma unroll 1
  for (int r = 0; r < 15; ++r) {
    float rr = 0.f, ri = 0.f;
#pragma unroll
    for (int s = 0; s < 15; ++s) {
      float wv = bk[r * 15 + s];
      rr += wv * es[s].x; ri += wv * es[s].y;
    }
    ar += er[r].x * rr - er[r].y * ri;
    ai += er[r].x * ri + er[r].y * rr;
  }
  Hf[p] = make_float2(ar, ai);
}

// ---------------- weight normalization, plain layout (wiener 5x5, conv5) ----------------
__global__ __launch_bounds__(256) void k_wnorm(const float* __restrict__ w, const float* __restrict__ scale,
                                               float* __restrict__ out, int fsize) {
  int f = blockIdx.x;
  const float* wf = w + (size_t)f * fsize;
  float s = 0.f;
  for (int i = threadIdx.x; i < fsize; i += 256) s += wf[i];
  float mean = blockReduceSum(s) / (float)fsize;
  float s2 = 0.f;
  for (int i = threadIdx.x; i < fsize; i += 256) { float d = wf[i] - mean; s2 += d * d; }
  float nrm = sqrtf(blockReduceSum(s2));
  float sc = scale[f] / nrm;
  for (int i = threadIdx.x; i < fsize; i += 256) out[(size_t)f * fsize + i] = (wf[i] - mean) * sc;
}

// ---------------- weight normalization -> split-bf16 MFMA fragment layout ----------------
// A-operand layout (16x16x32): A[m=lane&15][k=quad*8+j].  m=oc_local, k=ci_local.
// ushort layout: (((o*KC+kc)*MT+mt)*64+lane)*16 + (0..7 hi j, 8..15 lo j)
template <int CIN, int COUT>
__global__ __launch_bounds__(256) void k_wfrag(const float* __restrict__ w, const float* __restrict__ scale,
                                               unsigned short* __restrict__ outb) {
  constexpr int KC = CIN / 32, MT = COUT / 16, FS = CIN * 9;
  int fg = blockIdx.x;
  int f = fg % COUT, iter = fg / COUT;
  const float* wf = w + (size_t)fg * FS;
  float s = 0.f;
  for (int i = threadIdx.x; i < FS; i += 256) s += wf[i];
  float mean = blockReduceSum(s) / (float)FS;
  float s2 = 0.f;
  for (int i = threadIdx.x; i < FS; i += 256) { float d = wf[i] - mean; s2 += d * d; }
  float nrm = sqrtf(blockReduceSum(s2));
  float scv = scale[fg] / nrm;
  unsigned short* dst0 = outb + (size_t)iter * (9 * KC * MT * 64 * 16);
  for (int i = threadIdx.x; i < FS; i += 256) {
    float val = (wf[i] - mean) * scv;
    int ci = i / 9, rs = i - ci * 9;
    int kc = ci >> 5, cil = ci & 31, q = cil >> 3, j = cil & 7;
    int mt = f >> 4, ocl = f & 15, lane = q * 16 + ocl;
    unsigned short* d2 = dst0 + ((((rs * KC + kc) * MT + mt) * 64 + lane) * 16);
    uint32 u = __float_as_uint(val);
    d2[j] = (unsigned short)(u >> 16);
    float lof = val - __uint_as_float(u & 0xFFFF0000u);
    d2[8 + j] = (unsigned short)(__float_as_uint(lof) >> 16);
  }
}

// ---------------- S = sum_f |FT(ww_f 5x5)|^2 ----------------
__global__ __launch_bounds__(256) void k_S(const float* __restrict__ wwn, float* __restrict__ S) {
  int p = blockIdx.x * 256 + threadIdx.x;
  if (p >= PLANE) return;
  int u = p / HP, v = p % HP;
  float2 er[5], es[5];
#pragma unroll
  for (int r = 0; r < 5; ++r) {
    float sn, cs;
    int m = (u * r) % HP;
    sincosf(2.f * (float)M_PI * (float)m / 270.f, &sn, &cs);
    er[r] = make_float2(cs, -sn);
    int m2 = (v * r) % HP;
    sincosf(2.f * (float)M_PI * (float)m2 / 270.f, &sn, &cs);
    es[r] = make_float2(cs, -sn);
  }
  float prr[25], pii[25];
#pragma unroll
  for (int r = 0; r < 5; ++r)
#pragma unroll
    for (int s = 0; s < 5; ++s) {
      prr[r * 5 + s] = er[r].x * es[s].x - er[r].y * es[s].y;
      pii[r * 5 + s] = er[r].x * es[s].y + er[r].y * es[s].x;
    }
  float acc = 0.f;
#pragma unroll 1
  for (int f = 0; f < 24; ++f) {
    float xr = 0.f, xi = 0.f;
#pragma unroll
    for (int t = 0; t < 25; ++t) {
      float wv = wwn[f * 25 + t];
      xr += wv * prr[t]; xi += wv * pii[t];
    }
    acc += xr * xr + xi * xi;
  }
  S[p] = acc;
}

// ---------------- T = conj(Hf)/(|Hf|^2 + a_d S) ----------------
__global__ __launch_bounds__(256) void k_T(const float2* __restrict__ Hf, const float* __restrict__ S,
                                           const float* __restrict__ alpha, float2* __restrict__ T) {
  int idx = blockIdx.x * 256 + threadIdx.x;
  if (idx >= 4 * PLANE) return;
  int d = idx / PLANE, p = idx % PLANE;
  float a = expf(alpha[d]);
  float2 h = Hf[p];
  float den = h.x * h.x + h.y * h.y + a * S[p];
  T[idx] = make_float2(h.x / den, -h.y / den);
}

__global__ __launch_bounds__(256) void k_amp(const float2* __restrict__ T, float* __restrict__ red) {
  int d = blockIdx.x;
  const float2* Td = T + (size_t)d * PLANE;
  float acc = 0.f;
  for (int i = threadIdx.x; i < PLANE; i += 256) { float2 t = Td[i]; acc += t.x * t.x + t.y * t.y; }
  float tot = blockReduceSum(acc);
  if (threadIdx.x == 0) red[d] = tot / (float)PLANE;
}

__global__ void k_eps(const float* __restrict__ apj, const float* __restrict__ stdn, float* __restrict__ red) {
  int s = threadIdx.x;
  if (s < 8) {
    int b = s >> 2, d = s & 3;
    red[8 + s] = expf(apj[0]) * stdn[b] * sqrtf(red[d]) * sqrtf(72899.f);
  }
}

__global__ void k_inv(const float* __restrict__ p, float* __restrict__ inv) {
  int t = threadIdx.x;
  if (t < 32) inv[t] = 1.f / p[t];
}

// ---------------- DFT passes (270-pt dense) ----------------
__global__ __launch_bounds__(256) void k_row_r(const float* __restrict__ in, float2* __restrict__ out,
                                               const float2* __restrict__ tw, float sgn) {
  int v = blockIdx.x * 64 + threadIdx.x;
  int r = blockIdx.y * 4 + threadIdx.y;
  int m = blockIdx.z;
  if (v >= HP || r >= HP) return;
  const float* row = in + ((size_t)m * HP + r) * HP;
  float ar = 0.f, ai = 0.f;
#pragma unroll 2
  for (int w = 0; w < HP; ++w) {
    float a = row[w];
    float2 t = tw[w * HP + v];
    ar += a * t.x;
    ai += (a * sgn) * t.y;
  }
  out[((size_t)m * HP + r) * HP + v] = make_float2(ar, ai);
}

__global__ __launch_bounds__(256) void k_row_c(const float2* __restrict__ in, float2* __restrict__ out,
                                               const float2* __restrict__ tw, float sgn) {
  int v = blockIdx.x * 64 + threadIdx.x;
  int r = blockIdx.y * 4 + threadIdx.y;
  int m = blockIdx.z;
  if (v >= HP || r >= HP) return;
  const float2* row = in + ((size_t)m * HP + r) * HP;
  float ar = 0.f, ai = 0.f;
#pragma unroll 2
  for (int w = 0; w < HP; ++w) {
    float2 g = row[w];
    float2 t = tw[w * HP + v];
    float ty = sgn * t.y;
    ar += g.x * t.x - g.y * ty;
    ai += g.x * ty + g.y * t.x;
  }
  out[((size_t)m * HP + r) * HP + v] = make_float2(ar, ai);
}

__global__ __launch_bounds__(256) void k_col_c(const float2* __restrict__ in, float2* __restrict__ out,
                                               const float2* __restrict__ tw, float sgn, float scale) {
  int v = blockIdx.x * 64 + threadIdx.x;
  int u = blockIdx.y * 4 + threadIdx.y;
  int m = blockIdx.z;
  if (v >= HP || u >= HP) return;
  const float2* cp = in + (size_t)m * PLANE;
  float ar = 0.f, ai = 0.f;
#pragma unroll 2
  for (int h = 0; h < HP; ++h) {
    float2 g = cp[h * HP + v];
    float2 t = tw[h * HP + u];
    float ty = sgn * t.y;
    ar += g.x * t.x - g.y * ty;
    ai += g.x * ty + g.y * t.x;
  }
  out[((size_t)m * HP + u) * HP + v] = make_float2(ar * scale, ai * scale);
}

__global__ __launch_bounds__(256) void k_col_r(const float2* __restrict__ in, float* __restrict__ out,
                                               const float2* __restrict__ tw, float sgn, float scale) {
  int v = blockIdx.x * 64 + threadIdx.x;
  int u = blockIdx.y * 4 + threadIdx.y;
  int m = blockIdx.z;
  if (v >= HP || u >= HP) return;
  const float2* cp = in + (size_t)m * PLANE;
  float ar = 0.f;
#pragma unroll 2
  for (int h = 0; h < HP; ++h) {
    float2 g = cp[h * HP + v];
    float2 t = tw[h * HP + u];
    float ty = sgn * t.y;
    ar += g.x * t.x - g.y * ty;
  }
  out[((size_t)m * HP + u) * HP + v] = ar * scale;
}

// ---------------- pointwise ----------------
__global__ __launch_bounds__(256) void k_mulHf(const float2* __restrict__ in, const float2* __restrict__ Hf,
                                               float2* __restrict__ out) {
  int idx = blockIdx.x * 256 + threadIdx.x;
  if (idx >= 2 * PLANE) return;
  int p = idx % PLANE;
  float2 a = in[idx], b = Hf[p];
  out[idx] = make_float2(a.x * b.x - a.y * b.y, a.x * b.y + a.y * b.x);
}

__global__ __launch_bounds__(256) void k_taper(float* __restrict__ xp, const float* __restrict__ blr,
                                               const float* __restrict__ ahw) {
  int idx = blockIdx.x * 256 + threadIdx.x;
  if (idx >= 2 * PLANE) return;
  int p = idx % PLANE;
  int i = p / HP, j = p % HP;
  float al = ahw[i] * ahw[270 + j];
  xp[idx] = al * xp[idx] + (1.f - al) * blr[idx];
}

__global__ __launch_bounds__(256) void k_mulTY(const float2* __restrict__ T, const float2* __restrict__ Y,
                                               float2* __restrict__ out) {
  int idx = blockIdx.x * 256 + threadIdx.x;
  if (idx >= 8 * PLANE) return;
  int s = idx / PLANE, p = idx % PLANE;
  int b = s >> 2, d = s & 3;
  float2 a = T[(size_t)d * PLANE + p], y = Y[(size_t)b * PLANE + p];
  out[idx] = make_float2(a.x * y.x - a.y * y.y, a.x * y.y + a.y * y.x);
}

// ---------------- split+pack helper: two fp32 -> uint2(hi-pair, lo-pair) ----------------
__device__ __forceinline__ uint2 split_pack(float t0, float t1) {
  uint32 u0 = __float_as_uint(t0), u1 = __float_as_uint(t1);
  uint32 hiw = (u0 >> 16) | (u1 & 0xFFFF0000u);
  float r0 = t0 - __uint_as_float(u0 & 0xFFFF0000u);
  float r1 = t1 - __uint_as_float(u1 & 0xFFFF0000u);
  uint32 low = (__float_as_uint(r0) >> 16) | (__float_as_uint(r1) & 0xFFFF0000u);
  return make_uint2(hiw, low);
}

template <typename T>
__device__ __forceinline__ void store_halo_t(T* __restrict__ op, int xx, int yy, int o, T val) {
  op[o] = val;
  bool xl = (xx == 0), xr = (xx == 269), yt = (yy == 0), yb = (yy == 269);
  if (xl) op[o - 1] = val;
  if (xr) op[o + 1] = val;
  if (yt) { op[o - PW] = val; if (xl) op[o - PW - 1] = val; if (xr) op[o - PW + 1] = val; }
  if (yb) { op[o + PW] = val; if (xl) op[o + PW - 1] = val; if (xr) op[o + PW + 1] = val; }
}

// ---------------- first conv 5x5 1->32 (symmetric pad 2) -> split act planes ----------------
__global__ __launch_bounds__(256) void k_conv5(const float* __restrict__ z, const float* __restrict__ cw,
                                               const float* __restrict__ bias, const float* __restrict__ pre,
                                               uint2* __restrict__ actout) {
  int p = blockIdx.x * 256 + threadIdx.x;
  if (p >= PLANE) return;
  int sc = blockIdx.y;
  int i = p / HP, j = p % HP;
  const float* zs = z + (size_t)sc * PLANE;
  float v[25];
#pragma unroll
  for (int r = 0; r < 5; ++r) {
    int ii = i + r - 2; ii = ii < 0 ? -1 - ii : (ii > 269 ? 539 - ii : ii);
#pragma unroll
    for (int s = 0; s < 5; ++s) {
      int jj = j + s - 2; jj = jj < 0 ? -1 - jj : (jj > 269 ? 539 - jj : jj);
      v[r * 5 + s] = zs[ii * HP + jj];
    }
  }
  int o = (i + 1) * PW + (j + 1);
#pragma unroll 1
  for (int cp = 0; cp < 16; ++cp) {
    float a0 = bias[2 * cp], a1 = bias[2 * cp + 1];
#pragma unroll
    for (int k = 0; k < 25; ++k) { a0 += cw[(2 * cp) * 25 + k] * v[k]; a1 += cw[(2 * cp + 1) * 25 + k] * v[k]; }
    float pa0 = pre[2 * cp], pa1 = pre[2 * cp + 1];
    float t0 = fmaxf(a0, 0.f) + pa0 * fminf(a0, 0.f);
    float t1 = fmaxf(a1, 0.f) + pa1 * fminf(a1, 0.f);
    uint2 wv = split_pack(t0, t1);
    store_halo_t(actout + (size_t)(sc * 16 + cp) * PPLANE, j, i, o, wv);
  }
}

// ---------------- MFMA 3x3 conv: D[oc][pix] = sum_{tap,ci} W*act ----------------
// A = weights (split frags precomputed), B = activations (split, ci-pair packed uint2).
template <int CIN, int COUT, bool SC, bool SPLIT>
__global__ __launch_bounds__(256) void k_mconv(
    const uint2* __restrict__ act, const unsigned short* __restrict__ wf,
    const float* __restrict__ bias, const float* __restrict__ pre,
    uint2* __restrict__ actout, float* __restrict__ rawout,
    const uint2* __restrict__ scact, const float* __restrict__ scinv) {
  constexpr int KC = CIN / 32, MT = COUT / 16;
  const int lane = threadIdx.x & 63, wv = threadIdx.x >> 6;
  const int quad = lane >> 4, col = lane & 15;
  const int sc = blockIdx.y;
  const int p0 = (blockIdx.x * 4 + wv) * 64;

  uint32 pix[4], py[4], px[4], boff[4];
#pragma unroll
  for (int nt = 0; nt < 4; ++nt) {
    uint32 p = p0 + nt * 16 + col;
    pix[nt] = p;
    uint32 pc = p > 72899u ? 72899u : p;
    uint32 y = pc / 270u, x = pc - y * 270u;
    py[nt] = y; px[nt] = x;
    boff[nt] = (y + 1) * PW + x;   // padded (y+1, x): window center-row, left col
  }
  uint32 bo[KC][4][4];
#pragma unroll
  for (int kc = 0; kc < KC; ++kc)
#pragma unroll
    for (int nt = 0; nt < 4; ++nt)
#pragma unroll
      for (int r = 0; r < 4; ++r)
        bo[kc][nt][r] = (uint32)((sc * (CIN / 2) + kc * 16 + quad * 4 + r) * PPLANE) + boff[nt];

  f32x4 acc[MT][4];
#pragma unroll
  for (int mt = 0; mt < MT; ++mt)
#pragma unroll
    for (int nt = 0; nt < 4; ++nt) { f32x4 z = {0.f, 0.f, 0.f, 0.f}; acc[mt][nt] = z; }

#pragma unroll
  for (int o = 0; o < 9; ++o) {
    const int dy = o / 3, dx = o % 3;
    const int doff = (dy - 1) * PW + dx;
#pragma unroll
    for (int kc = 0; kc < KC; ++kc) {
      union { uint4 u; bf16x8 v; } Wh[MT], Wl[MT];
#pragma unroll
      for (int mt = 0; mt < MT; ++mt) {
        const uint4* wp = (const uint4*)wf + ((((o * KC + kc) * MT + mt) * 64 + lane) * 2);
        Wh[mt].u = wp[0]; Wl[mt].u = wp[1];
      }
#pragma unroll
      for (int nt = 0; nt < 4; ++nt) {
        union { uint32 u[4]; bf16x8 v; } Bh, Bl;
#pragma unroll
        for (int r = 0; r < 4; ++r) {
          uint2 w = act[bo[kc][nt][r] + doff];
          Bh.u[r] = w.x; Bl.u[r] = w.y;
        }
#pragma unroll
        for (int mt = 0; mt < MT; ++mt)
          acc[mt][nt] = __builtin_amdgcn_mfma_f32_16x16x32_bf16(Wh[mt].v, Bh.v, acc[mt][nt], 0, 0, 0);
#pragma unroll
        for (int mt = 0; mt < MT; ++mt)
          acc[mt][nt] = __builtin_amdgcn_mfma_f32_16x16x32_bf16(Wl[mt].v, Bh.v, acc[mt][nt], 0, 0, 0);
#pragma unroll
        for (int mt = 0; mt < MT; ++mt)
          acc[mt][nt] = __builtin_amdgcn_mfma_f32_16x16x32_bf16(Wh[mt].v, Bl.v, acc[mt][nt], 0, 0, 0);
      }
    }
  }

  // epilogue: D row = oc = mt*16 + quad*4 + r, col = pixel
#pragma unroll
  for (int mt = 0; mt < MT; ++mt) {
    const int ocb = mt * 16 + quad * 4;
    f32x4 bias4 = *(const f32x4*)(bias + ocb);
    f32x4 pr4, inv4;
    if (SPLIT) pr4 = *(const f32x4*)(pre + ocb);
    if (SC)    inv4 = *(const f32x4*)(scinv + ocb);
#pragma unroll
    for (int nt = 0; nt < 4; ++nt) {
      if (pix[nt] > 72899u) continue;
      const uint32 ppix = boff[nt] + 1;
      float v[4];
#pragma unroll
      for (int r = 0; r < 4; ++r) v[r] = acc[mt][nt][r] + bias4[r];
      if (SC) {
#pragma unroll
        for (int pr = 0; pr < 2; ++pr) {
          uint2 w = scact[(uint32)((sc * (COUT / 2) + (ocb >> 1) + pr) * PPLANE) + ppix];
          float h0 = __uint_as_float(w.x << 16), h1 = __uint_as_float(w.x & 0xFFFF0000u);
          float l0 = __uint_as_float(w.y << 16), l1 = __uint_as_float(w.y & 0xFFFF0000u);
          float s0 = h0 + l0, s1 = h1 + l1;
          v[2 * pr]     += (s0 >= 0.f) ? s0 : s0 * inv4[2 * pr];
          v[2 * pr + 1] += (s1 >= 0.f) ? s1 : s1 * inv4[2 * pr + 1];
        }
      }
      if (SPLIT) {
#pragma unroll
        for (int pr = 0; pr < 2; ++pr) {
          float a0 = v[2 * pr], a1 = v[2 * pr + 1];
          float t0 = fmaxf(a0, 0.f) + pr4[2 * pr] * fminf(a0, 0.f);
          float t1 = fmaxf(a1, 0.f) + pr4[2 * pr + 1] * fminf(a1, 0.f);
          uint2 wv2 = split_pack(t0, t1);
          uint2* op = actout + (size_t)((sc * (COUT / 2) + (ocb >> 1) + pr)) * PPLANE;
          store_halo_t(op, (int)px[nt], (int)py[nt], (int)ppix, wv2);
        }
      } else {
#pragma unroll
        for (int r = 0; r < 4; ++r)
          rawout[(size_t)(sc * COUT + ocb + r) * PPLANE + ppix] = v[r];
      }
    }
  }
}

// ---------------- transposed conv 5x5 32->1 ----------------
__global__ __launch_bounds__(256) void k_convT(const float* __restrict__ O, const float* __restrict__ cw,
                                               const float* __restrict__ bt, float* __restrict__ yo) {
  int p = blockIdx.x * 256 + threadIdx.x;
  if (p >= PLANE) return;
  int sc = blockIdx.y;
  int h = p / HP, w = p % HP;
  float acc = bt[0];
#pragma unroll 1
  for (int f = 0; f < 32; ++f) {
    const float* Of = O + (size_t)(sc * 32 + f) * PPLANE;
    const float* wfp = cw + f * 25;
#pragma unroll
    for (int r = 0; r < 5; ++r) {
      int ih = h + 2 - r;
      if ((unsigned)ih >= (unsigned)HP) continue;
      const float* orow = Of + (ih + 1) * PW + 1;
#pragma unroll
      for (int s = 0; s < 5; ++s) {
        int iw = w + 2 - s;
        if ((unsigned)iw < (unsigned)HP) acc += orow[iw] * wfp[r * 5 + s];
      }
    }
  }
  yo[(size_t)sc * PLANE + p] = acc;
}

// ---------------- norm projection scale ----------------
__global__ __launch_bounds__(256) void k_nrm(const float* __restrict__ yb, float* __restrict__ red) {
  int s = blockIdx.x;
  const float* ys = yb + (size_t)s * PLANE;
  float acc = 0.f;
  for (int i = threadIdx.x; i < PLANE; i += 256) { float v = ys[i]; acc += v * v; }
  float tot = blockReduceSum(acc);
  if (threadIdx.x == 0) {
    float nrm = sqrtf(tot);
    float eps = red[8 + s];
    red[16 + s] = (nrm > eps) ? eps / fmaxf(nrm, 1e-12f) : 1.0f;
  }
}

// ---------------- final: clip(z - scl*y), crop, mix ----------------
__global__ __launch_bounds__(256) void k_final(const float* __restrict__ z, const float* __restrict__ yb,
                                               const float* __restrict__ red, const float* __restrict__ mw,
                                               float* __restrict__ out) {
  int idx = blockIdx.x * 256 + threadIdx.x;
  if (idx >= 131072) return;
  int b = idx >> 16;
  int rem = idx & 65535;
  int h = rem >> 8, w = rem & 255;
  int p = (h + 7) * HP + (w + 7);
  float acc = 0.f;
#pragma unroll
  for (int d = 0; d < 4; ++d) {
    int s = b * 4 + d;
    float v = z[(size_t)s * PLANE + p] - red[16 + s] * yb[(size_t)s * PLANE + p];
    v = fminf(fmaxf(v, 0.f), 255.f);
    acc += mw[d] * v;
  }
  out[idx] = acc;
}

// =====================================================================
extern "C" void kernel_launch(void* const* d_in, const int* in_sizes, int n_in,
                              void* d_out, int out_size, void* d_ws, size_t ws_size,
                              hipStream_t stream) {
  (void)in_sizes; (void)n_in; (void)out_size; (void)ws_size;
  const float* x    = (const float*)d_in[0];
  const float* bk   = (const float*)d_in[1];
  const float* stdn = (const float*)d_in[2];
  const float* ww   = (const float*)d_in[3];
  const float* wwsc = (const float*)d_in[4];
  const float* alph = (const float*)d_in[5];
  const float* cw   = (const float*)d_in[6];
  const float* sf   = (const float*)d_in[7];
  const float* bf   = (const float*)d_in[8];
  const float* bt   = (const float*)d_in[9];
  const float* p1   = (const float*)d_in[10];
  const float* w1   = (const float*)d_in[11];
  const float* s1   = (const float*)d_in[12];
  const float* b1   = (const float*)d_in[13];
  const float* p2   = (const float*)d_in[14];
  const float* w2   = (const float*)d_in[15];
  const float* s2   = (const float*)d_in[16];
  const float* b2   = (const float*)d_in[17];
  const float* apj  = (const float*)d_in[18];
  const float* mwp  = (const float*)d_in[19];
  float* out = (float*)d_out;

  char* wsbase = (char*)d_ws;
  size_t off = 0;
  auto alloc = [&](size_t nbytes) -> char* {
    char* p = wsbase + off;
    off = (off + nbytes + 255) & ~(size_t)255;
    return p;
  };
  // ---- persistent region ----
  float*  zb  = (float*)alloc(8 * (size_t)PLANE * 4);
  float*  yb  = (float*)alloc(8 * (size_t)PLANE * 4);
  float*  red = (float*)alloc(64 * 4);
  float*  inv = (float*)alloc(32 * 4);
  float*  cwn = (float*)alloc(800 * 4);
  unsigned short* w1f = (unsigned short*)alloc(5 * 36864 * (size_t)2);  // 9*1*4*64*16
  unsigned short* w2f = (unsigned short*)alloc(5 * 36864 * (size_t)2);  // 9*2*2*64*16
  // ---- union region ----
  size_t U0 = off;
  // DFT view
  float2* tw  = (float2*)alloc(2 * (size_t)PLANE * 4);
  float*  xp  = (float*)alloc(2 * (size_t)PLANE * 4);
  float*  rtm = (float*)alloc(2 * (size_t)PLANE * 4);
  float2* cb0 = (float2*)alloc(2 * 8 * (size_t)PLANE * 8);
  float2* cb1 = (float2*)alloc(2 * 8 * (size_t)PLANE * 8);
  float2* Yb  = (float2*)alloc(2 * 2 * (size_t)PLANE * 8);
  float2* Hf  = (float2*)alloc(2 * (size_t)PLANE * 4);
  float*  Sb  = (float*)alloc((size_t)PLANE * 4);
  float2* Tb  = (float2*)alloc(2 * 4 * (size_t)PLANE * 4);
  float*  ahw = (float*)alloc(540 * 4);
  float*  wwn = (float*)alloc(600 * 4);
  // conv view (aliases the DFT view; conv phase starts after all DFT temps are dead)
  off = U0;
  uint2* act1 = (uint2*)alloc(4 * 16 * (size_t)PPLANE * 8);   // 32ch split, 4 samples; doubles as rawOb f32 4*32*PPLANE
  uint2* act2 = (uint2*)alloc(4 * 32 * (size_t)PPLANE * 8);   // 64ch split
  float* rawOb = (float*)act1;

  dim3 dft_g(5, 68, 2), dft_b(64, 4);

  // setup
  k_twiddle<<<285, 256, 0, stream>>>(tw);
  k_sympad<<<(2 * PLANE + 255) / 256, 256, 0, stream>>>(x, xp);
  k_edget<<<1, 512, 0, stream>>>(bk, ahw);
  k_Hf<<<285, 256, 0, stream>>>(bk, Hf);
  k_wnorm<<<24, 256, 0, stream>>>(ww, wwsc, wwn, 25);
  k_wnorm<<<32, 256, 0, stream>>>(cw, sf, cwn, 25);
  k_wfrag<32, 64><<<320, 256, 0, stream>>>(w1, s1, w1f);
  k_wfrag<64, 32><<<160, 256, 0, stream>>>(w2, s2, w2f);
  k_inv<<<1, 32, 0, stream>>>(p1, inv);
  k_S<<<285, 256, 0, stream>>>(wwn, Sb);
  k_T<<<(4 * PLANE + 255) / 256, 256, 0, stream>>>(Hf, Sb, alph, Tb);
  k_amp<<<4, 256, 0, stream>>>(Tb, red);
  k_eps<<<1, 64, 0, stream>>>(apj, stdn, red);

  // edgetaper
  k_row_r<<<dft_g, dft_b, 0, stream>>>(xp, cb1, tw, -1.f);
  k_col_c<<<dft_g, dft_b, 0, stream>>>(cb1, cb0, tw, -1.f, 1.f);
  k_mulHf<<<(2 * PLANE + 255) / 256, 256, 0, stream>>>(cb0, Hf, cb1);
  k_row_c<<<dft_g, dft_b, 0, stream>>>(cb1, cb0, tw, 1.f);
  k_col_r<<<dft_g, dft_b, 0, stream>>>(cb0, rtm, tw, 1.f, 1.f / (float)PLANE);
  k_taper<<<(2 * PLANE + 255) / 256, 256, 0, stream>>>(xp, rtm, ahw);

  // Y = fft2(xp)
  k_row_r<<<dft_g, dft_b, 0, stream>>>(xp, cb1, tw, -1.f);
  k_col_c<<<dft_g, dft_b, 0, stream>>>(cb1, Yb, tw, -1.f, 1.f);

  // z = ifft2(T*Y).real for all 8 (b,d)
  dim3 dft_g8(5, 68, 8);
  k_mulTY<<<(8 * PLANE + 255) / 256, 256, 0, stream>>>(Tb, Yb, cb0);
  k_row_c<<<dft_g8, dft_b, 0, stream>>>(cb0, cb1, tw, 1.f);
  k_col_r<<<dft_g8, dft_b, 0, stream>>>(cb1, zb, tw, 1.f, 1.f / (float)PLANE);

  // conv net, 2 chunks of 4 samples
  for (int c = 0; c < 2; ++c) {
    const float* zc = zb + (size_t)c * 4 * PLANE;
    float* ybc = yb + (size_t)c * 4 * PLANE;
    k_conv5<<<dim3(285, 4), 256, 0, stream>>>(zc, cwn, bf, p1 /*p1[0]*/, act1);
    for (int i = 0; i < 5; ++i) {
      // layer1: 32->64, output = prelu(p2[i]) split
      k_mconv<32, 64, false, true><<<dim3(285, 4), 256, 0, stream>>>(
          act1, w1f + (size_t)i * 36864, b1 + i * 64, p2 + i * 64, act2, nullptr, nullptr, nullptr);
      // layer2: 64->32
      if (i == 0)
        k_mconv<64, 32, true, true><<<dim3(285, 4), 256, 0, stream>>>(
            act2, w2f + (size_t)i * 36864, b2 + i * 32, p1 + (i + 1) * 32, act1, nullptr, act1, inv);
      else if (i < 4)
        k_mconv<64, 32, false, true><<<dim3(285, 4), 256, 0, stream>>>(
            act2, w2f + (size_t)i * 36864, b2 + i * 32, p1 + (i + 1) * 32, act1, nullptr, nullptr, nullptr);
      else
        k_mconv<64, 32, false, false><<<dim3(285, 4), 256, 0, stream>>>(
            act2, w2f + (size_t)i * 36864, b2 + i * 32, nullptr, nullptr, rawOb, nullptr, nullptr);
    }
    k_convT<<<dim3(285, 4), 256, 0, stream>>>(rawOb, cwn, bt, ybc);
  }

  // projection + final mix
  k_nrm<<<8, 256, 0, stream>>>(yb, red);
  k_final<<<(131072 + 255) / 256, 256, 0, stream>>>(zb, yb, red, mwp, out);
}

// Round 4
// 2582.158 us; speedup vs baseline: 2.7950x; 1.3166x over previous
//
#include <hip/hip_runtime.h>
#include <math.h>

#define HP     270
#define PLANE  72900      // 270*270
#define PW     272
#define PPLANE 73984      // 272*272

typedef unsigned int uint32;
typedef __attribute__((ext_vector_type(8))) short bf16x8;
typedef __attribute__((ext_vector_type(4))) float f32x4;

// ---------------- reduction helper ----------------
__device__ __forceinline__ float blockReduceSum(float val) {
  __shared__ float sh[16];
  int lane = threadIdx.x & 63, wid = threadIdx.x >> 6;
#pragma unroll
  for (int o = 32; o > 0; o >>= 1) val += __shfl_down(val, o, 64);
  __syncthreads();
  if (lane == 0) sh[wid] = val;
  __syncthreads();
  float tot = 0.f;
  int nw = (blockDim.x + 63) >> 6;
  for (int i = 0; i < nw; ++i) tot += sh[i];
  return tot;
}

// ---------------- twiddle matrix ----------------
__global__ __launch_bounds__(256) void k_twiddle(float2* __restrict__ tw) {
  int idx = blockIdx.x * 256 + threadIdx.x;
  if (idx >= PLANE) return;
  int j = idx / HP, k = idx % HP;
  int m = (j * k) % HP;
  double ang = (2.0 * M_PI * (double)m) / 270.0;
  tw[idx] = make_float2((float)cos(ang), (float)sin(ang));
}

// ---------------- symmetric pad x (2,256,256) -> xp (2,270,270), pad 7 ----------------
__global__ __launch_bounds__(256) void k_sympad(const float* __restrict__ x, float* __restrict__ xp) {
  int idx = blockIdx.x * 256 + threadIdx.x;
  if (idx >= 2 * PLANE) return;
  int b = idx / PLANE, p = idx % PLANE;
  int i = p / HP, j = p % HP;
  int si = i - 7; si = si < 0 ? -1 - si : (si > 255 ? 511 - si : si);
  int sj = j - 7; sj = sj < 0 ? -1 - sj : (sj > 255 ? 511 - sj : sj);
  xp[idx] = x[(b * 256 + si) * 256 + sj];
}

// ---------------- edgetaper 1D weights ----------------
__global__ __launch_bounds__(512) void k_edget(const float* __restrict__ bk, float* __restrict__ ahw) {
  __shared__ float pr[15], pc[15], acr[15], accl[15];
  int t = threadIdx.x;
  if (t < 15) {
    float sr = 0.f, scv = 0.f;
    for (int k = 0; k < 15; ++k) { sr += bk[t * 15 + k]; scv += bk[k * 15 + t]; }
    pr[t] = sr; pc[t] = scv;
  }
  __syncthreads();
  if (t < 30) {
    int l = t % 15; bool isr = (t < 15);
    const float* p = isr ? pr : pc;
    float s = 0.f;
    for (int j = 0; j + l < 15; ++j) s += p[j] * p[j + l];
    if (isr) acr[l] = s; else accl[l] = s;
  }
  __syncthreads();
  for (int i = t; i < 540; i += blockDim.x) {
    bool isr = (i < 270);
    int ii = isr ? i : i - 270;
    const float* ac = isr ? acr : accl;
    int m = (ii == 269) ? 0 : ii;
    float zv;
    if (m < 15) zv = ac[m];
    else if (m >= 255) zv = ac[269 - m];
    else zv = 0.f;
    ahw[i] = 1.f - zv / ac[0];
  }
}

// ---------------- Hf = psf2otf(blur 15x15) ----------------
__global__ __launch_bounds__(256) void k_Hf(const float* __restrict__ bk, float2* __restrict__ Hf) {
  int p = blockIdx.x * 256 + threadIdx.x;
  if (p >= PLANE) return;
  int u = p / HP, v = p % HP;
  float2 er[15], es[15];
#pragma unroll
  for (int r = 0; r < 15; ++r) {
    int m = ((u * (r - 7)) % HP + HP) % HP;
    float sn, cs;
    sincosf(2.f * (float)M_PI * (float)m / 270.f, &sn, &cs);
    er[r] = make_float2(cs, -sn);
    int m2 = ((v * (r - 7)) % HP + HP) % HP;
    sincosf(2.f * (float)M_PI * (float)m2 / 270.f, &sn, &cs);
    es[r] = make_float2(cs, -sn);
  }
  float ar = 0.f, ai = 0.f;
#pragma unroll 1
  for (int r = 0; r < 15; ++r) {
    float rr = 0.f, ri = 0.f;
#pragma unroll
    for (int s = 0; s < 15; ++s) {
      float wv = bk[r * 15 + s];
      rr += wv * es[s].x; ri += wv * es[s].y;
    }
    ar += er[r].x * rr - er[r].y * ri;
    ai += er[r].x * ri + er[r].y * rr;
  }
  Hf[p] = make_float2(ar, ai);
}

// ---------------- weight normalization, plain layout ----------------
__global__ __launch_bounds__(256) void k_wnorm(const float* __restrict__ w, const float* __restrict__ scale,
                                               float* __restrict__ out, int fsize) {
  int f = blockIdx.x;
  const float* wf = w + (size_t)f * fsize;
  float s = 0.f;
  for (int i = threadIdx.x; i < fsize; i += 256) s += wf[i];
  float mean = blockReduceSum(s) / (float)fsize;
  float s2 = 0.f;
  for (int i = threadIdx.x; i < fsize; i += 256) { float d = wf[i] - mean; s2 += d * d; }
  float nrm = sqrtf(blockReduceSum(s2));
  float sc = scale[f] / nrm;
  for (int i = threadIdx.x; i < fsize; i += 256) out[(size_t)f * fsize + i] = (wf[i] - mean) * sc;
}

// ---------------- weight normalization -> split-bf16 MFMA fragment layout ----------------
template <int CIN, int COUT>
__global__ __launch_bounds__(256) void k_wfrag(const float* __restrict__ w, const float* __restrict__ scale,
                                               unsigned short* __restrict__ outb) {
  constexpr int KC = CIN / 32, MT = COUT / 16, FS = CIN * 9;
  int fg = blockIdx.x;
  int f = fg % COUT, iter = fg / COUT;
  const float* wf = w + (size_t)fg * FS;
  float s = 0.f;
  for (int i = threadIdx.x; i < FS; i += 256) s += wf[i];
  float mean = blockReduceSum(s) / (float)FS;
  float s2 = 0.f;
  for (int i = threadIdx.x; i < FS; i += 256) { float d = wf[i] - mean; s2 += d * d; }
  float nrm = sqrtf(blockReduceSum(s2));
  float scv = scale[fg] / nrm;
  unsigned short* dst0 = outb + (size_t)iter * (9 * KC * MT * 64 * 16);
  for (int i = threadIdx.x; i < FS; i += 256) {
    float val = (wf[i] - mean) * scv;
    int ci = i / 9, rs = i - ci * 9;
    int kc = ci >> 5, cil = ci & 31, q = cil >> 3, j = cil & 7;
    int mt = f >> 4, ocl = f & 15, lane = q * 16 + ocl;
    unsigned short* d2 = dst0 + ((((rs * KC + kc) * MT + mt) * 64 + lane) * 16);
    uint32 u = __float_as_uint(val);
    d2[j] = (unsigned short)(u >> 16);
    float lof = val - __uint_as_float(u & 0xFFFF0000u);
    d2[8 + j] = (unsigned short)(__float_as_uint(lof) >> 16);
  }
}

// ---------------- S = sum_f |FT(ww_f 5x5)|^2 ----------------
__global__ __launch_bounds__(256) void k_S(const float* __restrict__ wwn, float* __restrict__ S) {
  int p = blockIdx.x * 256 + threadIdx.x;
  if (p >= PLANE) return;
  int u = p / HP, v = p % HP;
  float2 er[5], es[5];
#pragma unroll
  for (int r = 0; r < 5; ++r) {
    float sn, cs;
    int m = (u * r) % HP;
    sincosf(2.f * (float)M_PI * (float)m / 270.f, &sn, &cs);
    er[r] = make_float2(cs, -sn);
    int m2 = (v * r) % HP;
    sincosf(2.f * (float)M_PI * (float)m2 / 270.f, &sn, &cs);
    es[r] = make_float2(cs, -sn);
  }
  float prr[25], pii[25];
#pragma unroll
  for (int r = 0; r < 5; ++r)
#pragma unroll
    for (int s = 0; s < 5; ++s) {
      prr[r * 5 + s] = er[r].x * es[s].x - er[r].y * es[s].y;
      pii[r * 5 + s] = er[r].x * es[s].y + er[r].y * es[s].x;
    }
  float acc = 0.f;
#pragma unroll 1
  for (int f = 0; f < 24; ++f) {
    float xr = 0.f, xi = 0.f;
#pragma unroll
    for (int t = 0; t < 25; ++t) {
      float wv = wwn[f * 25 + t];
      xr += wv * prr[t]; xi += wv * pii[t];
    }
    acc += xr * xr + xi * xi;
  }
  S[p] = acc;
}

// ---------------- T = conj(Hf)/(|Hf|^2 + a_d S) ----------------
__global__ __launch_bounds__(256) void k_T(const float2* __restrict__ Hf, const float* __restrict__ S,
                                           const float* __restrict__ alpha, float2* __restrict__ T) {
  int idx = blockIdx.x * 256 + threadIdx.x;
  if (idx >= 4 * PLANE) return;
  int d = idx / PLANE, p = idx % PLANE;
  float a = expf(alpha[d]);
  float2 h = Hf[p];
  float den = h.x * h.x + h.y * h.y + a * S[p];
  T[idx] = make_float2(h.x / den, -h.y / den);
}

__global__ __launch_bounds__(256) void k_amp(const float2* __restrict__ T, float* __restrict__ red) {
  int d = blockIdx.x;
  const float2* Td = T + (size_t)d * PLANE;
  float acc = 0.f;
  for (int i = threadIdx.x; i < PLANE; i += 256) { float2 t = Td[i]; acc += t.x * t.x + t.y * t.y; }
  float tot = blockReduceSum(acc);
  if (threadIdx.x == 0) red[d] = tot / (float)PLANE;
}

__global__ void k_eps(const float* __restrict__ apj, const float* __restrict__ stdn, float* __restrict__ red) {
  int s = threadIdx.x;
  if (s < 8) {
    int b = s >> 2, d = s & 3;
    red[8 + s] = expf(apj[0]) * stdn[b] * sqrtf(red[d]) * sqrtf(72899.f);
  }
}

__global__ void k_inv(const float* __restrict__ p, float* __restrict__ inv) {
  int t = threadIdx.x;
  if (t < 32) inv[t] = 1.f / p[t];
}

// ---------------- register-tiled DFT passes ----------------
// row pass: out[m][r][v] = sum_w in[m][r][w] * (tw.x, sgn*tw.y)[w*270+v]
// NR rows per block; blockDim=64; grid (5, 270/NR, m)
template <int NR, bool REALIN>
__global__ __launch_bounds__(64) void k_rowT(const void* __restrict__ inv_, float2* __restrict__ out,
                                             const float2* __restrict__ tw, float sgn) {
  int v = blockIdx.x * 64 + threadIdx.x;
  int r0 = blockIdx.y * NR;
  int m = blockIdx.z;
  bool ok = v < HP;
  int vc = ok ? v : 0;
  float P[NR], R[NR], Q[NR], Sm[NR];
#pragma unroll
  for (int i = 0; i < NR; ++i) { P[i] = R[i] = 0.f; if (!REALIN) { Q[i] = Sm[i] = 0.f; } }
  const float*  inR = (const float*)inv_  + ((size_t)m * HP + r0) * HP;
  const float2* inC = (const float2*)inv_ + ((size_t)m * HP + r0) * HP;
#pragma unroll 3
  for (int w = 0; w < HP; ++w) {
    float2 t = tw[w * HP + vc];
#pragma unroll
    for (int i = 0; i < NR; ++i) {
      if (REALIN) {
        float a = inR[i * HP + w];
        P[i] += a * t.x; R[i] += a * t.y;
      } else {
        float2 g = inC[i * HP + w];
        P[i] += g.x * t.x; Q[i] += g.y * t.y;
        R[i] += g.x * t.y; Sm[i] += g.y * t.x;
      }
    }
  }
  if (ok) {
#pragma unroll
    for (int i = 0; i < NR; ++i) {
      float ar, ai;
      if (REALIN) { ar = P[i]; ai = sgn * R[i]; }
      else        { ar = P[i] - sgn * Q[i]; ai = sgn * R[i] + Sm[i]; }
      out[((size_t)m * HP + r0 + i) * HP + v] = make_float2(ar, ai);
    }
  }
}

// col pass: out[m][u][v] = sum_h in[m][h][v] * (tw.x, sgn*tw.y)[h*270+u]
template <int NU, bool REALOUT>
__global__ __launch_bounds__(64) void k_colT(const float2* __restrict__ in, void* __restrict__ outv,
                                             const float2* __restrict__ tw, float sgn, float scale) {
  int v = blockIdx.x * 64 + threadIdx.x;
  int u0 = blockIdx.y * NU;
  int m = blockIdx.z;
  bool ok = v < HP;
  int vc = ok ? v : 0;
  float P[NU], Q[NU], R[NU], Sm[NU];
#pragma unroll
  for (int j = 0; j < NU; ++j) { P[j] = Q[j] = 0.f; if (!REALOUT) { R[j] = Sm[j] = 0.f; } }
  const float2* cp = in + (size_t)m * PLANE + vc;
#pragma unroll 3
  for (int h = 0; h < HP; ++h) {
    float2 g = cp[(size_t)h * HP];
    const float2* tr = tw + h * HP + u0;
#pragma unroll
    for (int j = 0; j < NU; ++j) {
      float2 t = tr[j];
      P[j] += g.x * t.x; Q[j] += g.y * t.y;
      if (!REALOUT) { R[j] += g.x * t.y; Sm[j] += g.y * t.x; }
    }
  }
  if (ok) {
#pragma unroll
    for (int j = 0; j < NU; ++j) {
      float ar = (P[j] - sgn * Q[j]) * scale;
      if (REALOUT) ((float*)outv)[((size_t)m * HP + u0 + j) * HP + v] = ar;
      else {
        float ai = (sgn * R[j] + Sm[j]) * scale;
        ((float2*)outv)[((size_t)m * HP + u0 + j) * HP + v] = make_float2(ar, ai);
      }
    }
  }
}

// ---------------- pointwise ----------------
__global__ __launch_bounds__(256) void k_mulHf(const float2* __restrict__ in, const float2* __restrict__ Hf,
                                               float2* __restrict__ out) {
  int idx = blockIdx.x * 256 + threadIdx.x;
  if (idx >= 2 * PLANE) return;
  int p = idx % PLANE;
  float2 a = in[idx], b = Hf[p];
  out[idx] = make_float2(a.x * b.x - a.y * b.y, a.x * b.y + a.y * b.x);
}

__global__ __launch_bounds__(256) void k_taper(float* __restrict__ xp, const float* __restrict__ blr,
                                               const float* __restrict__ ahw) {
  int idx = blockIdx.x * 256 + threadIdx.x;
  if (idx >= 2 * PLANE) return;
  int p = idx % PLANE;
  int i = p / HP, j = p % HP;
  float al = ahw[i] * ahw[270 + j];
  xp[idx] = al * xp[idx] + (1.f - al) * blr[idx];
}

__global__ __launch_bounds__(256) void k_mulTY(const float2* __restrict__ T, const float2* __restrict__ Y,
                                               float2* __restrict__ out) {
  int idx = blockIdx.x * 256 + threadIdx.x;
  if (idx >= 8 * PLANE) return;
  int s = idx / PLANE, p = idx % PLANE;
  int b = s >> 2, d = s & 3;
  float2 a = T[(size_t)d * PLANE + p], y = Y[(size_t)b * PLANE + p];
  out[idx] = make_float2(a.x * y.x - a.y * y.y, a.x * y.y + a.y * y.x);
}

// ---------------- split+pack helper ----------------
__device__ __forceinline__ uint2 split_pack(float t0, float t1) {
  uint32 u0 = __float_as_uint(t0), u1 = __float_as_uint(t1);
  uint32 hiw = (u0 >> 16) | (u1 & 0xFFFF0000u);
  float r0 = t0 - __uint_as_float(u0 & 0xFFFF0000u);
  float r1 = t1 - __uint_as_float(u1 & 0xFFFF0000u);
  uint32 low = (__float_as_uint(r0) >> 16) | (__float_as_uint(r1) & 0xFFFF0000u);
  return make_uint2(hiw, low);
}

// strided halo store: pixel stride = STRIDE elements of T; o = pix*STRIDE + slot
template <typename T, int STRIDE>
__device__ __forceinline__ void store_halo_s(T* __restrict__ op, int xx, int yy, int o, T val) {
  op[o] = val;
  bool xl = (xx == 0), xr = (xx == 269), yt = (yy == 0), yb = (yy == 269);
  if (xl) op[o - STRIDE] = val;
  if (xr) op[o + STRIDE] = val;
  if (yt) { op[o - PW * STRIDE] = val; if (xl) op[o - (PW + 1) * STRIDE] = val; if (xr) op[o - (PW - 1) * STRIDE] = val; }
  if (yb) { op[o + PW * STRIDE] = val; if (xl) op[o + (PW - 1) * STRIDE] = val; if (xr) op[o + (PW + 1) * STRIDE] = val; }
}

// ---------------- first conv 5x5 1->32 -> grouped split act records ----------------
// act record layout: per (group g in CIN/8, pixel): uint4 hi{pairs 4g..4g+3}, uint4 lo
__global__ __launch_bounds__(256) void k_conv5(const float* __restrict__ z, const float* __restrict__ cw,
                                               const float* __restrict__ bias, const float* __restrict__ pre,
                                               uint4* __restrict__ actout) {
  int p = blockIdx.x * 256 + threadIdx.x;
  if (p >= PLANE) return;
  int sc = blockIdx.y;
  int i = p / HP, j = p % HP;
  const float* zs = z + (size_t)sc * PLANE;
  float v[25];
#pragma unroll
  for (int r = 0; r < 5; ++r) {
    int ii = i + r - 2; ii = ii < 0 ? -1 - ii : (ii > 269 ? 539 - ii : ii);
#pragma unroll
    for (int s = 0; s < 5; ++s) {
      int jj = j + s - 2; jj = jj < 0 ? -1 - jj : (jj > 269 ? 539 - jj : jj);
      v[r * 5 + s] = zs[ii * HP + jj];
    }
  }
  int o = (i + 1) * PW + (j + 1);
#pragma unroll 1
  for (int g = 0; g < 4; ++g) {
    float tt[8];
#pragma unroll
    for (int r8 = 0; r8 < 8; ++r8) {
      int oc = 8 * g + r8;
      float a = bias[oc];
#pragma unroll
      for (int k = 0; k < 25; ++k) a += cw[oc * 25 + k] * v[k];
      float pa = pre[oc];
      tt[r8] = fmaxf(a, 0.f) + pa * fminf(a, 0.f);
    }
    uint2 sp0 = split_pack(tt[0], tt[1]), sp1 = split_pack(tt[2], tt[3]);
    uint2 sp2 = split_pack(tt[4], tt[5]), sp3 = split_pack(tt[6], tt[7]);
    uint4 hi = make_uint4(sp0.x, sp1.x, sp2.x, sp3.x);
    uint4 lo = make_uint4(sp0.y, sp1.y, sp2.y, sp3.y);
    uint4* opb = actout + (size_t)(sc * 4 + g) * PPLANE * 2;
    store_halo_s<uint4, 2>(opb, j, i, o * 2, hi);
    store_halo_s<uint4, 2>(opb, j, i, o * 2 + 1, lo);
  }
}

// ---------------- MFMA 3x3 conv ----------------
template <int CIN, int COUT, bool SC, bool SPLIT>
__global__ __launch_bounds__(256) void k_mconv(
    const uint4* __restrict__ act, const unsigned short* __restrict__ wf,
    const float* __restrict__ bias, const float* __restrict__ pre,
    uint2* __restrict__ actout, float* __restrict__ rawout,
    const uint2* __restrict__ scact, const float* __restrict__ scinv) {
  constexpr int KC = CIN / 32, MT = COUT / 16;
  const int lane = threadIdx.x & 63, wv = threadIdx.x >> 6;
  const int quad = lane >> 4, col = lane & 15;
  const int sc = blockIdx.y;
  const int p0 = (blockIdx.x * 4 + wv) * 64;

  uint32 pix[4], py[4], px[4], boff[4];
#pragma unroll
  for (int nt = 0; nt < 4; ++nt) {
    uint32 p = p0 + nt * 16 + col;
    pix[nt] = p;
    uint32 pc = p > 72899u ? 72899u : p;
    uint32 y = pc / 270u, x = pc - y * 270u;
    py[nt] = y; px[nt] = x;
    boff[nt] = (y + 1) * PW + x;   // padded (y+1, x) = window center row, left col
  }
  uint32 bo[KC][4];
#pragma unroll
  for (int kc = 0; kc < KC; ++kc)
#pragma unroll
    for (int nt = 0; nt < 4; ++nt)
      bo[kc][nt] = ((uint32)(sc * (CIN / 8) + kc * 4 + quad) * PPLANE + boff[nt]) * 2;

  f32x4 acc[MT][4];
#pragma unroll
  for (int mt = 0; mt < MT; ++mt)
#pragma unroll
    for (int nt = 0; nt < 4; ++nt) { f32x4 z = {0.f, 0.f, 0.f, 0.f}; acc[mt][nt] = z; }

#pragma unroll
  for (int o = 0; o < 9; ++o) {
    const int dy = o / 3, dx = o % 3;
    const int doff2 = ((dy - 1) * PW + dx) * 2;
#pragma unroll
    for (int kc = 0; kc < KC; ++kc) {
      union { uint4 u; bf16x8 v; } Wh[MT], Wl[MT];
#pragma unroll
      for (int mt = 0; mt < MT; ++mt) {
        const uint4* wp = (const uint4*)wf + ((((o * KC + kc) * MT + mt) * 64 + lane) * 2);
        Wh[mt].u = wp[0]; Wl[mt].u = wp[1];
      }
#pragma unroll
      for (int nt = 0; nt < 4; ++nt) {
        union { uint4 u; bf16x8 v; } Bh, Bl;
        Bh.u = act[bo[kc][nt] + doff2];
        Bl.u = act[bo[kc][nt] + doff2 + 1];
#pragma unroll
        for (int mt = 0; mt < MT; ++mt)
          acc[mt][nt] = __builtin_amdgcn_mfma_f32_16x16x32_bf16(Wh[mt].v, Bh.v, acc[mt][nt], 0, 0, 0);
#pragma unroll
        for (int mt = 0; mt < MT; ++mt)
          acc[mt][nt] = __builtin_amdgcn_mfma_f32_16x16x32_bf16(Wl[mt].v, Bh.v, acc[mt][nt], 0, 0, 0);
#pragma unroll
        for (int mt = 0; mt < MT; ++mt)
          acc[mt][nt] = __builtin_amdgcn_mfma_f32_16x16x32_bf16(Wh[mt].v, Bl.v, acc[mt][nt], 0, 0, 0);
      }
    }
  }

  // epilogue: D row = oc = mt*16 + quad*4 + r, col = pixel
#pragma unroll
  for (int mt = 0; mt < MT; ++mt) {
    const int ocb = mt * 16 + quad * 4;
    const int g2 = 2 * mt + (quad >> 1), slot = quad & 1;
    f32x4 bias4 = *(const f32x4*)(bias + ocb);
    f32x4 pr4, inv4;
    if (SPLIT) pr4 = *(const f32x4*)(pre + ocb);
    if (SC)    inv4 = *(const f32x4*)(scinv + ocb);
#pragma unroll
    for (int nt = 0; nt < 4; ++nt) {
      if (pix[nt] > 72899u) continue;
      const uint32 ppix = boff[nt] + 1;
      float v[4];
#pragma unroll
      for (int r = 0; r < 4; ++r) v[r] = acc[mt][nt][r] + bias4[r];
      if (SC) {
        const uint2* rec = scact + ((size_t)(sc * (COUT / 8) + g2) * PPLANE + ppix) * 4;
        uint2 hi = rec[slot], lo = rec[2 + slot];
        float s0 = __uint_as_float(hi.x << 16) + __uint_as_float(lo.x << 16);
        float s1 = __uint_as_float(hi.x & 0xFFFF0000u) + __uint_as_float(lo.x & 0xFFFF0000u);
        float s2 = __uint_as_float(hi.y << 16) + __uint_as_float(lo.y << 16);
        float s3 = __uint_as_float(hi.y & 0xFFFF0000u) + __uint_as_float(lo.y & 0xFFFF0000u);
        v[0] += (s0 >= 0.f) ? s0 : s0 * inv4[0];
        v[1] += (s1 >= 0.f) ? s1 : s1 * inv4[1];
        v[2] += (s2 >= 0.f) ? s2 : s2 * inv4[2];
        v[3] += (s3 >= 0.f) ? s3 : s3 * inv4[3];
      }
      if (SPLIT) {
        float t0 = fmaxf(v[0], 0.f) + pr4[0] * fminf(v[0], 0.f);
        float t1 = fmaxf(v[1], 0.f) + pr4[1] * fminf(v[1], 0.f);
        float t2 = fmaxf(v[2], 0.f) + pr4[2] * fminf(v[2], 0.f);
        float t3 = fmaxf(v[3], 0.f) + pr4[3] * fminf(v[3], 0.f);
        uint2 sp0 = split_pack(t0, t1), sp1 = split_pack(t2, t3);
        uint2* opb = actout + (size_t)(sc * (COUT / 8) + g2) * PPLANE * 4;
        int oidx = (int)ppix * 4;
        store_halo_s<uint2, 4>(opb, (int)px[nt], (int)py[nt], oidx + slot,     make_uint2(sp0.x, sp1.x));
        store_halo_s<uint2, 4>(opb, (int)px[nt], (int)py[nt], oidx + 2 + slot, make_uint2(sp0.y, sp1.y));
      } else {
#pragma unroll
        for (int r = 0; r < 4; ++r)
          rawout[(size_t)(sc * COUT + ocb + r) * PPLANE + ppix] = v[r];
      }
    }
  }
}

// ---------------- transposed conv 5x5 32->1 ----------------
__global__ __launch_bounds__(256) void k_convT(const float* __restrict__ O, const float* __restrict__ cw,
                                               const float* __restrict__ bt, float* __restrict__ yo) {
  int p = blockIdx.x * 256 + threadIdx.x;
  if (p >= PLANE) return;
  int sc = blockIdx.y;
  int h = p / HP, w = p % HP;
  float acc = bt[0];
#pragma unroll 1
  for (int f = 0; f < 32; ++f) {
    const float* Of = O + (size_t)(sc * 32 + f) * PPLANE;
    const float* wfp = cw + f * 25;
#pragma unroll
    for (int r = 0; r < 5; ++r) {
      int ih = h + 2 - r;
      if ((unsigned)ih >= (unsigned)HP) continue;
      const float* orow = Of + (ih + 1) * PW + 1;
#pragma unroll
      for (int s = 0; s < 5; ++s) {
        int iw = w + 2 - s;
        if ((unsigned)iw < (unsigned)HP) acc += orow[iw] * wfp[r * 5 + s];
      }
    }
  }
  yo[(size_t)sc * PLANE + p] = acc;
}

// ---------------- norm projection scale ----------------
__global__ __launch_bounds__(256) void k_nrm(const float* __restrict__ yb, float* __restrict__ red) {
  int s = blockIdx.x;
  const float* ys = yb + (size_t)s * PLANE;
  float acc = 0.f;
  for (int i = threadIdx.x; i < PLANE; i += 256) { float v = ys[i]; acc += v * v; }
  float tot = blockReduceSum(acc);
  if (threadIdx.x == 0) {
    float nrm = sqrtf(tot);
    float eps = red[8 + s];
    red[16 + s] = (nrm > eps) ? eps / fmaxf(nrm, 1e-12f) : 1.0f;
  }
}

// ---------------- final: clip(z - scl*y), crop, mix ----------------
__global__ __launch_bounds__(256) void k_final(const float* __restrict__ z, const float* __restrict__ yb,
                                               const float* __restrict__ red, const float* __restrict__ mw,
                                               float* __restrict__ out) {
  int idx = blockIdx.x * 256 + threadIdx.x;
  if (idx >= 131072) return;
  int b = idx >> 16;
  int rem = idx & 65535;
  int h = rem >> 8, w = rem & 255;
  int p = (h + 7) * HP + (w + 7);
  float acc = 0.f;
#pragma unroll
  for (int d = 0; d < 4; ++d) {
    int s = b * 4 + d;
    float v = z[(size_t)s * PLANE + p] - red[16 + s] * yb[(size_t)s * PLANE + p];
    v = fminf(fmaxf(v, 0.f), 255.f);
    acc += mw[d] * v;
  }
  out[idx] = acc;
}

// =====================================================================
extern "C" void kernel_launch(void* const* d_in, const int* in_sizes, int n_in,
                              void* d_out, int out_size, void* d_ws, size_t ws_size,
                              hipStream_t stream) {
  (void)in_sizes; (void)n_in; (void)out_size; (void)ws_size;
  const float* x    = (const float*)d_in[0];
  const float* bk   = (const float*)d_in[1];
  const float* stdn = (const float*)d_in[2];
  const float* ww   = (const float*)d_in[3];
  const float* wwsc = (const float*)d_in[4];
  const float* alph = (const float*)d_in[5];
  const float* cw   = (const float*)d_in[6];
  const float* sf   = (const float*)d_in[7];
  const float* bf   = (const float*)d_in[8];
  const float* bt   = (const float*)d_in[9];
  const float* p1   = (const float*)d_in[10];
  const float* w1   = (const float*)d_in[11];
  const float* s1   = (const float*)d_in[12];
  const float* b1   = (const float*)d_in[13];
  const float* p2   = (const float*)d_in[14];
  const float* w2   = (const float*)d_in[15];
  const float* s2   = (const float*)d_in[16];
  const float* b2   = (const float*)d_in[17];
  const float* apj  = (const float*)d_in[18];
  const float* mwp  = (const float*)d_in[19];
  float* out = (float*)d_out;

  char* wsbase = (char*)d_ws;
  size_t off = 0;
  auto alloc = [&](size_t nbytes) -> char* {
    char* p = wsbase + off;
    off = (off + nbytes + 255) & ~(size_t)255;
    return p;
  };
  // ---- persistent region ----
  float*  zb  = (float*)alloc(8 * (size_t)PLANE * 4);
  float*  yb  = (float*)alloc(8 * (size_t)PLANE * 4);
  float*  red = (float*)alloc(64 * 4);
  float*  inv = (float*)alloc(32 * 4);
  float*  cwn = (float*)alloc(800 * 4);
  unsigned short* w1f = (unsigned short*)alloc(5 * 36864 * (size_t)2);
  unsigned short* w2f = (unsigned short*)alloc(5 * 36864 * (size_t)2);
  // ---- union region ----
  size_t U0 = off;
  // DFT view
  float2* tw  = (float2*)alloc(2 * (size_t)PLANE * 4);
  float*  xp  = (float*)alloc(2 * (size_t)PLANE * 4);
  float*  rtm = (float*)alloc(2 * (size_t)PLANE * 4);
  float2* cb0 = (float2*)alloc(2 * 8 * (size_t)PLANE * 8);
  float2* cb1 = (float2*)alloc(2 * 8 * (size_t)PLANE * 8);
  float2* Yb  = (float2*)alloc(2 * 2 * (size_t)PLANE * 8);
  float2* Hf  = (float2*)alloc(2 * (size_t)PLANE * 4);
  float*  Sb  = (float*)alloc((size_t)PLANE * 4);
  float2* Tb  = (float2*)alloc(2 * 4 * (size_t)PLANE * 4);
  float*  ahw = (float*)alloc(540 * 4);
  float*  wwn = (float*)alloc(600 * 4);
  // conv view (aliases the DFT view)
  off = U0;
  uint4* act1 = (uint4*)alloc(4 * 4 * (size_t)PPLANE * 32);   // 32ch: 4 groups x 32B records; aliases rawOb
  uint4* act2 = (uint4*)alloc(4 * 8 * (size_t)PPLANE * 32);   // 64ch: 8 groups
  float* rawOb = (float*)act1;

  // setup
  k_twiddle<<<285, 256, 0, stream>>>(tw);
  k_sympad<<<(2 * PLANE + 255) / 256, 256, 0, stream>>>(x, xp);
  k_edget<<<1, 512, 0, stream>>>(bk, ahw);
  k_Hf<<<285, 256, 0, stream>>>(bk, Hf);
  k_wnorm<<<24, 256, 0, stream>>>(ww, wwsc, wwn, 25);
  k_wnorm<<<32, 256, 0, stream>>>(cw, sf, cwn, 25);
  k_wfrag<32, 64><<<320, 256, 0, stream>>>(w1, s1, w1f);
  k_wfrag<64, 32><<<160, 256, 0, stream>>>(w2, s2, w2f);
  k_inv<<<1, 32, 0, stream>>>(p1, inv);
  k_S<<<285, 256, 0, stream>>>(wwn, Sb);
  k_T<<<(4 * PLANE + 255) / 256, 256, 0, stream>>>(Hf, Sb, alph, Tb);
  k_amp<<<4, 256, 0, stream>>>(Tb, red);
  k_eps<<<1, 64, 0, stream>>>(apj, stdn, red);

  dim3 g2(5, 45, 2), g8(5, 45, 8);

  // edgetaper: blurred = ifft2(fft2(xp)*Hf); xp = a*xp + (1-a)*blurred
  k_rowT<6, true ><<<g2, 64, 0, stream>>>(xp, cb1, tw, -1.f);
  k_colT<6, false><<<g2, 64, 0, stream>>>(cb1, cb0, tw, -1.f, 1.f);
  k_mulHf<<<(2 * PLANE + 255) / 256, 256, 0, stream>>>(cb0, Hf, cb1);
  k_rowT<6, false><<<g2, 64, 0, stream>>>(cb1, cb0, tw, 1.f);
  k_colT<6, true ><<<g2, 64, 0, stream>>>(cb0, rtm, tw, 1.f, 1.f / (float)PLANE);
  k_taper<<<(2 * PLANE + 255) / 256, 256, 0, stream>>>(xp, rtm, ahw);

  // Y = fft2(xp)
  k_rowT<6, true ><<<g2, 64, 0, stream>>>(xp, cb1, tw, -1.f);
  k_colT<6, false><<<g2, 64, 0, stream>>>(cb1, Yb, tw, -1.f, 1.f);

  // z = ifft2(T*Y).real for all 8 (b,d)
  k_mulTY<<<(8 * PLANE + 255) / 256, 256, 0, stream>>>(Tb, Yb, cb0);
  k_rowT<6, false><<<g8, 64, 0, stream>>>(cb0, cb1, tw, 1.f);
  k_colT<6, true ><<<g8, 64, 0, stream>>>(cb1, zb, tw, 1.f, 1.f / (float)PLANE);

  // conv net, 2 chunks of 4 samples
  for (int c = 0; c < 2; ++c) {
    const float* zc = zb + (size_t)c * 4 * PLANE;
    float* ybc = yb + (size_t)c * 4 * PLANE;
    k_conv5<<<dim3(285, 4), 256, 0, stream>>>(zc, cwn, bf, p1, act1);
    for (int i = 0; i < 5; ++i) {
      k_mconv<32, 64, false, true><<<dim3(285, 4), 256, 0, stream>>>(
          act1, w1f + (size_t)i * 36864, b1 + i * 64, p2 + i * 64, (uint2*)act2, nullptr, nullptr, nullptr);
      if (i == 0)
        k_mconv<64, 32, true, true><<<dim3(285, 4), 256, 0, stream>>>(
            act2, w2f + (size_t)i * 36864, b2 + i * 32, p1 + (i + 1) * 32, (uint2*)act1, nullptr, (const uint2*)act1, inv);
      else if (i < 4)
        k_mconv<64, 32, false, true><<<dim3(285, 4), 256, 0, stream>>>(
            act2, w2f + (size_t)i * 36864, b2 + i * 32, p1 + (i + 1) * 32, (uint2*)act1, nullptr, nullptr, nullptr);
      else
        k_mconv<64, 32, false, false><<<dim3(285, 4), 256, 0, stream>>>(
            act2, w2f + (size_t)i * 36864, b2 + i * 32, nullptr, nullptr, rawOb, nullptr, nullptr);
    }
    k_convT<<<dim3(285, 4), 256, 0, stream>>>(rawOb, cwn, bt, ybc);
  }

  // projection + final mix
  k_nrm<<<8, 256, 0, stream>>>(yb, red);
  k_final<<<(131072 + 255) / 256, 256, 0, stream>>>(zb, yb, red, mwp, out);
}

// Round 5
// 2506.026 us; speedup vs baseline: 2.8799x; 1.0304x over previous
//
#include <hip/hip_runtime.h>
#include <math.h>

#define HP     270
#define PLANE  72900      // 270*270
#define PW     272
#define PPLANE 73984      // 272*272

typedef unsigned int uint32;
typedef __attribute__((ext_vector_type(8))) short bf16x8;
typedef __attribute__((ext_vector_type(4))) float f32x4;

// ---------------- reduction helper ----------------
__device__ __forceinline__ float blockReduceSum(float val) {
  __shared__ float sh[16];
  int lane = threadIdx.x & 63, wid = threadIdx.x >> 6;
#pragma unroll
  for (int o = 32; o > 0; o >>= 1) val += __shfl_down(val, o, 64);
  __syncthreads();
  if (lane == 0) sh[wid] = val;
  __syncthreads();
  float tot = 0.f;
  int nw = (blockDim.x + 63) >> 6;
  for (int i = 0; i < nw; ++i) tot += sh[i];
  return tot;
}

// ---------------- twiddle matrix ----------------
__global__ __launch_bounds__(256) void k_twiddle(float2* __restrict__ tw) {
  int idx = blockIdx.x * 256 + threadIdx.x;
  if (idx >= PLANE) return;
  int j = idx / HP, k = idx % HP;
  int m = (j * k) % HP;
  double ang = (2.0 * M_PI * (double)m) / 270.0;
  tw[idx] = make_float2((float)cos(ang), (float)sin(ang));
}

// ---------------- symmetric pad x (2,256,256) -> xp (2,270,270), pad 7 ----------------
__global__ __launch_bounds__(256) void k_sympad(const float* __restrict__ x, float* __restrict__ xp) {
  int idx = blockIdx.x * 256 + threadIdx.x;
  if (idx >= 2 * PLANE) return;
  int b = idx / PLANE, p = idx % PLANE;
  int i = p / HP, j = p % HP;
  int si = i - 7; si = si < 0 ? -1 - si : (si > 255 ? 511 - si : si);
  int sj = j - 7; sj = sj < 0 ? -1 - sj : (sj > 255 ? 511 - sj : sj);
  xp[idx] = x[(b * 256 + si) * 256 + sj];
}

// ---------------- edgetaper 1D weights ----------------
__global__ __launch_bounds__(512) void k_edget(const float* __restrict__ bk, float* __restrict__ ahw) {
  __shared__ float pr[15], pc[15], acr[15], accl[15];
  int t = threadIdx.x;
  if (t < 15) {
    float sr = 0.f, scv = 0.f;
    for (int k = 0; k < 15; ++k) { sr += bk[t * 15 + k]; scv += bk[k * 15 + t]; }
    pr[t] = sr; pc[t] = scv;
  }
  __syncthreads();
  if (t < 30) {
    int l = t % 15; bool isr = (t < 15);
    const float* p = isr ? pr : pc;
    float s = 0.f;
    for (int j = 0; j + l < 15; ++j) s += p[j] * p[j + l];
    if (isr) acr[l] = s; else accl[l] = s;
  }
  __syncthreads();
  for (int i = t; i < 540; i += blockDim.x) {
    bool isr = (i < 270);
    int ii = isr ? i : i - 270;
    const float* ac = isr ? acr : accl;
    int m = (ii == 269) ? 0 : ii;
    float zv;
    if (m < 15) zv = ac[m];
    else if (m >= 255) zv = ac[269 - m];
    else zv = 0.f;
    ahw[i] = 1.f - zv / ac[0];
  }
}

// ---------------- Hf = psf2otf(blur 15x15) ----------------
__global__ __launch_bounds__(256) void k_Hf(const float* __restrict__ bk, float2* __restrict__ Hf) {
  int p = blockIdx.x * 256 + threadIdx.x;
  if (p >= PLANE) return;
  int u = p / HP, v = p % HP;
  float2 er[15], es[15];
#pragma unroll
  for (int r = 0; r < 15; ++r) {
    int m = ((u * (r - 7)) % HP + HP) % HP;
    float sn, cs;
    sincosf(2.f * (float)M_PI * (float)m / 270.f, &sn, &cs);
    er[r] = make_float2(cs, -sn);
    int m2 = ((v * (r - 7)) % HP + HP) % HP;
    sincosf(2.f * (float)M_PI * (float)m2 / 270.f, &sn, &cs);
    es[r] = make_float2(cs, -sn);
  }
  float ar = 0.f, ai = 0.f;
#pragma unroll 1
  for (int r = 0; r < 15; ++r) {
    float rr = 0.f, ri = 0.f;
#pragma unroll
    for (int s = 0; s < 15; ++s) {
      float wv = bk[r * 15 + s];
      rr += wv * es[s].x; ri += wv * es[s].y;
    }
    ar += er[r].x * rr - er[r].y * ri;
    ai += er[r].x * ri + er[r].y * rr;
  }
  Hf[p] = make_float2(ar, ai);
}

// ---------------- weight normalization, plain layout ----------------
__global__ __launch_bounds__(256) void k_wnorm(const float* __restrict__ w, const float* __restrict__ scale,
                                               float* __restrict__ out, int fsize) {
  int f = blockIdx.x;
  const float* wf = w + (size_t)f * fsize;
  float s = 0.f;
  for (int i = threadIdx.x; i < fsize; i += 256) s += wf[i];
  float mean = blockReduceSum(s) / (float)fsize;
  float s2 = 0.f;
  for (int i = threadIdx.x; i < fsize; i += 256) { float d = wf[i] - mean; s2 += d * d; }
  float nrm = sqrtf(blockReduceSum(s2));
  float sc = scale[f] / nrm;
  for (int i = threadIdx.x; i < fsize; i += 256) out[(size_t)f * fsize + i] = (wf[i] - mean) * sc;
}

// ---------------- transpose conv5 weights to tap-major for k_convTi ----------------
__global__ void k_wT(const float* __restrict__ cwn, float* __restrict__ wT) {
  int idx = blockIdx.x * 256 + threadIdx.x;
  if (idx >= 800) return;
  int t = idx >> 5, f = idx & 31;
  int dri = t / 5, dci = t % 5;           // input offsets dr = dri-2, dc = dci-2
  wT[t * 32 + f] = cwn[f * 25 + (4 - dri) * 5 + (4 - dci)];
}

// ---------------- weight normalization -> split-bf16 MFMA fragment layout ----------------
template <int CIN, int COUT>
__global__ __launch_bounds__(256) void k_wfrag(const float* __restrict__ w, const float* __restrict__ scale,
                                               unsigned short* __restrict__ outb) {
  constexpr int KC = CIN / 32, MT = COUT / 16, FS = CIN * 9;
  int fg = blockIdx.x;
  int f = fg % COUT, iter = fg / COUT;
  const float* wf = w + (size_t)fg * FS;
  float s = 0.f;
  for (int i = threadIdx.x; i < FS; i += 256) s += wf[i];
  float mean = blockReduceSum(s) / (float)FS;
  float s2 = 0.f;
  for (int i = threadIdx.x; i < FS; i += 256) { float d = wf[i] - mean; s2 += d * d; }
  float nrm = sqrtf(blockReduceSum(s2));
  float scv = scale[fg] / nrm;
  unsigned short* dst0 = outb + (size_t)iter * (9 * KC * MT * 64 * 16);
  for (int i = threadIdx.x; i < FS; i += 256) {
    float val = (wf[i] - mean) * scv;
    int ci = i / 9, rs = i - ci * 9;
    int kc = ci >> 5, cil = ci & 31, q = cil >> 3, j = cil & 7;
    int mt = f >> 4, ocl = f & 15, lane = q * 16 + ocl;
    unsigned short* d2 = dst0 + ((((rs * KC + kc) * MT + mt) * 64 + lane) * 16);
    uint32 u = __float_as_uint(val);
    d2[j] = (unsigned short)(u >> 16);
    float lof = val - __uint_as_float(u & 0xFFFF0000u);
    d2[8 + j] = (unsigned short)(__float_as_uint(lof) >> 16);
  }
}

// ---------------- S = sum_f |FT(ww_f 5x5)|^2 ----------------
__global__ __launch_bounds__(256) void k_S(const float* __restrict__ wwn, float* __restrict__ S) {
  int p = blockIdx.x * 256 + threadIdx.x;
  if (p >= PLANE) return;
  int u = p / HP, v = p % HP;
  float2 er[5], es[5];
#pragma unroll
  for (int r = 0; r < 5; ++r) {
    float sn, cs;
    int m = (u * r) % HP;
    sincosf(2.f * (float)M_PI * (float)m / 270.f, &sn, &cs);
    er[r] = make_float2(cs, -sn);
    int m2 = (v * r) % HP;
    sincosf(2.f * (float)M_PI * (float)m2 / 270.f, &sn, &cs);
    es[r] = make_float2(cs, -sn);
  }
  float prr[25], pii[25];
#pragma unroll
  for (int r = 0; r < 5; ++r)
#pragma unroll
    for (int s = 0; s < 5; ++s) {
      prr[r * 5 + s] = er[r].x * es[s].x - er[r].y * es[s].y;
      pii[r * 5 + s] = er[r].x * es[s].y + er[r].y * es[s].x;
    }
  float acc = 0.f;
#pragma unroll 1
  for (int f = 0; f < 24; ++f) {
    float xr = 0.f, xi = 0.f;
#pragma unroll
    for (int t = 0; t < 25; ++t) {
      float wv = wwn[f * 25 + t];
      xr += wv * prr[t]; xi += wv * pii[t];
    }
    acc += xr * xr + xi * xi;
  }
  S[p] = acc;
}

// ---------------- T = conj(Hf)/(|Hf|^2 + a_d S) ----------------
__global__ __launch_bounds__(256) void k_T(const float2* __restrict__ Hf, const float* __restrict__ S,
                                           const float* __restrict__ alpha, float2* __restrict__ T) {
  int idx = blockIdx.x * 256 + threadIdx.x;
  if (idx >= 4 * PLANE) return;
  int d = idx / PLANE, p = idx % PLANE;
  float a = expf(alpha[d]);
  float2 h = Hf[p];
  float den = h.x * h.x + h.y * h.y + a * S[p];
  T[idx] = make_float2(h.x / den, -h.y / den);
}

__global__ __launch_bounds__(256) void k_amp(const float2* __restrict__ T, float* __restrict__ red) {
  int d = blockIdx.x;
  const float2* Td = T + (size_t)d * PLANE;
  float acc = 0.f;
  for (int i = threadIdx.x; i < PLANE; i += 256) { float2 t = Td[i]; acc += t.x * t.x + t.y * t.y; }
  float tot = blockReduceSum(acc);
  if (threadIdx.x == 0) red[d] = tot / (float)PLANE;
}

__global__ void k_eps(const float* __restrict__ apj, const float* __restrict__ stdn, float* __restrict__ red) {
  int s = threadIdx.x;
  if (s < 8) {
    int b = s >> 2, d = s & 3;
    red[8 + s] = expf(apj[0]) * stdn[b] * sqrtf(red[d]) * sqrtf(72899.f);
  }
}

__global__ void k_inv(const float* __restrict__ p, float* __restrict__ inv) {
  int t = threadIdx.x;
  if (t < 32) inv[t] = 1.f / p[t];
}

// ---------------- register-tiled DFT passes ----------------
template <int NR, bool REALIN>
__global__ __launch_bounds__(64) void k_rowT(const void* __restrict__ inv_, float2* __restrict__ out,
                                             const float2* __restrict__ tw, float sgn) {
  int v = blockIdx.x * 64 + threadIdx.x;
  int r0 = blockIdx.y * NR;
  int m = blockIdx.z;
  bool ok = v < HP;
  int vc = ok ? v : 0;
  float P[NR], R[NR], Q[NR], Sm[NR];
#pragma unroll
  for (int i = 0; i < NR; ++i) { P[i] = R[i] = 0.f; if (!REALIN) { Q[i] = Sm[i] = 0.f; } }
  const float*  inR = (const float*)inv_  + ((size_t)m * HP + r0) * HP;
  const float2* inC = (const float2*)inv_ + ((size_t)m * HP + r0) * HP;
#pragma unroll 3
  for (int w = 0; w < HP; ++w) {
    float2 t = tw[w * HP + vc];
#pragma unroll
    for (int i = 0; i < NR; ++i) {
      if (REALIN) {
        float a = inR[i * HP + w];
        P[i] += a * t.x; R[i] += a * t.y;
      } else {
        float2 g = inC[i * HP + w];
        P[i] += g.x * t.x; Q[i] += g.y * t.y;
        R[i] += g.x * t.y; Sm[i] += g.y * t.x;
      }
    }
  }
  if (ok) {
#pragma unroll
    for (int i = 0; i < NR; ++i) {
      float ar, ai;
      if (REALIN) { ar = P[i]; ai = sgn * R[i]; }
      else        { ar = P[i] - sgn * Q[i]; ai = sgn * R[i] + Sm[i]; }
      out[((size_t)m * HP + r0 + i) * HP + v] = make_float2(ar, ai);
    }
  }
}

template <int NU, bool REALOUT>
__global__ __launch_bounds__(64) void k_colT(const float2* __restrict__ in, void* __restrict__ outv,
                                             const float2* __restrict__ tw, float sgn, float scale) {
  int v = blockIdx.x * 64 + threadIdx.x;
  int u0 = blockIdx.y * NU;
  int m = blockIdx.z;
  bool ok = v < HP;
  int vc = ok ? v : 0;
  float P[NU], Q[NU], R[NU], Sm[NU];
#pragma unroll
  for (int j = 0; j < NU; ++j) { P[j] = Q[j] = 0.f; if (!REALOUT) { R[j] = Sm[j] = 0.f; } }
  const float2* cp = in + (size_t)m * PLANE + vc;
#pragma unroll 3
  for (int h = 0; h < HP; ++h) {
    float2 g = cp[(size_t)h * HP];
    const float2* tr = tw + h * HP + u0;
#pragma unroll
    for (int j = 0; j < NU; ++j) {
      float2 t = tr[j];
      P[j] += g.x * t.x; Q[j] += g.y * t.y;
      if (!REALOUT) { R[j] += g.x * t.y; Sm[j] += g.y * t.x; }
    }
  }
  if (ok) {
#pragma unroll
    for (int j = 0; j < NU; ++j) {
      float ar = (P[j] - sgn * Q[j]) * scale;
      if (REALOUT) ((float*)outv)[((size_t)m * HP + u0 + j) * HP + v] = ar;
      else {
        float ai = (sgn * R[j] + Sm[j]) * scale;
        ((float2*)outv)[((size_t)m * HP + u0 + j) * HP + v] = make_float2(ar, ai);
      }
    }
  }
}

// ---------------- pointwise ----------------
__global__ __launch_bounds__(256) void k_mulHf(const float2* __restrict__ in, const float2* __restrict__ Hf,
                                               float2* __restrict__ out) {
  int idx = blockIdx.x * 256 + threadIdx.x;
  if (idx >= 2 * PLANE) return;
  int p = idx % PLANE;
  float2 a = in[idx], b = Hf[p];
  out[idx] = make_float2(a.x * b.x - a.y * b.y, a.x * b.y + a.y * b.x);
}

__global__ __launch_bounds__(256) void k_taper(float* __restrict__ xp, const float* __restrict__ blr,
                                               const float* __restrict__ ahw) {
  int idx = blockIdx.x * 256 + threadIdx.x;
  if (idx >= 2 * PLANE) return;
  int p = idx % PLANE;
  int i = p / HP, j = p % HP;
  float al = ahw[i] * ahw[270 + j];
  xp[idx] = al * xp[idx] + (1.f - al) * blr[idx];
}

__global__ __launch_bounds__(256) void k_mulTY(const float2* __restrict__ T, const float2* __restrict__ Y,
                                               float2* __restrict__ out) {
  int idx = blockIdx.x * 256 + threadIdx.x;
  if (idx >= 8 * PLANE) return;
  int s = idx / PLANE, p = idx % PLANE;
  int b = s >> 2, d = s & 3;
  float2 a = T[(size_t)d * PLANE + p], y = Y[(size_t)b * PLANE + p];
  out[idx] = make_float2(a.x * y.x - a.y * y.y, a.x * y.y + a.y * y.x);
}

// ---------------- split+pack helper ----------------
__device__ __forceinline__ uint2 split_pack(float t0, float t1) {
  uint32 u0 = __float_as_uint(t0), u1 = __float_as_uint(t1);
  uint32 hiw = (u0 >> 16) | (u1 & 0xFFFF0000u);
  float r0 = t0 - __uint_as_float(u0 & 0xFFFF0000u);
  float r1 = t1 - __uint_as_float(u1 & 0xFFFF0000u);
  uint32 low = (__float_as_uint(r0) >> 16) | (__float_as_uint(r1) & 0xFFFF0000u);
  return make_uint2(hiw, low);
}

template <typename T, int STRIDE>
__device__ __forceinline__ void store_halo_s(T* __restrict__ op, int xx, int yy, int o, T val) {
  op[o] = val;
  bool xl = (xx == 0), xr = (xx == 269), yt = (yy == 0), yb = (yy == 269);
  if (xl) op[o - STRIDE] = val;
  if (xr) op[o + STRIDE] = val;
  if (yt) { op[o - PW * STRIDE] = val; if (xl) op[o - (PW + 1) * STRIDE] = val; if (xr) op[o - (PW - 1) * STRIDE] = val; }
  if (yb) { op[o + PW * STRIDE] = val; if (xl) op[o + (PW - 1) * STRIDE] = val; if (xr) op[o + (PW + 1) * STRIDE] = val; }
}

// ---------------- first conv 5x5 1->32 -> grouped split act records ----------------
__global__ __launch_bounds__(256) void k_conv5(const float* __restrict__ z, const float* __restrict__ cw,
                                               const float* __restrict__ bias, const float* __restrict__ pre,
                                               uint4* __restrict__ actout) {
  int p = blockIdx.x * 256 + threadIdx.x;
  if (p >= PLANE) return;
  int sc = blockIdx.y;
  int i = p / HP, j = p % HP;
  const float* zs = z + (size_t)sc * PLANE;
  float v[25];
#pragma unroll
  for (int r = 0; r < 5; ++r) {
    int ii = i + r - 2; ii = ii < 0 ? -1 - ii : (ii > 269 ? 539 - ii : ii);
#pragma unroll
    for (int s = 0; s < 5; ++s) {
      int jj = j + s - 2; jj = jj < 0 ? -1 - jj : (jj > 269 ? 539 - jj : jj);
      v[r * 5 + s] = zs[ii * HP + jj];
    }
  }
  int o = (i + 1) * PW + (j + 1);
#pragma unroll 1
  for (int g = 0; g < 4; ++g) {
    float tt[8];
#pragma unroll
    for (int r8 = 0; r8 < 8; ++r8) {
      int oc = 8 * g + r8;
      float a = bias[oc];
#pragma unroll
      for (int k = 0; k < 25; ++k) a += cw[oc * 25 + k] * v[k];
      float pa = pre[oc];
      tt[r8] = fmaxf(a, 0.f) + pa * fminf(a, 0.f);
    }
    uint2 sp0 = split_pack(tt[0], tt[1]), sp1 = split_pack(tt[2], tt[3]);
    uint2 sp2 = split_pack(tt[4], tt[5]), sp3 = split_pack(tt[6], tt[7]);
    uint4 hi = make_uint4(sp0.x, sp1.x, sp2.x, sp3.x);
    uint4 lo = make_uint4(sp0.y, sp1.y, sp2.y, sp3.y);
    uint4* opb = actout + (size_t)(sc * 4 + g) * PPLANE * 2;
    store_halo_s<uint4, 2>(opb, j, i, o * 2, hi);
    store_halo_s<uint4, 2>(opb, j, i, o * 2 + 1, lo);
  }
}

// ---------------- MFMA 3x3 conv ----------------
// RAW (!SPLIT) output layout: rec[sc][y (270)][x+2 (274)][32ch] fp32, x-halo (2 cols) zeroed.
template <int CIN, int COUT, bool SC, bool SPLIT>
__global__ __launch_bounds__(256) void k_mconv(
    const uint4* __restrict__ act, const unsigned short* __restrict__ wf,
    const float* __restrict__ bias, const float* __restrict__ pre,
    uint2* __restrict__ actout, float* __restrict__ rawout,
    const uint2* __restrict__ scact, const float* __restrict__ scinv) {
  constexpr int KC = CIN / 32, MT = COUT / 16;
  const int lane = threadIdx.x & 63, wv = threadIdx.x >> 6;
  const int quad = lane >> 4, col = lane & 15;
  const int sc = blockIdx.y;
  const int p0 = (blockIdx.x * 4 + wv) * 64;

  uint32 pix[4], py[4], px[4], boff[4];
#pragma unroll
  for (int nt = 0; nt < 4; ++nt) {
    uint32 p = p0 + nt * 16 + col;
    pix[nt] = p;
    uint32 pc = p > 72899u ? 72899u : p;
    uint32 y = pc / 270u, x = pc - y * 270u;
    py[nt] = y; px[nt] = x;
    boff[nt] = (y + 1) * PW + x;
  }
  uint32 bo[KC][4];
#pragma unroll
  for (int kc = 0; kc < KC; ++kc)
#pragma unroll
    for (int nt = 0; nt < 4; ++nt)
      bo[kc][nt] = ((uint32)(sc * (CIN / 8) + kc * 4 + quad) * PPLANE + boff[nt]) * 2;

  f32x4 acc[MT][4];
#pragma unroll
  for (int mt = 0; mt < MT; ++mt)
#pragma unroll
    for (int nt = 0; nt < 4; ++nt) { f32x4 z = {0.f, 0.f, 0.f, 0.f}; acc[mt][nt] = z; }

#pragma unroll
  for (int o = 0; o < 9; ++o) {
    const int dy = o / 3, dx = o % 3;
    const int doff2 = ((dy - 1) * PW + dx) * 2;
#pragma unroll
    for (int kc = 0; kc < KC; ++kc) {
      union { uint4 u; bf16x8 v; } Wh[MT], Wl[MT];
#pragma unroll
      for (int mt = 0; mt < MT; ++mt) {
        const uint4* wp = (const uint4*)wf + ((((o * KC + kc) * MT + mt) * 64 + lane) * 2);
        Wh[mt].u = wp[0]; Wl[mt].u = wp[1];
      }
#pragma unroll
      for (int nt = 0; nt < 4; ++nt) {
        union { uint4 u; bf16x8 v; } Bh, Bl;
        Bh.u = act[bo[kc][nt] + doff2];
        Bl.u = act[bo[kc][nt] + doff2 + 1];
#pragma unroll
        for (int mt = 0; mt < MT; ++mt)
          acc[mt][nt] = __builtin_amdgcn_mfma_f32_16x16x32_bf16(Wh[mt].v, Bh.v, acc[mt][nt], 0, 0, 0);
#pragma unroll
        for (int mt = 0; mt < MT; ++mt)
          acc[mt][nt] = __builtin_amdgcn_mfma_f32_16x16x32_bf16(Wl[mt].v, Bh.v, acc[mt][nt], 0, 0, 0);
#pragma unroll
        for (int mt = 0; mt < MT; ++mt)
          acc[mt][nt] = __builtin_amdgcn_mfma_f32_16x16x32_bf16(Wh[mt].v, Bl.v, acc[mt][nt], 0, 0, 0);
      }
    }
  }

#pragma unroll
  for (int mt = 0; mt < MT; ++mt) {
    const int ocb = mt * 16 + quad * 4;
    const int g2 = 2 * mt + (quad >> 1), slot = quad & 1;
    f32x4 bias4 = *(const f32x4*)(bias + ocb);
    f32x4 pr4, inv4;
    if (SPLIT) pr4 = *(const f32x4*)(pre + ocb);
    if (SC)    inv4 = *(const f32x4*)(scinv + ocb);
#pragma unroll
    for (int nt = 0; nt < 4; ++nt) {
      if (pix[nt] > 72899u) continue;
      const uint32 ppix = boff[nt] + 1;
      float v[4];
#pragma unroll
      for (int r = 0; r < 4; ++r) v[r] = acc[mt][nt][r] + bias4[r];
      if (SC) {
        const uint2* rec = scact + ((size_t)(sc * (COUT / 8) + g2) * PPLANE + ppix) * 4;
        uint2 hi = rec[slot], lo = rec[2 + slot];
        float s0 = __uint_as_float(hi.x << 16) + __uint_as_float(lo.x << 16);
        float s1 = __uint_as_float(hi.x & 0xFFFF0000u) + __uint_as_float(lo.x & 0xFFFF0000u);
        float s2 = __uint_as_float(hi.y << 16) + __uint_as_float(lo.y << 16);
        float s3 = __uint_as_float(hi.y & 0xFFFF0000u) + __uint_as_float(lo.y & 0xFFFF0000u);
        v[0] += (s0 >= 0.f) ? s0 : s0 * inv4[0];
        v[1] += (s1 >= 0.f) ? s1 : s1 * inv4[1];
        v[2] += (s2 >= 0.f) ? s2 : s2 * inv4[2];
        v[3] += (s3 >= 0.f) ? s3 : s3 * inv4[3];
      }
      if (SPLIT) {
        float t0 = fmaxf(v[0], 0.f) + pr4[0] * fminf(v[0], 0.f);
        float t1 = fmaxf(v[1], 0.f) + pr4[1] * fminf(v[1], 0.f);
        float t2 = fmaxf(v[2], 0.f) + pr4[2] * fminf(v[2], 0.f);
        float t3 = fmaxf(v[3], 0.f) + pr4[3] * fminf(v[3], 0.f);
        uint2 sp0 = split_pack(t0, t1), sp1 = split_pack(t2, t3);
        uint2* opb = actout + (size_t)(sc * (COUT / 8) + g2) * PPLANE * 4;
        int oidx = (int)ppix * 4;
        store_halo_s<uint2, 4>(opb, (int)px[nt], (int)py[nt], oidx + slot,     make_uint2(sp0.x, sp1.x));
        store_halo_s<uint2, 4>(opb, (int)px[nt], (int)py[nt], oidx + 2 + slot, make_uint2(sp0.y, sp1.y));
      } else {
        // channel-interleaved raw output with 2-col zero halo
        size_t rec = ((size_t)(sc * 270 + (int)py[nt]) * 274 + ((int)px[nt] + 2)) * 32 + ocb;
        *(float4*)(rawout + rec) = make_float4(v[0], v[1], v[2], v[3]);
        float4 zz = make_float4(0.f, 0.f, 0.f, 0.f);
        if (px[nt] == 0u) {
          *(float4*)(rawout + rec - 32) = zz;
          *(float4*)(rawout + rec - 64) = zz;
        } else if (px[nt] == 269u) {
          *(float4*)(rawout + rec + 32) = zz;
          *(float4*)(rawout + rec + 64) = zz;
        }
      }
    }
  }
}

// ---------------- transposed conv 5x5 32->1, channel-interleaved input ----------------
__global__ __launch_bounds__(256) void k_convTi(const float* __restrict__ rawI, const float* __restrict__ wT,
                                                const float* __restrict__ bt, float* __restrict__ yo) {
  int q = blockIdx.x * 256 + threadIdx.x;
  if (q >= 270 * 68) return;
  int sc = blockIdx.y;
  int y = q / 68, xq = q - y * 68;
  int x0 = xq * 4;
  float4 acc[4];
#pragma unroll
  for (int i = 0; i < 4; ++i) acc[i] = make_float4(0.f, 0.f, 0.f, 0.f);
#pragma unroll
  for (int dr = -2; dr <= 2; ++dr) {
    int iy = y + dr;
    if ((unsigned)iy >= 270u) continue;
    const float* rowp = rawI + ((size_t)(sc * 270 + iy) * 274 + x0) * 32;
    const float* wrow = wT + (dr + 2) * 5 * 32;
#pragma unroll
    for (int g = 0; g < 8; ++g) {
      float4 c[8];
#pragma unroll
      for (int k = 0; k < 8; ++k) c[k] = *(const float4*)(rowp + k * 32 + g * 4);
#pragma unroll
      for (int dc = 0; dc < 5; ++dc) {
        float4 w4 = *(const float4*)(wrow + dc * 32 + g * 4);
#pragma unroll
        for (int i = 0; i < 4; ++i) {
          float4 cv = c[i + dc];
          acc[i].x += cv.x * w4.x; acc[i].y += cv.y * w4.y;
          acc[i].z += cv.z * w4.z; acc[i].w += cv.w * w4.w;
        }
      }
    }
  }
  float b0 = bt[0];
#pragma unroll
  for (int i = 0; i < 4; ++i) {
    int xx = x0 + i;
    if (xx < 270)
      yo[(size_t)sc * PLANE + y * 270 + xx] = b0 + acc[i].x + acc[i].y + acc[i].z + acc[i].w;
  }
}

// ---------------- norm projection scale ----------------
__global__ __launch_bounds__(256) void k_nrm(const float* __restrict__ yb, float* __restrict__ red) {
  int s = blockIdx.x;
  const float* ys = yb + (size_t)s * PLANE;
  float acc = 0.f;
  for (int i = threadIdx.x; i < PLANE; i += 256) { float v = ys[i]; acc += v * v; }
  float tot = blockReduceSum(acc);
  if (threadIdx.x == 0) {
    float nrm = sqrtf(tot);
    float eps = red[8 + s];
    red[16 + s] = (nrm > eps) ? eps / fmaxf(nrm, 1e-12f) : 1.0f;
  }
}

// ---------------- final: clip(z - scl*y), crop, mix ----------------
__global__ __launch_bounds__(256) void k_final(const float* __restrict__ z, const float* __restrict__ yb,
                                               const float* __restrict__ red, const float* __restrict__ mw,
                                               float* __restrict__ out) {
  int idx = blockIdx.x * 256 + threadIdx.x;
  if (idx >= 131072) return;
  int b = idx >> 16;
  int rem = idx & 65535;
  int h = rem >> 8, w = rem & 255;
  int p = (h + 7) * HP + (w + 7);
  float acc = 0.f;
#pragma unroll
  for (int d = 0; d < 4; ++d) {
    int s = b * 4 + d;
    float v = z[(size_t)s * PLANE + p] - red[16 + s] * yb[(size_t)s * PLANE + p];
    v = fminf(fmaxf(v, 0.f), 255.f);
    acc += mw[d] * v;
  }
  out[idx] = acc;
}

// =====================================================================
extern "C" void kernel_launch(void* const* d_in, const int* in_sizes, int n_in,
                              void* d_out, int out_size, void* d_ws, size_t ws_size,
                              hipStream_t stream) {
  (void)in_sizes; (void)n_in; (void)out_size; (void)ws_size;
  const float* x    = (const float*)d_in[0];
  const float* bk   = (const float*)d_in[1];
  const float* stdn = (const float*)d_in[2];
  const float* ww   = (const float*)d_in[3];
  const float* wwsc = (const float*)d_in[4];
  const float* alph = (const float*)d_in[5];
  const float* cw   = (const float*)d_in[6];
  const float* sf   = (const float*)d_in[7];
  const float* bf   = (const float*)d_in[8];
  const float* bt   = (const float*)d_in[9];
  const float* p1   = (const float*)d_in[10];
  const float* w1   = (const float*)d_in[11];
  const float* s1   = (const float*)d_in[12];
  const float* b1   = (const float*)d_in[13];
  const float* p2   = (const float*)d_in[14];
  const float* w2   = (const float*)d_in[15];
  const float* s2   = (const float*)d_in[16];
  const float* b2   = (const float*)d_in[17];
  const float* apj  = (const float*)d_in[18];
  const float* mwp  = (const float*)d_in[19];
  float* out = (float*)d_out;

  char* wsbase = (char*)d_ws;
  size_t off = 0;
  auto alloc = [&](size_t nbytes) -> char* {
    char* p = wsbase + off;
    off = (off + nbytes + 255) & ~(size_t)255;
    return p;
  };
  // ---- persistent region ----
  float*  zb  = (float*)alloc(8 * (size_t)PLANE * 4);
  float*  yb  = (float*)alloc(8 * (size_t)PLANE * 4);
  float*  red = (float*)alloc(64 * 4);
  float*  inv = (float*)alloc(32 * 4);
  float*  cwn = (float*)alloc(800 * 4);
  float*  wTt = (float*)alloc(800 * 4);
  unsigned short* w1f = (unsigned short*)alloc(5 * 36864 * (size_t)2);
  unsigned short* w2f = (unsigned short*)alloc(5 * 36864 * (size_t)2);
  // ---- union region ----
  size_t U0 = off;
  // DFT view
  float2* tw  = (float2*)alloc(2 * (size_t)PLANE * 4);
  float*  xp  = (float*)alloc(2 * (size_t)PLANE * 4);
  float*  rtm = (float*)alloc(2 * (size_t)PLANE * 4);
  float2* cb0 = (float2*)alloc(2 * 8 * (size_t)PLANE * 8);
  float2* cb1 = (float2*)alloc(2 * 8 * (size_t)PLANE * 8);
  float2* Yb  = (float2*)alloc(2 * 2 * (size_t)PLANE * 8);
  float2* Hf  = (float2*)alloc(2 * (size_t)PLANE * 4);
  float*  Sb  = (float*)alloc((size_t)PLANE * 4);
  float2* Tb  = (float2*)alloc(2 * 4 * (size_t)PLANE * 4);
  float*  ahw = (float*)alloc(540 * 4);
  float*  wwn = (float*)alloc(600 * 4);
  // conv view (aliases the DFT view)
  off = U0;
  uint4* act1 = (uint4*)alloc(4 * 4 * (size_t)PPLANE * 32);   // 32ch split acts; also aliases rawOb (4*270*274*32 f32)
  uint4* act2 = (uint4*)alloc(4 * 8 * (size_t)PPLANE * 32);   // 64ch split acts
  float* rawOb = (float*)act1;

  // setup
  k_twiddle<<<285, 256, 0, stream>>>(tw);
  k_sympad<<<(2 * PLANE + 255) / 256, 256, 0, stream>>>(x, xp);
  k_edget<<<1, 512, 0, stream>>>(bk, ahw);
  k_Hf<<<285, 256, 0, stream>>>(bk, Hf);
  k_wnorm<<<24, 256, 0, stream>>>(ww, wwsc, wwn, 25);
  k_wnorm<<<32, 256, 0, stream>>>(cw, sf, cwn, 25);
  k_wT<<<4, 256, 0, stream>>>(cwn, wTt);
  k_wfrag<32, 64><<<320, 256, 0, stream>>>(w1, s1, w1f);
  k_wfrag<64, 32><<<160, 256, 0, stream>>>(w2, s2, w2f);
  k_inv<<<1, 32, 0, stream>>>(p1, inv);
  k_S<<<285, 256, 0, stream>>>(wwn, Sb);
  k_T<<<(4 * PLANE + 255) / 256, 256, 0, stream>>>(Hf, Sb, alph, Tb);
  k_amp<<<4, 256, 0, stream>>>(Tb, red);
  k_eps<<<1, 64, 0, stream>>>(apj, stdn, red);

  dim3 g2(5, 45, 2), g8(5, 45, 8);

  // edgetaper
  k_rowT<6, true ><<<g2, 64, 0, stream>>>(xp, cb1, tw, -1.f);
  k_colT<6, false><<<g2, 64, 0, stream>>>(cb1, cb0, tw, -1.f, 1.f);
  k_mulHf<<<(2 * PLANE + 255) / 256, 256, 0, stream>>>(cb0, Hf, cb1);
  k_rowT<6, false><<<g2, 64, 0, stream>>>(cb1, cb0, tw, 1.f);
  k_colT<6, true ><<<g2, 64, 0, stream>>>(cb0, rtm, tw, 1.f, 1.f / (float)PLANE);
  k_taper<<<(2 * PLANE + 255) / 256, 256, 0, stream>>>(xp, rtm, ahw);

  // Y = fft2(xp)
  k_rowT<6, true ><<<g2, 64, 0, stream>>>(xp, cb1, tw, -1.f);
  k_colT<6, false><<<g2, 64, 0, stream>>>(cb1, Yb, tw, -1.f, 1.f);

  // z = ifft2(T*Y).real for all 8 (b,d)
  k_mulTY<<<(8 * PLANE + 255) / 256, 256, 0, stream>>>(Tb, Yb, cb0);
  k_rowT<6, false><<<g8, 64, 0, stream>>>(cb0, cb1, tw, 1.f);
  k_colT<6, true ><<<g8, 64, 0, stream>>>(cb1, zb, tw, 1.f, 1.f / (float)PLANE);

  // conv net, 2 chunks of 4 samples
  for (int c = 0; c < 2; ++c) {
    const float* zc = zb + (size_t)c * 4 * PLANE;
    float* ybc = yb + (size_t)c * 4 * PLANE;
    k_conv5<<<dim3(285, 4), 256, 0, stream>>>(zc, cwn, bf, p1, act1);
    for (int i = 0; i < 5; ++i) {
      k_mconv<32, 64, false, true><<<dim3(285, 4), 256, 0, stream>>>(
          act1, w1f + (size_t)i * 36864, b1 + i * 64, p2 + i * 64, (uint2*)act2, nullptr, nullptr, nullptr);
      if (i == 0)
        k_mconv<64, 32, true, true><<<dim3(285, 4), 256, 0, stream>>>(
            act2, w2f + (size_t)i * 36864, b2 + i * 32, p1 + (i + 1) * 32, (uint2*)act1, nullptr, (const uint2*)act1, inv);
      else if (i < 4)
        k_mconv<64, 32, false, true><<<dim3(285, 4), 256, 0, stream>>>(
            act2, w2f + (size_t)i * 36864, b2 + i * 32, p1 + (i + 1) * 32, (uint2*)act1, nullptr, nullptr, nullptr);
      else
        k_mconv<64, 32, false, false><<<dim3(285, 4), 256, 0, stream>>>(
            act2, w2f + (size_t)i * 36864, b2 + i * 32, nullptr, nullptr, rawOb, nullptr, nullptr);
    }
    k_convTi<<<dim3(72, 4), 256, 0, stream>>>(rawOb, wTt, bt, ybc);
  }

  // projection + final mix
  k_nrm<<<8, 256, 0, stream>>>(yb, red);
  k_final<<<(131072 + 255) / 256, 256, 0, stream>>>(zb, yb, red, mwp, out);
}

// Round 6
// 2237.042 us; speedup vs baseline: 3.2262x; 1.1202x over previous
//
#include <hip/hip_runtime.h>
#include <math.h>

#define HP     270
#define PLANE  72900      // 270*270
#define PW     272
#define PPLANE 73984      // 272*272

typedef unsigned int uint32;
typedef __attribute__((ext_vector_type(8))) short bf16x8;
typedef __attribute__((ext_vector_type(4))) float f32x4;

// ---------------- reduction helper ----------------
__device__ __forceinline__ float blockReduceSum(float val) {
  __shared__ float sh[16];
  int lane = threadIdx.x & 63, wid = threadIdx.x >> 6;
#pragma unroll
  for (int o = 32; o > 0; o >>= 1) val += __shfl_down(val, o, 64);
  __syncthreads();
  if (lane == 0) sh[wid] = val;
  __syncthreads();
  float tot = 0.f;
  int nw = (blockDim.x + 63) >> 6;
  for (int i = 0; i < nw; ++i) tot += sh[i];
  return tot;
}

// ---------------- twiddle matrix ----------------
__global__ __launch_bounds__(256) void k_twiddle(float2* __restrict__ tw) {
  int idx = blockIdx.x * 256 + threadIdx.x;
  if (idx >= PLANE) return;
  int j = idx / HP, k = idx % HP;
  int m = (j * k) % HP;
  double ang = (2.0 * M_PI * (double)m) / 270.0;
  tw[idx] = make_float2((float)cos(ang), (float)sin(ang));
}

// ---------------- symmetric pad x (2,256,256) -> xp (2,270,270), pad 7 ----------------
__global__ __launch_bounds__(256) void k_sympad(const float* __restrict__ x, float* __restrict__ xp) {
  int idx = blockIdx.x * 256 + threadIdx.x;
  if (idx >= 2 * PLANE) return;
  int b = idx / PLANE, p = idx % PLANE;
  int i = p / HP, j = p % HP;
  int si = i - 7; si = si < 0 ? -1 - si : (si > 255 ? 511 - si : si);
  int sj = j - 7; sj = sj < 0 ? -1 - sj : (sj > 255 ? 511 - sj : sj);
  xp[idx] = x[(b * 256 + si) * 256 + sj];
}

// ---------------- edgetaper 1D weights ----------------
__global__ __launch_bounds__(512) void k_edget(const float* __restrict__ bk, float* __restrict__ ahw) {
  __shared__ float pr[15], pc[15], acr[15], accl[15];
  int t = threadIdx.x;
  if (t < 15) {
    float sr = 0.f, scv = 0.f;
    for (int k = 0; k < 15; ++k) { sr += bk[t * 15 + k]; scv += bk[k * 15 + t]; }
    pr[t] = sr; pc[t] = scv;
  }
  __syncthreads();
  if (t < 30) {
    int l = t % 15; bool isr = (t < 15);
    const float* p = isr ? pr : pc;
    float s = 0.f;
    for (int j = 0; j + l < 15; ++j) s += p[j] * p[j + l];
    if (isr) acr[l] = s; else accl[l] = s;
  }
  __syncthreads();
  for (int i = t; i < 540; i += blockDim.x) {
    bool isr = (i < 270);
    int ii = isr ? i : i - 270;
    const float* ac = isr ? acr : accl;
    int m = (ii == 269) ? 0 : ii;
    float zv;
    if (m < 15) zv = ac[m];
    else if (m >= 255) zv = ac[269 - m];
    else zv = 0.f;
    ahw[i] = 1.f - zv / ac[0];
  }
}

// ---------------- Hf = psf2otf(blur 15x15) ----------------
__global__ __launch_bounds__(256) void k_Hf(const float* __restrict__ bk, float2* __restrict__ Hf) {
  int p = blockIdx.x * 256 + threadIdx.x;
  if (p >= PLANE) return;
  int u = p / HP, v = p % HP;
  float2 er[15], es[15];
#pragma unroll
  for (int r = 0; r < 15; ++r) {
    int m = ((u * (r - 7)) % HP + HP) % HP;
    float sn, cs;
    sincosf(2.f * (float)M_PI * (float)m / 270.f, &sn, &cs);
    er[r] = make_float2(cs, -sn);
    int m2 = ((v * (r - 7)) % HP + HP) % HP;
    sincosf(2.f * (float)M_PI * (float)m2 / 270.f, &sn, &cs);
    es[r] = make_float2(cs, -sn);
  }
  float ar = 0.f, ai = 0.f;
#pragma unroll 1
  for (int r = 0; r < 15; ++r) {
    float rr = 0.f, ri = 0.f;
#pragma unroll
    for (int s = 0; s < 15; ++s) {
      float wv = bk[r * 15 + s];
      rr += wv * es[s].x; ri += wv * es[s].y;
    }
    ar += er[r].x * rr - er[r].y * ri;
    ai += er[r].x * ri + er[r].y * rr;
  }
  Hf[p] = make_float2(ar, ai);
}

// ---------------- weight normalization, plain layout ----------------
__global__ __launch_bounds__(256) void k_wnorm(const float* __restrict__ w, const float* __restrict__ scale,
                                               float* __restrict__ out, int fsize) {
  int f = blockIdx.x;
  const float* wf = w + (size_t)f * fsize;
  float s = 0.f;
  for (int i = threadIdx.x; i < fsize; i += 256) s += wf[i];
  float mean = blockReduceSum(s) / (float)fsize;
  float s2 = 0.f;
  for (int i = threadIdx.x; i < fsize; i += 256) { float d = wf[i] - mean; s2 += d * d; }
  float nrm = sqrtf(blockReduceSum(s2));
  float sc = scale[f] / nrm;
  for (int i = threadIdx.x; i < fsize; i += 256) out[(size_t)f * fsize + i] = (wf[i] - mean) * sc;
}

// ---------------- transpose conv5 weights to tap-major (flipped) ----------------
__global__ void k_wT(const float* __restrict__ cwn, float* __restrict__ wT) {
  int idx = blockIdx.x * 256 + threadIdx.x;
  if (idx >= 800) return;
  int t = idx >> 5, f = idx & 31;
  int dri = t / 5, dci = t % 5;           // input offsets dr = dri-2, dc = dci-2
  wT[t * 32 + f] = cwn[f * 25 + (4 - dri) * 5 + (4 - dci)];
}

// ---------------- weight normalization -> split-bf16 MFMA fragment layout ----------------
template <int CIN, int COUT>
__global__ __launch_bounds__(256) void k_wfrag(const float* __restrict__ w, const float* __restrict__ scale,
                                               unsigned short* __restrict__ outb) {
  constexpr int KC = CIN / 32, MT = COUT / 16, FS = CIN * 9;
  int fg = blockIdx.x;
  int f = fg % COUT, iter = fg / COUT;
  const float* wf = w + (size_t)fg * FS;
  float s = 0.f;
  for (int i = threadIdx.x; i < FS; i += 256) s += wf[i];
  float mean = blockReduceSum(s) / (float)FS;
  float s2 = 0.f;
  for (int i = threadIdx.x; i < FS; i += 256) { float d = wf[i] - mean; s2 += d * d; }
  float nrm = sqrtf(blockReduceSum(s2));
  float scv = scale[fg] / nrm;
  unsigned short* dst0 = outb + (size_t)iter * (9 * KC * MT * 64 * 16);
  for (int i = threadIdx.x; i < FS; i += 256) {
    float val = (wf[i] - mean) * scv;
    int ci = i / 9, rs = i - ci * 9;
    int kc = ci >> 5, cil = ci & 31, q = cil >> 3, j = cil & 7;
    int mt = f >> 4, ocl = f & 15, lane = q * 16 + ocl;
    unsigned short* d2 = dst0 + ((((rs * KC + kc) * MT + mt) * 64 + lane) * 16);
    uint32 u = __float_as_uint(val);
    d2[j] = (unsigned short)(u >> 16);
    float lof = val - __uint_as_float(u & 0xFFFF0000u);
    d2[8 + j] = (unsigned short)(__float_as_uint(lof) >> 16);
  }
}

// ---------------- S = sum_f |FT(ww_f 5x5)|^2 ----------------
__global__ __launch_bounds__(256) void k_S(const float* __restrict__ wwn, float* __restrict__ S) {
  int p = blockIdx.x * 256 + threadIdx.x;
  if (p >= PLANE) return;
  int u = p / HP, v = p % HP;
  float2 er[5], es[5];
#pragma unroll
  for (int r = 0; r < 5; ++r) {
    float sn, cs;
    int m = (u * r) % HP;
    sincosf(2.f * (float)M_PI * (float)m / 270.f, &sn, &cs);
    er[r] = make_float2(cs, -sn);
    int m2 = (v * r) % HP;
    sincosf(2.f * (float)M_PI * (float)m2 / 270.f, &sn, &cs);
    es[r] = make_float2(cs, -sn);
  }
  float prr[25], pii[25];
#pragma unroll
  for (int r = 0; r < 5; ++r)
#pragma unroll
    for (int s = 0; s < 5; ++s) {
      prr[r * 5 + s] = er[r].x * es[s].x - er[r].y * es[s].y;
      pii[r * 5 + s] = er[r].x * es[s].y + er[r].y * es[s].x;
    }
  float acc = 0.f;
#pragma unroll 1
  for (int f = 0; f < 24; ++f) {
    float xr = 0.f, xi = 0.f;
#pragma unroll
    for (int t = 0; t < 25; ++t) {
      float wv = wwn[f * 25 + t];
      xr += wv * prr[t]; xi += wv * pii[t];
    }
    acc += xr * xr + xi * xi;
  }
  S[p] = acc;
}

// ---------------- T = conj(Hf)/(|Hf|^2 + a_d S) ----------------
__global__ __launch_bounds__(256) void k_T(const float2* __restrict__ Hf, const float* __restrict__ S,
                                           const float* __restrict__ alpha, float2* __restrict__ T) {
  int idx = blockIdx.x * 256 + threadIdx.x;
  if (idx >= 4 * PLANE) return;
  int d = idx / PLANE, p = idx % PLANE;
  float a = expf(alpha[d]);
  float2 h = Hf[p];
  float den = h.x * h.x + h.y * h.y + a * S[p];
  T[idx] = make_float2(h.x / den, -h.y / den);
}

__global__ __launch_bounds__(256) void k_amp(const float2* __restrict__ T, float* __restrict__ red) {
  int d = blockIdx.x;
  const float2* Td = T + (size_t)d * PLANE;
  float acc = 0.f;
  for (int i = threadIdx.x; i < PLANE; i += 256) { float2 t = Td[i]; acc += t.x * t.x + t.y * t.y; }
  float tot = blockReduceSum(acc);
  if (threadIdx.x == 0) red[d] = tot / (float)PLANE;
}

__global__ void k_eps(const float* __restrict__ apj, const float* __restrict__ stdn, float* __restrict__ red) {
  int s = threadIdx.x;
  if (s < 8) {
    int b = s >> 2, d = s & 3;
    red[8 + s] = expf(apj[0]) * stdn[b] * sqrtf(red[d]) * sqrtf(72899.f);
  }
}

__global__ void k_inv(const float* __restrict__ p, float* __restrict__ inv) {
  int t = threadIdx.x;
  if (t < 32) inv[t] = 1.f / p[t];
}

// ---------------- register-tiled DFT passes ----------------
template <int NR, bool REALIN>
__global__ __launch_bounds__(64) void k_rowT(const void* __restrict__ inv_, float2* __restrict__ out,
                                             const float2* __restrict__ tw, float sgn) {
  int v = blockIdx.x * 64 + threadIdx.x;
  int r0 = blockIdx.y * NR;
  int m = blockIdx.z;
  bool ok = v < HP;
  int vc = ok ? v : 0;
  float P[NR], R[NR], Q[NR], Sm[NR];
#pragma unroll
  for (int i = 0; i < NR; ++i) { P[i] = R[i] = 0.f; if (!REALIN) { Q[i] = Sm[i] = 0.f; } }
  const float*  inR = (const float*)inv_  + ((size_t)m * HP + r0) * HP;
  const float2* inC = (const float2*)inv_ + ((size_t)m * HP + r0) * HP;
#pragma unroll 3
  for (int w = 0; w < HP; ++w) {
    float2 t = tw[w * HP + vc];
#pragma unroll
    for (int i = 0; i < NR; ++i) {
      if (REALIN) {
        float a = inR[i * HP + w];
        P[i] += a * t.x; R[i] += a * t.y;
      } else {
        float2 g = inC[i * HP + w];
        P[i] += g.x * t.x; Q[i] += g.y * t.y;
        R[i] += g.x * t.y; Sm[i] += g.y * t.x;
      }
    }
  }
  if (ok) {
#pragma unroll
    for (int i = 0; i < NR; ++i) {
      float ar, ai;
      if (REALIN) { ar = P[i]; ai = sgn * R[i]; }
      else        { ar = P[i] - sgn * Q[i]; ai = sgn * R[i] + Sm[i]; }
      out[((size_t)m * HP + r0 + i) * HP + v] = make_float2(ar, ai);
    }
  }
}

template <int NU, bool REALOUT>
__global__ __launch_bounds__(64) void k_colT(const float2* __restrict__ in, void* __restrict__ outv,
                                             const float2* __restrict__ tw, float sgn, float scale) {
  int v = blockIdx.x * 64 + threadIdx.x;
  int u0 = blockIdx.y * NU;
  int m = blockIdx.z;
  bool ok = v < HP;
  int vc = ok ? v : 0;
  float P[NU], Q[NU], R[NU], Sm[NU];
#pragma unroll
  for (int j = 0; j < NU; ++j) { P[j] = Q[j] = 0.f; if (!REALOUT) { R[j] = Sm[j] = 0.f; } }
  const float2* cp = in + (size_t)m * PLANE + vc;
#pragma unroll 3
  for (int h = 0; h < HP; ++h) {
    float2 g = cp[(size_t)h * HP];
    const float2* tr = tw + h * HP + u0;
#pragma unroll
    for (int j = 0; j < NU; ++j) {
      float2 t = tr[j];
      P[j] += g.x * t.x; Q[j] += g.y * t.y;
      if (!REALOUT) { R[j] += g.x * t.y; Sm[j] += g.y * t.x; }
    }
  }
  if (ok) {
#pragma unroll
    for (int j = 0; j < NU; ++j) {
      float ar = (P[j] - sgn * Q[j]) * scale;
      if (REALOUT) ((float*)outv)[((size_t)m * HP + u0 + j) * HP + v] = ar;
      else {
        float ai = (sgn * R[j] + Sm[j]) * scale;
        ((float2*)outv)[((size_t)m * HP + u0 + j) * HP + v] = make_float2(ar, ai);
      }
    }
  }
}

// ---------------- pointwise ----------------
__global__ __launch_bounds__(256) void k_mulHf(const float2* __restrict__ in, const float2* __restrict__ Hf,
                                               float2* __restrict__ out) {
  int idx = blockIdx.x * 256 + threadIdx.x;
  if (idx >= 2 * PLANE) return;
  int p = idx % PLANE;
  float2 a = in[idx], b = Hf[p];
  out[idx] = make_float2(a.x * b.x - a.y * b.y, a.x * b.y + a.y * b.x);
}

__global__ __launch_bounds__(256) void k_taper(float* __restrict__ xp, const float* __restrict__ blr,
                                               const float* __restrict__ ahw) {
  int idx = blockIdx.x * 256 + threadIdx.x;
  if (idx >= 2 * PLANE) return;
  int p = idx % PLANE;
  int i = p / HP, j = p % HP;
  float al = ahw[i] * ahw[270 + j];
  xp[idx] = al * xp[idx] + (1.f - al) * blr[idx];
}

__global__ __launch_bounds__(256) void k_mulTY(const float2* __restrict__ T, const float2* __restrict__ Y,
                                               float2* __restrict__ out) {
  int idx = blockIdx.x * 256 + threadIdx.x;
  if (idx >= 8 * PLANE) return;
  int s = idx / PLANE, p = idx % PLANE;
  int b = s >> 2, d = s & 3;
  float2 a = T[(size_t)d * PLANE + p], y = Y[(size_t)b * PLANE + p];
  out[idx] = make_float2(a.x * y.x - a.y * y.y, a.x * y.y + a.y * y.x);
}

// ---------------- split+pack helper ----------------
__device__ __forceinline__ uint2 split_pack(float t0, float t1) {
  uint32 u0 = __float_as_uint(t0), u1 = __float_as_uint(t1);
  uint32 hiw = (u0 >> 16) | (u1 & 0xFFFF0000u);
  float r0 = t0 - __uint_as_float(u0 & 0xFFFF0000u);
  float r1 = t1 - __uint_as_float(u1 & 0xFFFF0000u);
  uint32 low = (__float_as_uint(r0) >> 16) | (__float_as_uint(r1) & 0xFFFF0000u);
  return make_uint2(hiw, low);
}

template <typename T, int STRIDE>
__device__ __forceinline__ void store_halo_s(T* __restrict__ op, int xx, int yy, int o, T val) {
  op[o] = val;
  bool xl = (xx == 0), xr = (xx == 269), yt = (yy == 0), yb = (yy == 269);
  if (xl) op[o - STRIDE] = val;
  if (xr) op[o + STRIDE] = val;
  if (yt) { op[o - PW * STRIDE] = val; if (xl) op[o - (PW + 1) * STRIDE] = val; if (xr) op[o - (PW - 1) * STRIDE] = val; }
  if (yb) { op[o + PW * STRIDE] = val; if (xl) op[o + (PW - 1) * STRIDE] = val; if (xr) op[o + (PW + 1) * STRIDE] = val; }
}

// ---------------- first conv 5x5 1->32 -> grouped split act records ----------------
__global__ __launch_bounds__(256) void k_conv5(const float* __restrict__ z, const float* __restrict__ cw,
                                               const float* __restrict__ bias, const float* __restrict__ pre,
                                               uint4* __restrict__ actout) {
  int p = blockIdx.x * 256 + threadIdx.x;
  if (p >= PLANE) return;
  int sc = blockIdx.y;
  int i = p / HP, j = p % HP;
  const float* zs = z + (size_t)sc * PLANE;
  float v[25];
#pragma unroll
  for (int r = 0; r < 5; ++r) {
    int ii = i + r - 2; ii = ii < 0 ? -1 - ii : (ii > 269 ? 539 - ii : ii);
#pragma unroll
    for (int s = 0; s < 5; ++s) {
      int jj = j + s - 2; jj = jj < 0 ? -1 - jj : (jj > 269 ? 539 - jj : jj);
      v[r * 5 + s] = zs[ii * HP + jj];
    }
  }
  int o = (i + 1) * PW + (j + 1);
#pragma unroll 1
  for (int g = 0; g < 4; ++g) {
    float tt[8];
#pragma unroll
    for (int r8 = 0; r8 < 8; ++r8) {
      int oc = 8 * g + r8;
      float a = bias[oc];
#pragma unroll
      for (int k = 0; k < 25; ++k) a += cw[oc * 25 + k] * v[k];
      float pa = pre[oc];
      tt[r8] = fmaxf(a, 0.f) + pa * fminf(a, 0.f);
    }
    uint2 sp0 = split_pack(tt[0], tt[1]), sp1 = split_pack(tt[2], tt[3]);
    uint2 sp2 = split_pack(tt[4], tt[5]), sp3 = split_pack(tt[6], tt[7]);
    uint4 hi = make_uint4(sp0.x, sp1.x, sp2.x, sp3.x);
    uint4 lo = make_uint4(sp0.y, sp1.y, sp2.y, sp3.y);
    uint4* opb = actout + (size_t)(sc * 4 + g) * PPLANE * 2;
    store_halo_s<uint4, 2>(opb, j, i, o * 2, hi);
    store_halo_s<uint4, 2>(opb, j, i, o * 2 + 1, lo);
  }
}

// ---------------- MFMA 3x3 conv, ping-pong B prefetch ----------------
// SPLIT: writes split act records. !SPLIT: computes convT tap-sums
// s_t = sum_ch wT[t][ch]*O(pix,ch) and writes 25 tap planes s[sc][t][PLANE].
template <int CIN, int COUT, bool SC, bool SPLIT>
__global__ __launch_bounds__(256, 2) void k_mconv(
    const uint4* __restrict__ act, const unsigned short* __restrict__ wf,
    const float* __restrict__ bias, const float* __restrict__ pre,
    uint2* __restrict__ actout, float* __restrict__ sout,
    const uint2* __restrict__ scact, const float* __restrict__ scinv,
    const float* __restrict__ wTt) {
  constexpr int KC = CIN / 32, MT = COUT / 16;
  const int lane = threadIdx.x & 63, wv = threadIdx.x >> 6;
  const int quad = lane >> 4, col = lane & 15;
  const int sc = blockIdx.y;
  const int p0 = (blockIdx.x * 4 + wv) * 64;

  uint32 pix[4], py[4], px[4], boff[4];
#pragma unroll
  for (int nt = 0; nt < 4; ++nt) {
    uint32 p = p0 + nt * 16 + col;
    pix[nt] = p;
    uint32 pc = p > 72899u ? 72899u : p;
    uint32 y = pc / 270u, x = pc - y * 270u;
    py[nt] = y; px[nt] = x;
    boff[nt] = (y + 1) * PW + x;
  }
  uint32 bo[KC][4];
#pragma unroll
  for (int kc = 0; kc < KC; ++kc)
#pragma unroll
    for (int nt = 0; nt < 4; ++nt)
      bo[kc][nt] = ((uint32)(sc * (CIN / 8) + kc * 4 + quad) * PPLANE + boff[nt]) * 2;

  f32x4 acc[MT][4];
#pragma unroll
  for (int mt = 0; mt < MT; ++mt)
#pragma unroll
    for (int nt = 0; nt < 4; ++nt) { f32x4 z = {0.f, 0.f, 0.f, 0.f}; acc[mt][nt] = z; }

  // ping-pong B buffers: [parity][kc][nt][hi/lo]
  uint4 B[2][KC][4][2];
  {
    const int doff2 = (-1 * PW + 0) * 2;   // o=0: dy=0,dx=0
#pragma unroll
    for (int kc = 0; kc < KC; ++kc)
#pragma unroll
      for (int nt = 0; nt < 4; ++nt) {
        B[0][kc][nt][0] = act[bo[kc][nt] + doff2];
        B[0][kc][nt][1] = act[bo[kc][nt] + doff2 + 1];
      }
  }

#pragma unroll
  for (int o = 0; o < 9; ++o) {
    if (o < 8) {
      const int dy = (o + 1) / 3, dx = (o + 1) % 3;
      const int doff2 = ((dy - 1) * PW + dx) * 2;
#pragma unroll
      for (int kc = 0; kc < KC; ++kc)
#pragma unroll
        for (int nt = 0; nt < 4; ++nt) {
          B[(o + 1) & 1][kc][nt][0] = act[bo[kc][nt] + doff2];
          B[(o + 1) & 1][kc][nt][1] = act[bo[kc][nt] + doff2 + 1];
        }
    }
#pragma unroll
    for (int kc = 0; kc < KC; ++kc) {
      union { uint4 u; bf16x8 v; } Wh[MT], Wl[MT];
#pragma unroll
      for (int mt = 0; mt < MT; ++mt) {
        const uint4* wp = (const uint4*)wf + ((((o * KC + kc) * MT + mt) * 64 + lane) * 2);
        Wh[mt].u = wp[0]; Wl[mt].u = wp[1];
      }
#pragma unroll
      for (int nt = 0; nt < 4; ++nt) {
        union { uint4 u; bf16x8 v; } Bh, Bl;
        Bh.u = B[o & 1][kc][nt][0];
        Bl.u = B[o & 1][kc][nt][1];
#pragma unroll
        for (int mt = 0; mt < MT; ++mt)
          acc[mt][nt] = __builtin_amdgcn_mfma_f32_16x16x32_bf16(Wh[mt].v, Bh.v, acc[mt][nt], 0, 0, 0);
#pragma unroll
        for (int mt = 0; mt < MT; ++mt)
          acc[mt][nt] = __builtin_amdgcn_mfma_f32_16x16x32_bf16(Wl[mt].v, Bh.v, acc[mt][nt], 0, 0, 0);
#pragma unroll
        for (int mt = 0; mt < MT; ++mt)
          acc[mt][nt] = __builtin_amdgcn_mfma_f32_16x16x32_bf16(Wh[mt].v, Bl.v, acc[mt][nt], 0, 0, 0);
      }
    }
  }

  if (SPLIT) {
#pragma unroll
    for (int mt = 0; mt < MT; ++mt) {
      const int ocb = mt * 16 + quad * 4;
      const int g2 = 2 * mt + (quad >> 1), slot = quad & 1;
      f32x4 bias4 = *(const f32x4*)(bias + ocb);
      f32x4 pr4 = *(const f32x4*)(pre + ocb);
      f32x4 inv4;
      if (SC) inv4 = *(const f32x4*)(scinv + ocb);
#pragma unroll
      for (int nt = 0; nt < 4; ++nt) {
        if (pix[nt] > 72899u) continue;
        const uint32 ppix = boff[nt] + 1;
        float v[4];
#pragma unroll
        for (int r = 0; r < 4; ++r) v[r] = acc[mt][nt][r] + bias4[r];
        if (SC) {
          const uint2* rec = scact + ((size_t)(sc * (COUT / 8) + g2) * PPLANE + ppix) * 4;
          uint2 hi = rec[slot], lo = rec[2 + slot];
          float s0 = __uint_as_float(hi.x << 16) + __uint_as_float(lo.x << 16);
          float s1 = __uint_as_float(hi.x & 0xFFFF0000u) + __uint_as_float(lo.x & 0xFFFF0000u);
          float s2 = __uint_as_float(hi.y << 16) + __uint_as_float(lo.y << 16);
          float s3 = __uint_as_float(hi.y & 0xFFFF0000u) + __uint_as_float(lo.y & 0xFFFF0000u);
          v[0] += (s0 >= 0.f) ? s0 : s0 * inv4[0];
          v[1] += (s1 >= 0.f) ? s1 : s1 * inv4[1];
          v[2] += (s2 >= 0.f) ? s2 : s2 * inv4[2];
          v[3] += (s3 >= 0.f) ? s3 : s3 * inv4[3];
        }
        float t0 = fmaxf(v[0], 0.f) + pr4[0] * fminf(v[0], 0.f);
        float t1 = fmaxf(v[1], 0.f) + pr4[1] * fminf(v[1], 0.f);
        float t2 = fmaxf(v[2], 0.f) + pr4[2] * fminf(v[2], 0.f);
        float t3 = fmaxf(v[3], 0.f) + pr4[3] * fminf(v[3], 0.f);
        uint2 sp0 = split_pack(t0, t1), sp1 = split_pack(t2, t3);
        uint2* opb = actout + (size_t)(sc * (COUT / 8) + g2) * PPLANE * 4;
        int oidx = (int)ppix * 4;
        store_halo_s<uint2, 4>(opb, (int)px[nt], (int)py[nt], oidx + slot,     make_uint2(sp0.x, sp1.x));
        store_halo_s<uint2, 4>(opb, (int)px[nt], (int)py[nt], oidx + 2 + slot, make_uint2(sp0.y, sp1.y));
      }
    }
  } else {
    // fused convT channel contraction: s_t = sum_ch wT[t][ch]*(acc+bias)
    float4 b4[MT];
#pragma unroll
    for (int mt = 0; mt < MT; ++mt) b4[mt] = *(const float4*)(bias + mt * 16 + quad * 4);
#pragma unroll
    for (int nt = 0; nt < 4; ++nt) {
      if (pix[nt] > 72899u) continue;   // uniform across the 4-quad shuffle group
      float vv[MT][4];
#pragma unroll
      for (int mt = 0; mt < MT; ++mt) {
        vv[mt][0] = acc[mt][nt][0] + b4[mt].x;
        vv[mt][1] = acc[mt][nt][1] + b4[mt].y;
        vv[mt][2] = acc[mt][nt][2] + b4[mt].z;
        vv[mt][3] = acc[mt][nt][3] + b4[mt].w;
      }
      float* sp = sout + (size_t)sc * 25 * PLANE + (int)(py[nt] * 270 + px[nt]);
#pragma unroll
      for (int t = 0; t < 25; ++t) {
        const float* wp = wTt + t * 32 + quad * 4;
        float c = 0.f;
#pragma unroll
        for (int mt = 0; mt < MT; ++mt) {
          float4 w4 = *(const float4*)(wp + mt * 16);
          c += w4.x * vv[mt][0] + w4.y * vv[mt][1] + w4.z * vv[mt][2] + w4.w * vv[mt][3];
        }
        c += __shfl_xor(c, 16, 64);
        c += __shfl_xor(c, 32, 64);
        if (quad == 0) sp[(size_t)t * PLANE] = c;
      }
    }
  }
}

// ---------------- convT pass 2: out = bt + sum_t s_t(shifted) ----------------
__global__ __launch_bounds__(256) void k_convT2(const float* __restrict__ s, const float* __restrict__ bt,
                                                float* __restrict__ yo) {
  int p = blockIdx.x * 256 + threadIdx.x;
  if (p >= PLANE) return;
  int sc = blockIdx.y;
  int y = p / 270, x = p - y * 270;
  float acc = bt[0];
  const float* sb = s + (size_t)sc * 25 * PLANE;
#pragma unroll
  for (int a = 0; a < 5; ++a) {
    int yy = y + a - 2;
    if ((unsigned)yy >= 270u) continue;
    const float* row = sb + (size_t)(a * 5) * PLANE + yy * 270;
#pragma unroll
    for (int b = 0; b < 5; ++b) {
      int xx = x + b - 2;
      if ((unsigned)xx < 270u) acc += row[(size_t)b * PLANE + xx];
    }
  }
  yo[(size_t)sc * PLANE + p] = acc;
}

// ---------------- norm projection scale ----------------
__global__ __launch_bounds__(256) void k_nrm(const float* __restrict__ yb, float* __restrict__ red) {
  int s = blockIdx.x;
  const float* ys = yb + (size_t)s * PLANE;
  float acc = 0.f;
  for (int i = threadIdx.x; i < PLANE; i += 256) { float v = ys[i]; acc += v * v; }
  float tot = blockReduceSum(acc);
  if (threadIdx.x == 0) {
    float nrm = sqrtf(tot);
    float eps = red[8 + s];
    red[16 + s] = (nrm > eps) ? eps / fmaxf(nrm, 1e-12f) : 1.0f;
  }
}

// ---------------- final: clip(z - scl*y), crop, mix ----------------
__global__ __launch_bounds__(256) void k_final(const float* __restrict__ z, const float* __restrict__ yb,
                                               const float* __restrict__ red, const float* __restrict__ mw,
                                               float* __restrict__ out) {
  int idx = blockIdx.x * 256 + threadIdx.x;
  if (idx >= 131072) return;
  int b = idx >> 16;
  int rem = idx & 65535;
  int h = rem >> 8, w = rem & 255;
  int p = (h + 7) * HP + (w + 7);
  float acc = 0.f;
#pragma unroll
  for (int d = 0; d < 4; ++d) {
    int s = b * 4 + d;
    float v = z[(size_t)s * PLANE + p] - red[16 + s] * yb[(size_t)s * PLANE + p];
    v = fminf(fmaxf(v, 0.f), 255.f);
    acc += mw[d] * v;
  }
  out[idx] = acc;
}

// =====================================================================
extern "C" void kernel_launch(void* const* d_in, const int* in_sizes, int n_in,
                              void* d_out, int out_size, void* d_ws, size_t ws_size,
                              hipStream_t stream) {
  (void)in_sizes; (void)n_in; (void)out_size; (void)ws_size;
  const float* x    = (const float*)d_in[0];
  const float* bk   = (const float*)d_in[1];
  const float* stdn = (const float*)d_in[2];
  const float* ww   = (const float*)d_in[3];
  const float* wwsc = (const float*)d_in[4];
  const float* alph = (const float*)d_in[5];
  const float* cw   = (const float*)d_in[6];
  const float* sf   = (const float*)d_in[7];
  const float* bf   = (const float*)d_in[8];
  const float* bt   = (const float*)d_in[9];
  const float* p1   = (const float*)d_in[10];
  const float* w1   = (const float*)d_in[11];
  const float* s1   = (const float*)d_in[12];
  const float* b1   = (const float*)d_in[13];
  const float* p2   = (const float*)d_in[14];
  const float* w2   = (const float*)d_in[15];
  const float* s2   = (const float*)d_in[16];
  const float* b2   = (const float*)d_in[17];
  const float* apj  = (const float*)d_in[18];
  const float* mwp  = (const float*)d_in[19];
  float* out = (float*)d_out;

  char* wsbase = (char*)d_ws;
  size_t off = 0;
  auto alloc = [&](size_t nbytes) -> char* {
    char* p = wsbase + off;
    off = (off + nbytes + 255) & ~(size_t)255;
    return p;
  };
  // ---- persistent region ----
  float*  zb  = (float*)alloc(8 * (size_t)PLANE * 4);
  float*  yb  = (float*)alloc(8 * (size_t)PLANE * 4);
  float*  red = (float*)alloc(64 * 4);
  float*  inv = (float*)alloc(32 * 4);
  float*  cwn = (float*)alloc(800 * 4);
  float*  wTt = (float*)alloc(800 * 4);
  unsigned short* w1f = (unsigned short*)alloc(5 * 36864 * (size_t)2);
  unsigned short* w2f = (unsigned short*)alloc(5 * 36864 * (size_t)2);
  // ---- union region ----
  size_t U0 = off;
  // DFT view
  float2* tw  = (float2*)alloc(2 * (size_t)PLANE * 4);
  float*  xp  = (float*)alloc(2 * (size_t)PLANE * 4);
  float*  rtm = (float*)alloc(2 * (size_t)PLANE * 4);
  float2* cb0 = (float2*)alloc(2 * 8 * (size_t)PLANE * 8);
  float2* cb1 = (float2*)alloc(2 * 8 * (size_t)PLANE * 8);
  float2* Yb  = (float2*)alloc(2 * 2 * (size_t)PLANE * 8);
  float2* Hf  = (float2*)alloc(2 * (size_t)PLANE * 4);
  float*  Sb  = (float*)alloc((size_t)PLANE * 4);
  float2* Tb  = (float2*)alloc(2 * 4 * (size_t)PLANE * 4);
  float*  ahw = (float*)alloc(540 * 4);
  float*  wwn = (float*)alloc(600 * 4);
  // conv view (aliases the DFT view)
  off = U0;
  uint4* act1 = (uint4*)alloc(4 * 4 * (size_t)PPLANE * 32);   // 32ch split acts; also aliases sOb (4*25*PLANE f32)
  uint4* act2 = (uint4*)alloc(4 * 8 * (size_t)PPLANE * 32);   // 64ch split acts
  float* sOb = (float*)act1;

  // setup
  k_twiddle<<<285, 256, 0, stream>>>(tw);
  k_sympad<<<(2 * PLANE + 255) / 256, 256, 0, stream>>>(x, xp);
  k_edget<<<1, 512, 0, stream>>>(bk, ahw);
  k_Hf<<<285, 256, 0, stream>>>(bk, Hf);
  k_wnorm<<<24, 256, 0, stream>>>(ww, wwsc, wwn, 25);
  k_wnorm<<<32, 256, 0, stream>>>(cw, sf, cwn, 25);
  k_wT<<<4, 256, 0, stream>>>(cwn, wTt);
  k_wfrag<32, 64><<<320, 256, 0, stream>>>(w1, s1, w1f);
  k_wfrag<64, 32><<<160, 256, 0, stream>>>(w2, s2, w2f);
  k_inv<<<1, 32, 0, stream>>>(p1, inv);
  k_S<<<285, 256, 0, stream>>>(wwn, Sb);
  k_T<<<(4 * PLANE + 255) / 256, 256, 0, stream>>>(Hf, Sb, alph, Tb);
  k_amp<<<4, 256, 0, stream>>>(Tb, red);
  k_eps<<<1, 64, 0, stream>>>(apj, stdn, red);

  dim3 g2(5, 45, 2), g8(5, 45, 8);

  // edgetaper
  k_rowT<6, true ><<<g2, 64, 0, stream>>>(xp, cb1, tw, -1.f);
  k_colT<6, false><<<g2, 64, 0, stream>>>(cb1, cb0, tw, -1.f, 1.f);
  k_mulHf<<<(2 * PLANE + 255) / 256, 256, 0, stream>>>(cb0, Hf, cb1);
  k_rowT<6, false><<<g2, 64, 0, stream>>>(cb1, cb0, tw, 1.f);
  k_colT<6, true ><<<g2, 64, 0, stream>>>(cb0, rtm, tw, 1.f, 1.f / (float)PLANE);
  k_taper<<<(2 * PLANE + 255) / 256, 256, 0, stream>>>(xp, rtm, ahw);

  // Y = fft2(xp)
  k_rowT<6, true ><<<g2, 64, 0, stream>>>(xp, cb1, tw, -1.f);
  k_colT<6, false><<<g2, 64, 0, stream>>>(cb1, Yb, tw, -1.f, 1.f);

  // z = ifft2(T*Y).real for all 8 (b,d)
  k_mulTY<<<(8 * PLANE + 255) / 256, 256, 0, stream>>>(Tb, Yb, cb0);
  k_rowT<6, false><<<g8, 64, 0, stream>>>(cb0, cb1, tw, 1.f);
  k_colT<6, true ><<<g8, 64, 0, stream>>>(cb1, zb, tw, 1.f, 1.f / (float)PLANE);

  // conv net, 2 chunks of 4 samples
  for (int c = 0; c < 2; ++c) {
    const float* zc = zb + (size_t)c * 4 * PLANE;
    float* ybc = yb + (size_t)c * 4 * PLANE;
    k_conv5<<<dim3(285, 4), 256, 0, stream>>>(zc, cwn, bf, p1, act1);
    for (int i = 0; i < 5; ++i) {
      k_mconv<32, 64, false, true><<<dim3(285, 4), 256, 0, stream>>>(
          act1, w1f + (size_t)i * 36864, b1 + i * 64, p2 + i * 64, (uint2*)act2, nullptr, nullptr, nullptr, nullptr);
      if (i == 0)
        k_mconv<64, 32, true, true><<<dim3(285, 4), 256, 0, stream>>>(
            act2, w2f + (size_t)i * 36864, b2 + i * 32, p1 + (i + 1) * 32, (uint2*)act1, nullptr, (const uint2*)act1, inv, nullptr);
      else if (i < 4)
        k_mconv<64, 32, false, true><<<dim3(285, 4), 256, 0, stream>>>(
            act2, w2f + (size_t)i * 36864, b2 + i * 32, p1 + (i + 1) * 32, (uint2*)act1, nullptr, nullptr, nullptr, nullptr);
      else
        k_mconv<64, 32, false, false><<<dim3(285, 4), 256, 0, stream>>>(
            act2, w2f + (size_t)i * 36864, b2 + i * 32, nullptr, nullptr, sOb, nullptr, nullptr, wTt);
    }
    k_convT2<<<dim3(285, 4), 256, 0, stream>>>(sOb, bt, ybc);
  }

  // projection + final mix
  k_nrm<<<8, 256, 0, stream>>>(yb, red);
  k_final<<<(131072 + 255) / 256, 256, 0, stream>>>(zb, yb, red, mwp, out);
}

// Round 8
// 2075.134 us; speedup vs baseline: 3.4779x; 1.0780x over previous
//
#include <hip/hip_runtime.h>
#include <math.h>

#define HP     270
#define PLANE  72900      // 270*270
#define PW     272
#define PPLANE 73984      // 272*272

typedef unsigned int uint32;
typedef __attribute__((ext_vector_type(8))) short bf16x8;
typedef __attribute__((ext_vector_type(4))) float f32x4;

// ---------------- reduction helper ----------------
__device__ __forceinline__ float blockReduceSum(float val) {
  __shared__ float sh[16];
  int lane = threadIdx.x & 63, wid = threadIdx.x >> 6;
#pragma unroll
  for (int o = 32; o > 0; o >>= 1) val += __shfl_down(val, o, 64);
  __syncthreads();
  if (lane == 0) sh[wid] = val;
  __syncthreads();
  float tot = 0.f;
  int nw = (blockDim.x + 63) >> 6;
  for (int i = 0; i < nw; ++i) tot += sh[i];
  return tot;
}

// ---------------- twiddle matrix ----------------
__global__ __launch_bounds__(256) void k_twiddle(float2* __restrict__ tw) {
  int idx = blockIdx.x * 256 + threadIdx.x;
  if (idx >= PLANE) return;
  int j = idx / HP, k = idx % HP;
  int m = (j * k) % HP;
  double ang = (2.0 * M_PI * (double)m) / 270.0;
  tw[idx] = make_float2((float)cos(ang), (float)sin(ang));
}

// ---------------- symmetric pad x (2,256,256) -> xp (2,270,270), pad 7 ----------------
__global__ __launch_bounds__(256) void k_sympad(const float* __restrict__ x, float* __restrict__ xp) {
  int idx = blockIdx.x * 256 + threadIdx.x;
  if (idx >= 2 * PLANE) return;
  int b = idx / PLANE, p = idx % PLANE;
  int i = p / HP, j = p % HP;
  int si = i - 7; si = si < 0 ? -1 - si : (si > 255 ? 511 - si : si);
  int sj = j - 7; sj = sj < 0 ? -1 - sj : (sj > 255 ? 511 - sj : sj);
  xp[idx] = x[(b * 256 + si) * 256 + sj];
}

// ---------------- edgetaper 1D weights ----------------
__global__ __launch_bounds__(512) void k_edget(const float* __restrict__ bk, float* __restrict__ ahw) {
  __shared__ float pr[15], pc[15], acr[15], accl[15];
  int t = threadIdx.x;
  if (t < 15) {
    float sr = 0.f, scv = 0.f;
    for (int k = 0; k < 15; ++k) { sr += bk[t * 15 + k]; scv += bk[k * 15 + t]; }
    pr[t] = sr; pc[t] = scv;
  }
  __syncthreads();
  if (t < 30) {
    int l = t % 15; bool isr = (t < 15);
    const float* p = isr ? pr : pc;
    float s = 0.f;
    for (int j = 0; j + l < 15; ++j) s += p[j] * p[j + l];
    if (isr) acr[l] = s; else accl[l] = s;
  }
  __syncthreads();
  for (int i = t; i < 540; i += blockDim.x) {
    bool isr = (i < 270);
    int ii = isr ? i : i - 270;
    const float* ac = isr ? acr : accl;
    int m = (ii == 269) ? 0 : ii;
    float zv;
    if (m < 15) zv = ac[m];
    else if (m >= 255) zv = ac[269 - m];
    else zv = 0.f;
    ahw[i] = 1.f - zv / ac[0];
  }
}

// ---------------- Hf = psf2otf(blur 15x15) ----------------
__global__ __launch_bounds__(256) void k_Hf(const float* __restrict__ bk, float2* __restrict__ Hf) {
  int p = blockIdx.x * 256 + threadIdx.x;
  if (p >= PLANE) return;
  int u = p / HP, v = p % HP;
  float2 er[15], es[15];
#pragma unroll
  for (int r = 0; r < 15; ++r) {
    int m = ((u * (r - 7)) % HP + HP) % HP;
    float sn, cs;
    sincosf(2.f * (float)M_PI * (float)m / 270.f, &sn, &cs);
    er[r] = make_float2(cs, -sn);
    int m2 = ((v * (r - 7)) % HP + HP) % HP;
    sincosf(2.f * (float)M_PI * (float)m2 / 270.f, &sn, &cs);
    es[r] = make_float2(cs, -sn);
  }
  float ar = 0.f, ai = 0.f;
#pragma unroll 1
  for (int r = 0; r < 15; ++r) {
    float rr = 0.f, ri = 0.f;
#pragma unroll
    for (int s = 0; s < 15; ++s) {
      float wv = bk[r * 15 + s];
      rr += wv * es[s].x; ri += wv * es[s].y;
    }
    ar += er[r].x * rr - er[r].y * ri;
    ai += er[r].x * ri + er[r].y * rr;
  }
  Hf[p] = make_float2(ar, ai);
}

// ---------------- weight normalization, plain layout ----------------
__global__ __launch_bounds__(256) void k_wnorm(const float* __restrict__ w, const float* __restrict__ scale,
                                               float* __restrict__ out, int fsize) {
  int f = blockIdx.x;
  const float* wf = w + (size_t)f * fsize;
  float s = 0.f;
  for (int i = threadIdx.x; i < fsize; i += 256) s += wf[i];
  float mean = blockReduceSum(s) / (float)fsize;
  float s2 = 0.f;
  for (int i = threadIdx.x; i < fsize; i += 256) { float d = wf[i] - mean; s2 += d * d; }
  float nrm = sqrtf(blockReduceSum(s2));
  float sc = scale[f] / nrm;
  for (int i = threadIdx.x; i < fsize; i += 256) out[(size_t)f * fsize + i] = (wf[i] - mean) * sc;
}

// ---------------- transpose conv5 weights to tap-major (flipped) ----------------
__global__ void k_wT(const float* __restrict__ cwn, float* __restrict__ wT) {
  int idx = blockIdx.x * 256 + threadIdx.x;
  if (idx >= 800) return;
  int t = idx >> 5, f = idx & 31;
  int dri = t / 5, dci = t % 5;           // input offsets dr = dri-2, dc = dci-2
  wT[t * 32 + f] = cwn[f * 25 + (4 - dri) * 5 + (4 - dci)];
}

// ---------------- weight normalization -> split-bf16 MFMA fragment layout ----------------
template <int CIN, int COUT>
__global__ __launch_bounds__(256) void k_wfrag(const float* __restrict__ w, const float* __restrict__ scale,
                                               unsigned short* __restrict__ outb) {
  constexpr int KC = CIN / 32, MT = COUT / 16, FS = CIN * 9;
  int fg = blockIdx.x;
  int f = fg % COUT, iter = fg / COUT;
  const float* wf = w + (size_t)fg * FS;
  float s = 0.f;
  for (int i = threadIdx.x; i < FS; i += 256) s += wf[i];
  float mean = blockReduceSum(s) / (float)FS;
  float s2 = 0.f;
  for (int i = threadIdx.x; i < FS; i += 256) { float d = wf[i] - mean; s2 += d * d; }
  float nrm = sqrtf(blockReduceSum(s2));
  float scv = scale[fg] / nrm;
  unsigned short* dst0 = outb + (size_t)iter * (9 * KC * MT * 64 * 16);
  for (int i = threadIdx.x; i < FS; i += 256) {
    float val = (wf[i] - mean) * scv;
    int ci = i / 9, rs = i - ci * 9;
    int kc = ci >> 5, cil = ci & 31, q = cil >> 3, j = cil & 7;
    int mt = f >> 4, ocl = f & 15, lane = q * 16 + ocl;
    unsigned short* d2 = dst0 + ((((rs * KC + kc) * MT + mt) * 64 + lane) * 16);
    uint32 u = __float_as_uint(val);
    d2[j] = (unsigned short)(u >> 16);
    float lof = val - __uint_as_float(u & 0xFFFF0000u);
    d2[8 + j] = (unsigned short)(__float_as_uint(lof) >> 16);
  }
}

// ---------------- S = sum_f |FT(ww_f 5x5)|^2 ----------------
__global__ __launch_bounds__(256) void k_S(const float* __restrict__ wwn, float* __restrict__ S) {
  int p = blockIdx.x * 256 + threadIdx.x;
  if (p >= PLANE) return;
  int u = p / HP, v = p % HP;
  float2 er[5], es[5];
#pragma unroll
  for (int r = 0; r < 5; ++r) {
    float sn, cs;
    int m = (u * r) % HP;
    sincosf(2.f * (float)M_PI * (float)m / 270.f, &sn, &cs);
    er[r] = make_float2(cs, -sn);
    int m2 = (v * r) % HP;
    sincosf(2.f * (float)M_PI * (float)m2 / 270.f, &sn, &cs);
    es[r] = make_float2(cs, -sn);
  }
  float prr[25], pii[25];
#pragma unroll
  for (int r = 0; r < 5; ++r)
#pragma unroll
    for (int s = 0; s < 5; ++s) {
      prr[r * 5 + s] = er[r].x * es[s].x - er[r].y * es[s].y;
      pii[r * 5 + s] = er[r].x * es[s].y + er[r].y * es[s].x;
    }
  float acc = 0.f;
#pragma unroll 1
  for (int f = 0; f < 24; ++f) {
    float xr = 0.f, xi = 0.f;
#pragma unroll
    for (int t = 0; t < 25; ++t) {
      float wv = wwn[f * 25 + t];
      xr += wv * prr[t]; xi += wv * pii[t];
    }
    acc += xr * xr + xi * xi;
  }
  S[p] = acc;
}

// ---------------- T = conj(Hf)/(|Hf|^2 + a_d S) ----------------
__global__ __launch_bounds__(256) void k_T(const float2* __restrict__ Hf, const float* __restrict__ S,
                                           const float* __restrict__ alpha, float2* __restrict__ T) {
  int idx = blockIdx.x * 256 + threadIdx.x;
  if (idx >= 4 * PLANE) return;
  int d = idx / PLANE, p = idx % PLANE;
  float a = expf(alpha[d]);
  float2 h = Hf[p];
  float den = h.x * h.x + h.y * h.y + a * S[p];
  T[idx] = make_float2(h.x / den, -h.y / den);
}

__global__ __launch_bounds__(256) void k_amp(const float2* __restrict__ T, float* __restrict__ red) {
  int d = blockIdx.x;
  const float2* Td = T + (size_t)d * PLANE;
  float acc = 0.f;
  for (int i = threadIdx.x; i < PLANE; i += 256) { float2 t = Td[i]; acc += t.x * t.x + t.y * t.y; }
  float tot = blockReduceSum(acc);
  if (threadIdx.x == 0) red[d] = tot / (float)PLANE;
}

__global__ void k_eps(const float* __restrict__ apj, const float* __restrict__ stdn, float* __restrict__ red) {
  int s = threadIdx.x;
  if (s < 8) {
    int b = s >> 2, d = s & 3;
    red[8 + s] = expf(apj[0]) * stdn[b] * sqrtf(red[d]) * sqrtf(72899.f);
  }
}

__global__ void k_inv(const float* __restrict__ p, float* __restrict__ inv) {
  int t = threadIdx.x;
  if (t < 32) inv[t] = 1.f / p[t];
}

// ---------------- register-tiled DFT passes ----------------
template <int NR, bool REALIN>
__global__ __launch_bounds__(64) void k_rowT(const void* __restrict__ inv_, float2* __restrict__ out,
                                             const float2* __restrict__ tw, float sgn) {
  int v = blockIdx.x * 64 + threadIdx.x;
  int r0 = blockIdx.y * NR;
  int m = blockIdx.z;
  bool ok = v < HP;
  int vc = ok ? v : 0;
  float P[NR], R[NR], Q[NR], Sm[NR];
#pragma unroll
  for (int i = 0; i < NR; ++i) { P[i] = R[i] = 0.f; if (!REALIN) { Q[i] = Sm[i] = 0.f; } }
  const float*  inR = (const float*)inv_  + ((size_t)m * HP + r0) * HP;
  const float2* inC = (const float2*)inv_ + ((size_t)m * HP + r0) * HP;
#pragma unroll 3
  for (int w = 0; w < HP; ++w) {
    float2 t = tw[w * HP + vc];
#pragma unroll
    for (int i = 0; i < NR; ++i) {
      if (REALIN) {
        float a = inR[i * HP + w];
        P[i] += a * t.x; R[i] += a * t.y;
      } else {
        float2 g = inC[i * HP + w];
        P[i] += g.x * t.x; Q[i] += g.y * t.y;
        R[i] += g.x * t.y; Sm[i] += g.y * t.x;
      }
    }
  }
  if (ok) {
#pragma unroll
    for (int i = 0; i < NR; ++i) {
      float ar, ai;
      if (REALIN) { ar = P[i]; ai = sgn * R[i]; }
      else        { ar = P[i] - sgn * Q[i]; ai = sgn * R[i] + Sm[i]; }
      out[((size_t)m * HP + r0 + i) * HP + v] = make_float2(ar, ai);
    }
  }
}

template <int NU, bool REALOUT>
__global__ __launch_bounds__(64) void k_colT(const float2* __restrict__ in, void* __restrict__ outv,
                                             const float2* __restrict__ tw, float sgn, float scale) {
  int v = blockIdx.x * 64 + threadIdx.x;
  int u0 = blockIdx.y * NU;
  int m = blockIdx.z;
  bool ok = v < HP;
  int vc = ok ? v : 0;
  float P[NU], Q[NU], R[NU], Sm[NU];
#pragma unroll
  for (int j = 0; j < NU; ++j) { P[j] = Q[j] = 0.f; if (!REALOUT) { R[j] = Sm[j] = 0.f; } }
  const float2* cp = in + (size_t)m * PLANE + vc;
#pragma unroll 3
  for (int h = 0; h < HP; ++h) {
    float2 g = cp[(size_t)h * HP];
    const float2* tr = tw + h * HP + u0;
#pragma unroll
    for (int j = 0; j < NU; ++j) {
      float2 t = tr[j];
      P[j] += g.x * t.x; Q[j] += g.y * t.y;
      if (!REALOUT) { R[j] += g.x * t.y; Sm[j] += g.y * t.x; }
    }
  }
  if (ok) {
#pragma unroll
    for (int j = 0; j < NU; ++j) {
      float ar = (P[j] - sgn * Q[j]) * scale;
      if (REALOUT) ((float*)outv)[((size_t)m * HP + u0 + j) * HP + v] = ar;
      else {
        float ai = (sgn * R[j] + Sm[j]) * scale;
        ((float2*)outv)[((size_t)m * HP + u0 + j) * HP + v] = make_float2(ar, ai);
      }
    }
  }
}

// ---------------- pointwise ----------------
__global__ __launch_bounds__(256) void k_mulHf(const float2* __restrict__ in, const float2* __restrict__ Hf,
                                               float2* __restrict__ out) {
  int idx = blockIdx.x * 256 + threadIdx.x;
  if (idx >= 2 * PLANE) return;
  int p = idx % PLANE;
  float2 a = in[idx], b = Hf[p];
  out[idx] = make_float2(a.x * b.x - a.y * b.y, a.x * b.y + a.y * b.x);
}

__global__ __launch_bounds__(256) void k_taper(float* __restrict__ xp, const float* __restrict__ blr,
                                               const float* __restrict__ ahw) {
  int idx = blockIdx.x * 256 + threadIdx.x;
  if (idx >= 2 * PLANE) return;
  int p = idx % PLANE;
  int i = p / HP, j = p % HP;
  float al = ahw[i] * ahw[270 + j];
  xp[idx] = al * xp[idx] + (1.f - al) * blr[idx];
}

__global__ __launch_bounds__(256) void k_mulTY(const float2* __restrict__ T, const float2* __restrict__ Y,
                                               float2* __restrict__ out) {
  int idx = blockIdx.x * 256 + threadIdx.x;
  if (idx >= 8 * PLANE) return;
  int s = idx / PLANE, p = idx % PLANE;
  int b = s >> 2, d = s & 3;
  float2 a = T[(size_t)d * PLANE + p], y = Y[(size_t)b * PLANE + p];
  out[idx] = make_float2(a.x * y.x - a.y * y.y, a.x * y.y + a.y * y.x);
}

// ---------------- split+pack helper ----------------
__device__ __forceinline__ uint2 split_pack(float t0, float t1) {
  uint32 u0 = __float_as_uint(t0), u1 = __float_as_uint(t1);
  uint32 hiw = (u0 >> 16) | (u1 & 0xFFFF0000u);
  float r0 = t0 - __uint_as_float(u0 & 0xFFFF0000u);
  float r1 = t1 - __uint_as_float(u1 & 0xFFFF0000u);
  uint32 low = (__float_as_uint(r0) >> 16) | (__float_as_uint(r1) & 0xFFFF0000u);
  return make_uint2(hiw, low);
}

template <typename T, int STRIDE>
__device__ __forceinline__ void store_halo_s(T* __restrict__ op, int xx, int yy, int o, T val) {
  op[o] = val;
  bool xl = (xx == 0), xr = (xx == 269), yt = (yy == 0), yb = (yy == 269);
  if (xl) op[o - STRIDE] = val;
  if (xr) op[o + STRIDE] = val;
  if (yt) { op[o - PW * STRIDE] = val; if (xl) op[o - (PW + 1) * STRIDE] = val; if (xr) op[o - (PW - 1) * STRIDE] = val; }
  if (yb) { op[o + PW * STRIDE] = val; if (xl) op[o + (PW - 1) * STRIDE] = val; if (xr) op[o + (PW + 1) * STRIDE] = val; }
}

// ---------------- first conv 5x5 1->32 -> grouped split act records ----------------
__global__ __launch_bounds__(256) void k_conv5(const float* __restrict__ z, const float* __restrict__ cw,
                                               const float* __restrict__ bias, const float* __restrict__ pre,
                                               uint4* __restrict__ actout) {
  int p = blockIdx.x * 256 + threadIdx.x;
  if (p >= PLANE) return;
  int sc = blockIdx.y;
  int i = p / HP, j = p % HP;
  const float* zs = z + (size_t)sc * PLANE;
  float v[25];
#pragma unroll
  for (int r = 0; r < 5; ++r) {
    int ii = i + r - 2; ii = ii < 0 ? -1 - ii : (ii > 269 ? 539 - ii : ii);
#pragma unroll
    for (int s = 0; s < 5; ++s) {
      int jj = j + s - 2; jj = jj < 0 ? -1 - jj : (jj > 269 ? 539 - jj : jj);
      v[r * 5 + s] = zs[ii * HP + jj];
    }
  }
  int o = (i + 1) * PW + (j + 1);
#pragma unroll 1
  for (int g = 0; g < 4; ++g) {
    float tt[8];
#pragma unroll
    for (int r8 = 0; r8 < 8; ++r8) {
      int oc = 8 * g + r8;
      float a = bias[oc];
#pragma unroll
      for (int k = 0; k < 25; ++k) a += cw[oc * 25 + k] * v[k];
      float pa = pre[oc];
      tt[r8] = fmaxf(a, 0.f) + pa * fminf(a, 0.f);
    }
    uint2 sp0 = split_pack(tt[0], tt[1]), sp1 = split_pack(tt[2], tt[3]);
    uint2 sp2 = split_pack(tt[4], tt[5]), sp3 = split_pack(tt[6], tt[7]);
    uint4 hi = make_uint4(sp0.x, sp1.x, sp2.x, sp3.x);
    uint4 lo = make_uint4(sp0.y, sp1.y, sp2.y, sp3.y);
    uint4* opb = actout + (size_t)(sc * 4 + g) * PPLANE * 2;
    store_halo_s<uint4, 2>(opb, j, i, o * 2, hi);
    store_halo_s<uint4, 2>(opb, j, i, o * 2 + 1, lo);
  }
}

// ---------------- MFMA 3x3 conv, 16x16 pixel tiles + XCD band swizzle ----------------
// Wave = 16 cols x 4 rows; block = 16x16 tile. Out-of-range lanes clamp their LOADS
// to (269,269) but are masked from ALL epilogue stores/reads (vld) — clamped
// duplicates otherwise corrupt the in-place shortcut layer (R7 bug).
template <int CIN, int COUT, bool SC, bool SPLIT>
__global__ __launch_bounds__(256, 2) void k_mconv(
    const uint4* __restrict__ act, const unsigned short* __restrict__ wf,
    const float* __restrict__ bias, const float* __restrict__ pre,
    uint2* __restrict__ actout, float* __restrict__ sout,
    const uint2* __restrict__ scact, const float* __restrict__ scinv,
    const float* __restrict__ wTt) {
  constexpr int KC = CIN / 32, MT = COUT / 16;
  const int lane = threadIdx.x & 63, wv = threadIdx.x >> 6;
  const int quad = lane >> 4, col = lane & 15;
  const int sc = blockIdx.y;
  // XCD band swizzle: 289 tiles -> 8 bands of 36 (+1 tail)
  int bx = blockIdx.x;
  int tile = (bx < 288) ? ((bx & 7) * 36 + (bx >> 3)) : 288;
  const int tx0 = (tile % 17) * 16, ty0 = (tile / 17) * 16;

  uint32 py[4], px[4], boff[4];
  bool vld[4];
#pragma unroll
  for (int nt = 0; nt < 4; ++nt) {
    int xr = tx0 + col, yr = ty0 + wv * 4 + nt;
    vld[nt] = (xr < 270) && (yr < 270);
    int xx = xr > 269 ? 269 : xr;
    int yy = yr > 269 ? 269 : yr;
    px[nt] = xx; py[nt] = yy;
    boff[nt] = (yy + 1) * PW + xx;
  }
  uint32 bo[KC][4];
#pragma unroll
  for (int kc = 0; kc < KC; ++kc)
#pragma unroll
    for (int nt = 0; nt < 4; ++nt)
      bo[kc][nt] = ((uint32)(sc * (CIN / 8) + kc * 4 + quad) * PPLANE + boff[nt]) * 2;

  f32x4 acc[MT][4];
#pragma unroll
  for (int mt = 0; mt < MT; ++mt)
#pragma unroll
    for (int nt = 0; nt < 4; ++nt) { f32x4 z = {0.f, 0.f, 0.f, 0.f}; acc[mt][nt] = z; }

  // ping-pong B buffers: [parity][kc][nt][hi/lo]
  uint4 B[2][KC][4][2];
  {
    const int doff2 = (-1 * PW + 0) * 2;   // o=0: dy=0,dx=0
#pragma unroll
    for (int kc = 0; kc < KC; ++kc)
#pragma unroll
      for (int nt = 0; nt < 4; ++nt) {
        B[0][kc][nt][0] = act[bo[kc][nt] + doff2];
        B[0][kc][nt][1] = act[bo[kc][nt] + doff2 + 1];
      }
  }

#pragma unroll
  for (int o = 0; o < 9; ++o) {
    if (o < 8) {
      const int dy = (o + 1) / 3, dx = (o + 1) % 3;
      const int doff2 = ((dy - 1) * PW + dx) * 2;
#pragma unroll
      for (int kc = 0; kc < KC; ++kc)
#pragma unroll
        for (int nt = 0; nt < 4; ++nt) {
          B[(o + 1) & 1][kc][nt][0] = act[bo[kc][nt] + doff2];
          B[(o + 1) & 1][kc][nt][1] = act[bo[kc][nt] + doff2 + 1];
        }
    }
#pragma unroll
    for (int kc = 0; kc < KC; ++kc) {
      union { uint4 u; bf16x8 v; } Wh[MT], Wl[MT];
#pragma unroll
      for (int mt = 0; mt < MT; ++mt) {
        const uint4* wp = (const uint4*)wf + ((((o * KC + kc) * MT + mt) * 64 + lane) * 2);
        Wh[mt].u = wp[0]; Wl[mt].u = wp[1];
      }
#pragma unroll
      for (int nt = 0; nt < 4; ++nt) {
        union { uint4 u; bf16x8 v; } Bh, Bl;
        Bh.u = B[o & 1][kc][nt][0];
        Bl.u = B[o & 1][kc][nt][1];
#pragma unroll
        for (int mt = 0; mt < MT; ++mt)
          acc[mt][nt] = __builtin_amdgcn_mfma_f32_16x16x32_bf16(Wh[mt].v, Bh.v, acc[mt][nt], 0, 0, 0);
#pragma unroll
        for (int mt = 0; mt < MT; ++mt)
          acc[mt][nt] = __builtin_amdgcn_mfma_f32_16x16x32_bf16(Wl[mt].v, Bh.v, acc[mt][nt], 0, 0, 0);
#pragma unroll
        for (int mt = 0; mt < MT; ++mt)
          acc[mt][nt] = __builtin_amdgcn_mfma_f32_16x16x32_bf16(Wh[mt].v, Bl.v, acc[mt][nt], 0, 0, 0);
      }
    }
  }

  if (SPLIT) {
#pragma unroll
    for (int mt = 0; mt < MT; ++mt) {
      const int ocb = mt * 16 + quad * 4;
      const int g2 = 2 * mt + (quad >> 1), slot = quad & 1;
      f32x4 bias4 = *(const f32x4*)(bias + ocb);
      f32x4 pr4 = *(const f32x4*)(pre + ocb);
      f32x4 inv4;
      if (SC) inv4 = *(const f32x4*)(scinv + ocb);
#pragma unroll
      for (int nt = 0; nt < 4; ++nt) {
        if (!vld[nt]) continue;        // masked: clamped duplicates must not read/write
        const uint32 ppix = boff[nt] + 1;
        float v[4];
#pragma unroll
        for (int r = 0; r < 4; ++r) v[r] = acc[mt][nt][r] + bias4[r];
        if (SC) {
          const uint2* rec = scact + ((size_t)(sc * (COUT / 8) + g2) * PPLANE + ppix) * 4;
          uint2 hi = rec[slot], lo = rec[2 + slot];
          float s0 = __uint_as_float(hi.x << 16) + __uint_as_float(lo.x << 16);
          float s1 = __uint_as_float(hi.x & 0xFFFF0000u) + __uint_as_float(lo.x & 0xFFFF0000u);
          float s2 = __uint_as_float(hi.y << 16) + __uint_as_float(lo.y << 16);
          float s3 = __uint_as_float(hi.y & 0xFFFF0000u) + __uint_as_float(lo.y & 0xFFFF0000u);
          v[0] += (s0 >= 0.f) ? s0 : s0 * inv4[0];
          v[1] += (s1 >= 0.f) ? s1 : s1 * inv4[1];
          v[2] += (s2 >= 0.f) ? s2 : s2 * inv4[2];
          v[3] += (s3 >= 0.f) ? s3 : s3 * inv4[3];
        }
        float t0 = fmaxf(v[0], 0.f) + pr4[0] * fminf(v[0], 0.f);
        float t1 = fmaxf(v[1], 0.f) + pr4[1] * fminf(v[1], 0.f);
        float t2 = fmaxf(v[2], 0.f) + pr4[2] * fminf(v[2], 0.f);
        float t3 = fmaxf(v[3], 0.f) + pr4[3] * fminf(v[3], 0.f);
        uint2 sp0 = split_pack(t0, t1), sp1 = split_pack(t2, t3);
        uint2* opb = actout + (size_t)(sc * (COUT / 8) + g2) * PPLANE * 4;
        int oidx = (int)ppix * 4;
        store_halo_s<uint2, 4>(opb, (int)px[nt], (int)py[nt], oidx + slot,     make_uint2(sp0.x, sp1.x));
        store_halo_s<uint2, 4>(opb, (int)px[nt], (int)py[nt], oidx + 2 + slot, make_uint2(sp0.y, sp1.y));
      }
    }
  } else {
    // fused convT channel contraction: s_t = sum_ch wT[t][ch]*(acc+bias)
    float4 b4[MT];
#pragma unroll
    for (int mt = 0; mt < MT; ++mt) b4[mt] = *(const float4*)(bias + mt * 16 + quad * 4);
#pragma unroll
    for (int nt = 0; nt < 4; ++nt) {
      float vv[MT][4];
#pragma unroll
      for (int mt = 0; mt < MT; ++mt) {
        vv[mt][0] = acc[mt][nt][0] + b4[mt].x;
        vv[mt][1] = acc[mt][nt][1] + b4[mt].y;
        vv[mt][2] = acc[mt][nt][2] + b4[mt].z;
        vv[mt][3] = acc[mt][nt][3] + b4[mt].w;
      }
      float* sp = sout + (size_t)sc * 25 * PLANE + (int)(py[nt] * 270 + px[nt]);
#pragma unroll
      for (int t = 0; t < 25; ++t) {
        const float* wp = wTt + t * 32 + quad * 4;
        float c = 0.f;
#pragma unroll
        for (int mt = 0; mt < MT; ++mt) {
          float4 w4 = *(const float4*)(wp + mt * 16);
          c += w4.x * vv[mt][0] + w4.y * vv[mt][1] + w4.z * vv[mt][2] + w4.w * vv[mt][3];
        }
        c += __shfl_xor(c, 16, 64);        // vld is quad-uniform: shuffles stay uniform
        c += __shfl_xor(c, 32, 64);
        if (quad == 0 && vld[nt]) sp[(size_t)t * PLANE] = c;
      }
    }
  }
}

// ---------------- convT pass 2: out = bt + sum_t s_t(shifted) ----------------
__global__ __launch_bounds__(256) void k_convT2(const float* __restrict__ s, const float* __restrict__ bt,
                                                float* __restrict__ yo) {
  int p = blockIdx.x * 256 + threadIdx.x;
  if (p >= PLANE) return;
  int sc = blockIdx.y;
  int y = p / 270, x = p - y * 270;
  float acc = bt[0];
  const float* sb = s + (size_t)sc * 25 * PLANE;
#pragma unroll
  for (int a = 0; a < 5; ++a) {
    int yy = y + a - 2;
    if ((unsigned)yy >= 270u) continue;
    const float* row = sb + (size_t)(a * 5) * PLANE + yy * 270;
#pragma unroll
    for (int b = 0; b < 5; ++b) {
      int xx = x + b - 2;
      if ((unsigned)xx < 270u) acc += row[(size_t)b * PLANE + xx];
    }
  }
  yo[(size_t)sc * PLANE + p] = acc;
}

// ---------------- norm projection scale ----------------
__global__ __launch_bounds__(256) void k_nrm(const float* __restrict__ yb, float* __restrict__ red) {
  int s = blockIdx.x;
  const float* ys = yb + (size_t)s * PLANE;
  float acc = 0.f;
  for (int i = threadIdx.x; i < PLANE; i += 256) { float v = ys[i]; acc += v * v; }
  float tot = blockReduceSum(acc);
  if (threadIdx.x == 0) {
    float nrm = sqrtf(tot);
    float eps = red[8 + s];
    red[16 + s] = (nrm > eps) ? eps / fmaxf(nrm, 1e-12f) : 1.0f;
  }
}

// ---------------- final: clip(z - scl*y), crop, mix ----------------
__global__ __launch_bounds__(256) void k_final(const float* __restrict__ z, const float* __restrict__ yb,
                                               const float* __restrict__ red, const float* __restrict__ mw,
                                               float* __restrict__ out) {
  int idx = blockIdx.x * 256 + threadIdx.x;
  if (idx >= 131072) return;
  int b = idx >> 16;
  int rem = idx & 65535;
  int h = rem >> 8, w = rem & 255;
  int p = (h + 7) * HP + (w + 7);
  float acc = 0.f;
#pragma unroll
  for (int d = 0; d < 4; ++d) {
    int s = b * 4 + d;
    float v = z[(size_t)s * PLANE + p] - red[16 + s] * yb[(size_t)s * PLANE + p];
    v = fminf(fmaxf(v, 0.f), 255.f);
    acc += mw[d] * v;
  }
  out[idx] = acc;
}

// =====================================================================
extern "C" void kernel_launch(void* const* d_in, const int* in_sizes, int n_in,
                              void* d_out, int out_size, void* d_ws, size_t ws_size,
                              hipStream_t stream) {
  (void)in_sizes; (void)n_in; (void)out_size; (void)ws_size;
  const float* x    = (const float*)d_in[0];
  const float* bk   = (const float*)d_in[1];
  const float* stdn = (const float*)d_in[2];
  const float* ww   = (const float*)d_in[3];
  const float* wwsc = (const float*)d_in[4];
  const float* alph = (const float*)d_in[5];
  const float* cw   = (const float*)d_in[6];
  const float* sf   = (const float*)d_in[7];
  const float* bf   = (const float*)d_in[8];
  const float* bt   = (const float*)d_in[9];
  const float* p1   = (const float*)d_in[10];
  const float* w1   = (const float*)d_in[11];
  const float* s1   = (const float*)d_in[12];
  const float* b1   = (const float*)d_in[13];
  const float* p2   = (const float*)d_in[14];
  const float* w2   = (const float*)d_in[15];
  const float* s2   = (const float*)d_in[16];
  const float* b2   = (const float*)d_in[17];
  const float* apj  = (const float*)d_in[18];
  const float* mwp  = (const float*)d_in[19];
  float* out = (float*)d_out;

  char* wsbase = (char*)d_ws;
  size_t off = 0;
  auto alloc = [&](size_t nbytes) -> char* {
    char* p = wsbase + off;
    off = (off + nbytes + 255) & ~(size_t)255;
    return p;
  };
  // ---- persistent region ----
  float*  zb  = (float*)alloc(8 * (size_t)PLANE * 4);
  float*  yb  = (float*)alloc(8 * (size_t)PLANE * 4);
  float*  red = (float*)alloc(64 * 4);
  float*  inv = (float*)alloc(32 * 4);
  float*  cwn = (float*)alloc(800 * 4);
  float*  wTt = (float*)alloc(800 * 4);
  unsigned short* w1f = (unsigned short*)alloc(5 * 36864 * (size_t)2);
  unsigned short* w2f = (unsigned short*)alloc(5 * 36864 * (size_t)2);
  // ---- union region ----
  size_t U0 = off;
  // DFT view
  float2* tw  = (float2*)alloc(2 * (size_t)PLANE * 4);
  float*  xp  = (float*)alloc(2 * (size_t)PLANE * 4);
  float*  rtm = (float*)alloc(2 * (size_t)PLANE * 4);
  float2* cb0 = (float2*)alloc(2 * 8 * (size_t)PLANE * 8);
  float2* cb1 = (float2*)alloc(2 * 8 * (size_t)PLANE * 8);
  float2* Yb  = (float2*)alloc(2 * 2 * (size_t)PLANE * 8);
  float2* Hf  = (float2*)alloc(2 * (size_t)PLANE * 4);
  float*  Sb  = (float*)alloc((size_t)PLANE * 4);
  float2* Tb  = (float2*)alloc(2 * 4 * (size_t)PLANE * 4);
  float*  ahw = (float*)alloc(540 * 4);
  float*  wwn = (float*)alloc(600 * 4);
  // conv view (aliases the DFT view)
  off = U0;
  uint4* act1 = (uint4*)alloc(4 * 4 * (size_t)PPLANE * 32);   // 32ch split acts; also aliases sOb (4*25*PLANE f32)
  uint4* act2 = (uint4*)alloc(4 * 8 * (size_t)PPLANE * 32);   // 64ch split acts
  float* sOb = (float*)act1;

  // setup
  k_twiddle<<<285, 256, 0, stream>>>(tw);
  k_sympad<<<(2 * PLANE + 255) / 256, 256, 0, stream>>>(x, xp);
  k_edget<<<1, 512, 0, stream>>>(bk, ahw);
  k_Hf<<<285, 256, 0, stream>>>(bk, Hf);
  k_wnorm<<<24, 256, 0, stream>>>(ww, wwsc, wwn, 25);
  k_wnorm<<<32, 256, 0, stream>>>(cw, sf, cwn, 25);
  k_wT<<<4, 256, 0, stream>>>(cwn, wTt);
  k_wfrag<32, 64><<<320, 256, 0, stream>>>(w1, s1, w1f);
  k_wfrag<64, 32><<<160, 256, 0, stream>>>(w2, s2, w2f);
  k_inv<<<1, 32, 0, stream>>>(p1, inv);
  k_S<<<285, 256, 0, stream>>>(wwn, Sb);
  k_T<<<(4 * PLANE + 255) / 256, 256, 0, stream>>>(Hf, Sb, alph, Tb);
  k_amp<<<4, 256, 0, stream>>>(Tb, red);
  k_eps<<<1, 64, 0, stream>>>(apj, stdn, red);

  dim3 g2(5, 45, 2), g8(5, 45, 8);

  // edgetaper
  k_rowT<6, true ><<<g2, 64, 0, stream>>>(xp, cb1, tw, -1.f);
  k_colT<6, false><<<g2, 64, 0, stream>>>(cb1, cb0, tw, -1.f, 1.f);
  k_mulHf<<<(2 * PLANE + 255) / 256, 256, 0, stream>>>(cb0, Hf, cb1);
  k_rowT<6, false><<<g2, 64, 0, stream>>>(cb1, cb0, tw, 1.f);
  k_colT<6, true ><<<g2, 64, 0, stream>>>(cb0, rtm, tw, 1.f, 1.f / (float)PLANE);
  k_taper<<<(2 * PLANE + 255) / 256, 256, 0, stream>>>(xp, rtm, ahw);

  // Y = fft2(xp)
  k_rowT<6, true ><<<g2, 64, 0, stream>>>(xp, cb1, tw, -1.f);
  k_colT<6, false><<<g2, 64, 0, stream>>>(cb1, Yb, tw, -1.f, 1.f);

  // z = ifft2(T*Y).real for all 8 (b,d)
  k_mulTY<<<(8 * PLANE + 255) / 256, 256, 0, stream>>>(Tb, Yb, cb0);
  k_rowT<6, false><<<g8, 64, 0, stream>>>(cb0, cb1, tw, 1.f);
  k_colT<6, true ><<<g8, 64, 0, stream>>>(cb1, zb, tw, 1.f, 1.f / (float)PLANE);

  // conv net, 2 chunks of 4 samples
  for (int c = 0; c < 2; ++c) {
    const float* zc = zb + (size_t)c * 4 * PLANE;
    float* ybc = yb + (size_t)c * 4 * PLANE;
    k_conv5<<<dim3(285, 4), 256, 0, stream>>>(zc, cwn, bf, p1, act1);
    for (int i = 0; i < 5; ++i) {
      k_mconv<32, 64, false, true><<<dim3(289, 4), 256, 0, stream>>>(
          act1, w1f + (size_t)i * 36864, b1 + i * 64, p2 + i * 64, (uint2*)act2, nullptr, nullptr, nullptr, nullptr);
      if (i == 0)
        k_mconv<64, 32, true, true><<<dim3(289, 4), 256, 0, stream>>>(
            act2, w2f + (size_t)i * 36864, b2 + i * 32, p1 + (i + 1) * 32, (uint2*)act1, nullptr, (const uint2*)act1, inv, nullptr);
      else if (i < 4)
        k_mconv<64, 32, false, true><<<dim3(289, 4), 256, 0, stream>>>(
            act2, w2f + (size_t)i * 36864, b2 + i * 32, p1 + (i + 1) * 32, (uint2*)act1, nullptr, nullptr, nullptr, nullptr);
      else
        k_mconv<64, 32, false, false><<<dim3(289, 4), 256, 0, stream>>>(
            act2, w2f + (size_t)i * 36864, b2 + i * 32, nullptr, nullptr, sOb, nullptr, nullptr, wTt);
    }
    k_convT2<<<dim3(285, 4), 256, 0, stream>>>(sOb, bt, ybc);
  }

  // projection + final mix
  k_nrm<<<8, 256, 0, stream>>>(yb, red);
  k_final<<<(131072 + 255) / 256, 256, 0, stream>>>(zb, yb, red, mwp, out);
}